// Round 2
// baseline (2100.490 us; speedup 1.0000x reference)
//
#include <hip/hip_runtime.h>

#define NND 100000
#define NED 1600000
#define NB  1024
#define FEAT 9
#define HC 128

__device__ __forceinline__ void atomAdd(float* p, float v) {
    __hip_atomic_fetch_add(p, v, __ATOMIC_RELAXED, __HIP_MEMORY_SCOPE_AGENT);
}
__device__ __forceinline__ float leaky(float v, float s) { return v >= 0.f ? v : s * v; }

// ---- K2: per-node attention scalars a_s, a_d (h never materialized) ----
__global__ void k_node_att(const float* __restrict__ x, const float* __restrict__ Wg,
                           const float* __restrict__ attS, const float* __restrict__ attD,
                           float* __restrict__ a_s, float* __restrict__ a_d) {
    __shared__ float Wf[FEAT * HC];
    __shared__ float xs[FEAT];
    int t = threadIdx.x;  // 128
    for (int f = 0; f < FEAT; ++f) Wf[f * HC + t] = Wg[f * HC + t];
    float aS = attS[t], aD = attD[t];
    int i0 = blockIdx.x * 64;
    for (int n = 0; n < 64; ++n) {
        int i = i0 + n;
        if (i >= NND) break;
        __syncthreads();
        if (t < FEAT) xs[t] = x[i * FEAT + t];
        __syncthreads();
        float h = 0.f;
#pragma unroll
        for (int f = 0; f < FEAT; ++f) h += xs[f] * Wf[f * HC + t];
        float pS = h * aS, pD = h * aD;
#pragma unroll
        for (int off = 16; off; off >>= 1) {
            pS += __shfl_xor(pS, off, 32);
            pD += __shfl_xor(pD, off, 32);
        }
        if ((t & 31) == 0) {
            a_s[i * 4 + (t >> 5)] = pS;
            a_d[i * 4 + (t >> 5)] = pD;
        }
    }
}

// ---- K3: softmax denominators + in-degree (thread per edge, incl self loops) ----
__global__ void k_edge_denom(const int* __restrict__ ei, const float* __restrict__ a_s,
                             const float* __restrict__ a_d, float* __restrict__ sden,
                             float* __restrict__ deg) {
    int e = blockIdx.x * blockDim.x + threadIdx.x;
    const int etot = NED + NND;
    if (e >= etot) return;
    int src, dst;
    if (e < NED) { src = ei[e]; dst = ei[NED + e]; atomAdd(&deg[dst], 1.f); }
    else { src = e - NED; dst = src; }
    const float4 as = *(const float4*)(a_s + src * 4);
    const float4 ad = *(const float4*)(a_d + dst * 4);
    atomAdd(&sden[dst * 4 + 0], __expf(leaky(as.x + ad.x, 0.2f)));
    atomAdd(&sden[dst * 4 + 1], __expf(leaky(as.y + ad.y, 0.2f)));
    atomAdd(&sden[dst * 4 + 2], __expf(leaky(as.z + ad.z, 0.2f)));
    atomAdd(&sden[dst * 4 + 3], __expf(leaky(as.w + ad.w, 0.2f)));
}

// ---- K4: dinv = rsqrt(deg+1) in place ----
__global__ void k_dinv(float* deg) {
    int i = blockIdx.x * blockDim.x + threadIdx.x;
    if (i < NND) deg[i] = rsqrtf(deg[i] + 1.f);
}

// ---- K5: GAT weighted aggregation in x-space (wave per edge, 36 lanes active) ----
__global__ void k_gat_agg(const int* __restrict__ ei, const float* __restrict__ x,
                          const float* __restrict__ a_s, const float* __restrict__ a_d,
                          const float* __restrict__ sden, float* __restrict__ z) {
    long gid = (long)blockIdx.x * blockDim.x + threadIdx.x;
    int e = (int)(gid >> 6), lane = (int)(gid & 63);
    const int etot = NED + NND;
    if (e >= etot) return;
    int src, dst;
    if (e < NED) { src = ei[e]; dst = ei[NED + e]; }
    else { src = e - NED; dst = src; }
    if (lane >= 36) return;
    int h = lane / 9, f = lane - h * 9;
    float v = leaky(a_s[src * 4 + h] + a_d[dst * 4 + h], 0.2f);
    float alpha = __expf(v) / sden[dst * 4 + h];
    atomAdd(&z[dst * 36 + lane], alpha * x[src * FEAT + f]);
}

// ---- K6: g1 = leaky(z @ W_head + b_gat) ----
__global__ void k_gat_out(const float* __restrict__ z, const float* __restrict__ Wg,
                          const float* __restrict__ bg, float* __restrict__ g1) {
    __shared__ float Wf[FEAT * HC];
    __shared__ float zs[36];
    int t = threadIdx.x;  // 128
    for (int f = 0; f < FEAT; ++f) Wf[f * HC + t] = Wg[f * HC + t];
    float bias = bg[t];
    int h = t >> 5;
    int i0 = blockIdx.x * 64;
    for (int n = 0; n < 64; ++n) {
        int i = i0 + n;
        if (i >= NND) break;
        __syncthreads();
        if (t < 36) zs[t] = z[i * 36 + t];
        __syncthreads();
        float acc = bias;
#pragma unroll
        for (int f = 0; f < FEAT; ++f) acc += zs[h * 9 + f] * Wf[f * HC + t];
        g1[i * HC + t] = leaky(acc, 0.01f);
    }
}

// ---- K7: h2 = g1 @ W2  (N x 128 @ 128 x 64) ----
__global__ void k_gemm_h2(const float* __restrict__ g1, const float* __restrict__ W2,
                          float* __restrict__ h2) {
    __shared__ float Wf[128 * 64];
    __shared__ float rws[4][128];
    int t = threadIdx.x;  // 256
#pragma unroll
    for (int j = 0; j < 32; ++j) Wf[t + j * 256] = W2[t + j * 256];
    int rbase0 = blockIdx.x * 32;
    int sub = t >> 6, col = t & 63;
    for (int p = 0; p < 8; ++p) {
        int rbase = rbase0 + p * 4;
        __syncthreads();
        { int lr = t >> 7, k = t & 127;        rws[lr][k] = g1[(rbase + lr) * 128 + k]; }
        { int i2 = t + 256; int lr = i2 >> 7, k = i2 & 127; rws[lr][k] = g1[(rbase + lr) * 128 + k]; }
        __syncthreads();
        float acc = 0.f;
#pragma unroll
        for (int k = 0; k < 128; ++k) acc += rws[sub][k] * Wf[k * 64 + col];
        h2[(rbase + sub) * 64 + col] = acc;
    }
}

// ---- K8/K10: GCN edge aggregation (wave per edge, 64ch) ----
__global__ void k_gcn_agg(const int* __restrict__ ei, const float* __restrict__ dinv,
                          const float* __restrict__ hsrc, float* __restrict__ acc) {
    long gid = (long)blockIdx.x * blockDim.x + threadIdx.x;
    int e = (int)(gid >> 6), lane = (int)(gid & 63);
    if (e >= NED) return;
    int src = ei[e], dst = ei[NED + e];
    float nrm = dinv[src] * dinv[dst];
    atomAdd(&acc[dst * 64 + lane], nrm * hsrc[src * 64 + lane]);
}

// ---- K9: g2 = leaky(acc2 + dinv^2*h2 + b2); re-zero h2 for reuse as agg3 ----
__global__ void k_gcn1_fin(float* __restrict__ acc2, float* __restrict__ h2,
                           const float* __restrict__ dinv, const float* __restrict__ b2) {
    int idx = blockIdx.x * blockDim.x + threadIdx.x;
    if (idx >= NND * 64) return;
    int i = idx >> 6, c = idx & 63;
    float d = dinv[i];
    float v = acc2[idx] + d * d * h2[idx] + b2[c];
    acc2[idx] = leaky(v, 0.01f);
    h2[idx] = 0.f;
}

// ---- K11: g3 = leaky((agg3 + dinv^2*g2) @ W3 + b3)  (N x 64 @ 64 x 128) ----
__global__ void k_gcn2_out(const float* __restrict__ agg3, const float* __restrict__ g2,
                           const float* __restrict__ dinv, const float* __restrict__ W3,
                           const float* __restrict__ b3, float* __restrict__ g3) {
    __shared__ float Wf[64 * 128];
    __shared__ float rws[2][64];
    int t = threadIdx.x;  // 256
#pragma unroll
    for (int j = 0; j < 32; ++j) Wf[t + j * 256] = W3[t + j * 256];
    int col = t & 127, sub = t >> 7;
    float bias = b3[col];
    int rbase0 = blockIdx.x * 32;
    for (int p = 0; p < 16; ++p) {
        int rbase = rbase0 + p * 2;
        __syncthreads();
        if (t < 128) {
            int lr = t >> 6, k = t & 63;
            int row = rbase + lr;
            float d = dinv[row];
            rws[lr][k] = agg3[row * 64 + k] + d * d * g2[row * 64 + k];
        }
        __syncthreads();
        float acc = bias;
#pragma unroll
        for (int k = 0; k < 64; ++k) acc += rws[sub][k] * Wf[k * 128 + col];
        g3[(rbase + sub) * 128 + col] = leaky(acc, 0.01f);
    }
}

// ---- K12: mean-pool accumulation ----
__global__ void k_pool(const float* __restrict__ g3, const int* __restrict__ batch,
                       float* __restrict__ pooled, float* __restrict__ cnt) {
    int tid = blockIdx.x * blockDim.x + threadIdx.x;
    if (tid >= NND * 32) return;
    int i = tid >> 5, q = tid & 31;
    int b = batch[i];
    const float4 v = *(const float4*)(g3 + i * 128 + q * 4);
    atomAdd(&pooled[b * 128 + q * 4 + 0], v.x);
    atomAdd(&pooled[b * 128 + q * 4 + 1], v.y);
    atomAdd(&pooled[b * 128 + q * 4 + 2], v.z);
    atomAdd(&pooled[b * 128 + q * 4 + 3], v.w);
    if (q == 0) atomAdd(&cnt[b], 1.f);
}

// ---- K13: fused sequence branch -> sfc [B,64] ----
__global__ void k_seq(const float* __restrict__ seq, const float* __restrict__ w1, const float* __restrict__ c1b,
                      const float* __restrict__ w2, const float* __restrict__ c2b,
                      const float* __restrict__ g1n, const float* __restrict__ b1n,
                      const float* __restrict__ m1n, const float* __restrict__ v1n,
                      const float* __restrict__ g2n, const float* __restrict__ b2n,
                      const float* __restrict__ m2n, const float* __restrict__ v2n,
                      const float* __restrict__ fcW, const float* __restrict__ fcb,
                      float* __restrict__ sfc) {
    __shared__ float xs[30 * 20];
    __shared__ float y1[64 * 18];
    __shared__ float y2[64 * 16];
    __shared__ float red[4][64];
    int t = threadIdx.x;  // 256
    int b = blockIdx.x;
    for (int idx = t; idx < 600; idx += 256) xs[idx] = seq[b * 600 + idx];
    __syncthreads();
    for (int idx = t; idx < 64 * 18; idx += 256) {
        int o = idx / 18, l = idx - o * 18;
        float acc = c1b[o];
        for (int i = 0; i < 30; ++i)
#pragma unroll
            for (int k = 0; k < 3; ++k)
                acc += xs[i * 20 + l + k] * w1[o * 90 + i * 3 + k];
        float bn = (acc - m1n[o]) * rsqrtf(v1n[o] + 1e-5f) * g1n[o] + b1n[o];
        y1[idx] = leaky(bn, 0.01f);
    }
    __syncthreads();
    for (int idx = t; idx < 64 * 16; idx += 256) {
        int o = idx >> 4, l = idx & 15;
        float acc = c2b[o];
        for (int i = 0; i < 64; ++i)
#pragma unroll
            for (int k = 0; k < 3; ++k)
                acc += y1[i * 18 + l + k] * w2[o * 192 + i * 3 + k];
        float bn = (acc - m2n[o]) * rsqrtf(v2n[o] + 1e-5f) * g2n[o] + b2n[o];
        y2[idx] = leaky(bn, 0.01f);
    }
    __syncthreads();
    {
        int o = t & 63, part = t >> 6;
        float acc = 0.f;
        for (int j = part * 256; j < part * 256 + 256; ++j)
            acc += y2[j] * fcW[j * 64 + o];
        red[part][o] = acc;
    }
    __syncthreads();
    if (t < 64) sfc[b * 64 + t] = red[0][t] + red[1][t] + red[2][t] + red[3][t] + fcb[t];
}

// ---- K14: fusion + classifier -> out [B,1] f32 ----
__global__ void k_final(const float* __restrict__ pooled, const float* __restrict__ cnt,
                        const float* __restrict__ sfc,
                        const float* __restrict__ fusW, const float* __restrict__ fusb,
                        const float* __restrict__ c1W, const float* __restrict__ c1b,
                        const float* __restrict__ c3W, const float* __restrict__ c3b,
                        float* __restrict__ out) {
    __shared__ float comb[192];
    __shared__ float t1[128];
    int t = threadIdx.x;  // 128
    int b = blockIdx.x;
    float invc = 1.f / fmaxf(cnt[b], 1.f);
    comb[t] = pooled[b * 128 + t] * invc;
    if (t < 64) comb[128 + t] = sfc[b * 64 + t];
    __syncthreads();
    float acc = fusb[t];
    for (int k = 0; k < 192; ++k) acc += comb[k] * fusW[k * 128 + t];
    t1[t] = leaky(acc, 0.01f);
    __syncthreads();
    if (t < 64) {
        float a2 = c1b[t];
        for (int k = 0; k < 128; ++k) a2 += t1[k] * c1W[k * 64 + t];
        a2 = leaky(a2, 0.01f);
        float p = a2 * c3W[t];
#pragma unroll
        for (int off = 32; off; off >>= 1) p += __shfl_xor(p, off, 64);
        if (t == 0) out[b] = p + c3b[0];
    }
}

extern "C" void kernel_launch(void* const* d_in, const int* in_sizes, int n_in,
                              void* d_out, int out_size, void* d_ws, size_t ws_size,
                              hipStream_t stream) {
    const float* x     = (const float*)d_in[0];
    const int*   ei    = (const int*)d_in[1];
    const int*   batch = (const int*)d_in[2];
    const float* seq   = (const float*)d_in[3];
    const float* Wg    = (const float*)d_in[4];
    const float* attS  = (const float*)d_in[5];
    const float* attD  = (const float*)d_in[6];
    const float* bg    = (const float*)d_in[7];
    const float* W2    = (const float*)d_in[8];
    const float* b2    = (const float*)d_in[9];
    const float* W3    = (const float*)d_in[10];
    const float* b3    = (const float*)d_in[11];
    const float* c1w   = (const float*)d_in[12];
    const float* c1bb  = (const float*)d_in[13];
    const float* c2w   = (const float*)d_in[14];
    const float* c2bb  = (const float*)d_in[15];
    const float* bn1g  = (const float*)d_in[16];
    const float* bn1b  = (const float*)d_in[17];
    const float* bn1m  = (const float*)d_in[18];
    const float* bn1v  = (const float*)d_in[19];
    const float* bn2g  = (const float*)d_in[20];
    const float* bn2b  = (const float*)d_in[21];
    const float* bn2m  = (const float*)d_in[22];
    const float* bn2v  = (const float*)d_in[23];
    const float* fcW   = (const float*)d_in[24];
    const float* fcb   = (const float*)d_in[25];
    const float* fusW  = (const float*)d_in[26];
    const float* fusb  = (const float*)d_in[27];
    const float* cls1W = (const float*)d_in[28];
    const float* cls1b = (const float*)d_in[29];
    const float* cls3W = (const float*)d_in[30];
    const float* cls3b = (const float*)d_in[31];

    float* ws = (float*)d_ws;
    const size_t N = NND;
    float* a_s    = ws;                       // N*4
    float* a_d    = a_s + N * 4;              // N*4
    float* gA     = a_d + N * 4;              // N*128 (g1, then g3)
    float* B1     = gA + N * 128;             // N*64  (h2, then agg3)
    float* deg    = B1 + N * 64;              // N     -- zero block start
    float* sden   = deg + N;                  // N*4
    float* z      = sden + N * 4;             // N*36
    float* acc2   = z + N * 36;               // N*64  (becomes g2)
    float* pooled = acc2 + N * 64;            // B*128
    float* cnt    = pooled + (size_t)NB * 128;// B     -- zero block end
    float* sfc    = cnt + NB;                 // B*64

    size_t zero_floats = N * (1 + 4 + 36 + 64) + (size_t)NB * 129;
    hipMemsetAsync(deg, 0, zero_floats * sizeof(float), stream);

    const int etot = NED + NND;
    k_node_att<<<(NND + 63) / 64, 128, 0, stream>>>(x, Wg, attS, attD, a_s, a_d);
    k_edge_denom<<<(etot + 255) / 256, 256, 0, stream>>>(ei, a_s, a_d, sden, deg);
    k_dinv<<<(NND + 255) / 256, 256, 0, stream>>>(deg);
    k_gat_agg<<<(etot + 3) / 4, 256, 0, stream>>>(ei, x, a_s, a_d, sden, z);
    k_gat_out<<<(NND + 63) / 64, 128, 0, stream>>>(z, Wg, bg, gA);
    k_gemm_h2<<<NND / 32, 256, 0, stream>>>(gA, W2, B1);
    k_gcn_agg<<<(NED + 3) / 4, 256, 0, stream>>>(ei, deg, B1, acc2);
    k_gcn1_fin<<<(NND * 64 + 255) / 256, 256, 0, stream>>>(acc2, B1, deg, b2);
    k_gcn_agg<<<(NED + 3) / 4, 256, 0, stream>>>(ei, deg, acc2, B1);
    k_gcn2_out<<<NND / 32, 256, 0, stream>>>(B1, acc2, deg, W3, b3, gA);
    k_pool<<<(NND * 32 + 255) / 256, 256, 0, stream>>>(gA, batch, pooled, cnt);
    k_seq<<<NB, 256, 0, stream>>>(seq, c1w, c1bb, c2w, c2bb, bn1g, bn1b, bn1m, bn1v,
                                  bn2g, bn2b, bn2m, bn2v, fcW, fcb, sfc);
    k_final<<<NB, 128, 0, stream>>>(pooled, cnt, sfc, fusW, fusb, cls1W, cls1b,
                                    cls3W, cls3b, (float*)d_out);
}

// Round 3
// 1286.877 us; speedup vs baseline: 1.6322x; 1.6322x over previous
//
#include <hip/hip_runtime.h>

#define NND 100000
#define NED 1600000
#define NB  1024
#define FEAT 9
#define HC 128

__device__ __forceinline__ void atomAdd(float* p, float v) {
    __hip_atomic_fetch_add(p, v, __ATOMIC_RELAXED, __HIP_MEMORY_SCOPE_AGENT);
}
__device__ __forceinline__ unsigned atomAddU(unsigned* p, unsigned v) {
    return __hip_atomic_fetch_add(p, v, __ATOMIC_RELAXED, __HIP_MEMORY_SCOPE_AGENT);
}
__device__ __forceinline__ float leaky(float v, float s) { return v >= 0.f ? v : s * v; }

// ---- K1: M_s[f,h] = sum_c Wg[f,h*32+c]*attS[h,c]; same for M_d (one block) ----
__global__ void k_matt(const float* __restrict__ Wg, const float* __restrict__ attS,
                       const float* __restrict__ attD, float* __restrict__ M) {
    int t = threadIdx.x;  // 128, use 72
    if (t >= 72) return;
    int d = t >= 36 ? 1 : 0;
    int q = t - 36 * d;
    int f = q >> 2, h = q & 3;
    const float* av = d ? attD : attS;
    float s = 0.f;
#pragma unroll
    for (int c = 0; c < 32; ++c) s += Wg[f * HC + h * 32 + c] * av[h * 32 + c];
    M[d * 36 + q] = s;
}

// ---- K2: a_s = x @ M_s, a_d = x @ M_d (thread per node) ----
__global__ void k_att(const float* __restrict__ x, const float* __restrict__ M,
                      float* __restrict__ a_s, float* __restrict__ a_d) {
    __shared__ float Ms[36], Md[36];
    int t = threadIdx.x;  // 256
    if (t < 36) Ms[t] = M[t];
    else if (t < 72) Md[t - 36] = M[t];
    __syncthreads();
    int n = blockIdx.x * 256 + t;
    if (n >= NND) return;
    float xv[FEAT];
#pragma unroll
    for (int f = 0; f < FEAT; ++f) xv[f] = x[n * FEAT + f];
    float s0 = 0, s1 = 0, s2 = 0, s3 = 0, d0 = 0, d1 = 0, d2 = 0, d3 = 0;
#pragma unroll
    for (int f = 0; f < FEAT; ++f) {
        float xf = xv[f];
        s0 += xf * Ms[f * 4 + 0]; s1 += xf * Ms[f * 4 + 1];
        s2 += xf * Ms[f * 4 + 2]; s3 += xf * Ms[f * 4 + 3];
        d0 += xf * Md[f * 4 + 0]; d1 += xf * Md[f * 4 + 1];
        d2 += xf * Md[f * 4 + 2]; d3 += xf * Md[f * 4 + 3];
    }
    ((float4*)a_s)[n] = make_float4(s0, s1, s2, s3);
    ((float4*)a_d)[n] = make_float4(d0, d1, d2, d3);
}

// ---- K3: in-degree histogram (real edges only) ----
__global__ void k_deg(const int* __restrict__ ei, unsigned* __restrict__ deg) {
    int e = blockIdx.x * 256 + threadIdx.x;
    if (e < NED) atomAddU(&deg[ei[NED + e]], 1u);
}

// ---- K4: exclusive scan deg -> rowptr, cursor (single block, 1024 thr) ----
__global__ void k_scan(const unsigned* __restrict__ deg, unsigned* __restrict__ rowptr,
                       unsigned* __restrict__ cursor) {
    __shared__ unsigned sums[1024];
    int t = threadIdx.x;
    const int CHK = (NND + 1023) / 1024;  // 98
    int lo = t * CHK, hi = lo + CHK; if (hi > NND) hi = NND;
    unsigned s = 0;
    for (int i = lo; i < hi; ++i) s += deg[i];
    sums[t] = s;
    __syncthreads();
    for (int off = 1; off < 1024; off <<= 1) {
        unsigned v = (t >= off) ? sums[t - off] : 0u;
        __syncthreads();
        sums[t] += v;
        __syncthreads();
    }
    unsigned base = (t == 0) ? 0u : sums[t - 1];
    for (int i = lo; i < hi; ++i) {
        rowptr[i] = base; cursor[i] = base; base += deg[i];
    }
    if (t == 1023) rowptr[NND] = sums[1023];
}

// ---- K5: fill CSR (counting sort by dst) ----
__global__ void k_fill(const int* __restrict__ ei, unsigned* __restrict__ cursor,
                       unsigned* __restrict__ csr) {
    int e = blockIdx.x * 256 + threadIdx.x;
    if (e >= NED) return;
    int src = ei[e], dst = ei[NED + e];
    unsigned pos = atomAddU(&cursor[dst], 1u);
    csr[pos] = (unsigned)src;
}

// ---- K6: softmax denominators (gather) + dinv (thread per node) ----
__global__ void k_denom(const unsigned* __restrict__ rowptr, const unsigned* __restrict__ csr,
                        const float* __restrict__ a_s, const float* __restrict__ a_d,
                        float* __restrict__ inv_s, float* __restrict__ dinv) {
    int n = blockIdx.x * 256 + threadIdx.x;
    if (n >= NND) return;
    unsigned e0 = rowptr[n], e1 = rowptr[n + 1];
    float4 ad = ((const float4*)a_d)[n];
    float4 as = ((const float4*)a_s)[n];
    float s0 = __expf(leaky(as.x + ad.x, 0.2f));
    float s1 = __expf(leaky(as.y + ad.y, 0.2f));
    float s2 = __expf(leaky(as.z + ad.z, 0.2f));
    float s3 = __expf(leaky(as.w + ad.w, 0.2f));
    for (unsigned e = e0; e < e1; ++e) {
        float4 a = ((const float4*)a_s)[csr[e]];
        s0 += __expf(leaky(a.x + ad.x, 0.2f));
        s1 += __expf(leaky(a.y + ad.y, 0.2f));
        s2 += __expf(leaky(a.z + ad.z, 0.2f));
        s3 += __expf(leaky(a.w + ad.w, 0.2f));
    }
    ((float4*)inv_s)[n] = make_float4(1.f / (s0 + 1e-16f), 1.f / (s1 + 1e-16f),
                                      1.f / (s2 + 1e-16f), 1.f / (s3 + 1e-16f));
    dinv[n] = rsqrtf((float)(e1 - e0) + 1.f);
}

// ---- K7: GAT x-space aggregation (gather; wave per node, lanes 0..35) ----
__global__ void k_gat_g(const unsigned* __restrict__ rowptr, const unsigned* __restrict__ csr,
                        const float* __restrict__ x, const float* __restrict__ a_s,
                        const float* __restrict__ a_d, const float* __restrict__ inv_s,
                        float* __restrict__ z) {
    int n = blockIdx.x * 4 + (threadIdx.x >> 6);  // grid 25000 x 256 exact
    int lane = threadIdx.x & 63;
    bool active = lane < 36;
    int h = active ? lane / 9 : 0;
    int f = active ? lane - h * 9 : 0;
    unsigned e0 = rowptr[n], e1 = rowptr[n + 1];
    float adh = a_d[n * 4 + h];
    float ivh = inv_s[n * 4 + h];
    float acc = __expf(leaky(a_s[n * 4 + h] + adh, 0.2f)) * ivh * x[n * FEAT + f];
    for (unsigned e = e0; e < e1; ++e) {
        int src = (int)csr[e];
        float alpha = __expf(leaky(a_s[src * 4 + h] + adh, 0.2f)) * ivh;
        acc += alpha * x[src * FEAT + f];
    }
    if (active) z[n * 36 + lane] = acc;
}

// ---- K8: g1 = leaky(z @ W_head + b_gat) ----
__global__ void k_gat_out(const float* __restrict__ z, const float* __restrict__ Wg,
                          const float* __restrict__ bg, float* __restrict__ g1) {
    __shared__ float Wf[FEAT * HC];
    __shared__ float zs[36];
    int t = threadIdx.x;  // 128
    for (int f = 0; f < FEAT; ++f) Wf[f * HC + t] = Wg[f * HC + t];
    float bias = bg[t];
    int h = t >> 5;
    int i0 = blockIdx.x * 64;
    for (int n = 0; n < 64; ++n) {
        int i = i0 + n;
        if (i >= NND) break;
        __syncthreads();
        if (t < 36) zs[t] = z[i * 36 + t];
        __syncthreads();
        float acc = bias;
#pragma unroll
        for (int f = 0; f < FEAT; ++f) acc += zs[h * 9 + f] * Wf[f * HC + t];
        g1[i * HC + t] = leaky(acc, 0.01f);
    }
}

// ---- K9: h2 = g1 @ W2  (N x 128 @ 128 x 64) ----
__global__ void k_gemm_h2(const float* __restrict__ g1, const float* __restrict__ W2,
                          float* __restrict__ h2) {
    __shared__ float Wf[128 * 64];
    __shared__ float rws[4][128];
    int t = threadIdx.x;  // 256
#pragma unroll
    for (int j = 0; j < 32; ++j) Wf[t + j * 256] = W2[t + j * 256];
    int rbase0 = blockIdx.x * 32;
    int sub = t >> 6, col = t & 63;
    for (int p = 0; p < 8; ++p) {
        int rbase = rbase0 + p * 4;
        __syncthreads();
        { int lr = t >> 7, k = t & 127;        rws[lr][k] = g1[(rbase + lr) * 128 + k]; }
        { int i2 = t + 256; int lr = i2 >> 7, k = i2 & 127; rws[lr][k] = g1[(rbase + lr) * 128 + k]; }
        __syncthreads();
        float acc = 0.f;
#pragma unroll
        for (int k = 0; k < 128; ++k) acc += rws[sub][k] * Wf[k * 64 + col];
        h2[(rbase + sub) * 64 + col] = acc;
    }
}

// ---- K10/K11: GCN aggregation (gather; wave per node, 64 ch) ----
template <bool ACT>
__global__ void k_gcn_g(const unsigned* __restrict__ rowptr, const unsigned* __restrict__ csr,
                        const float* __restrict__ dinv, const float* __restrict__ hin,
                        const float* __restrict__ bias, float* __restrict__ hout) {
    int n = blockIdx.x * 4 + (threadIdx.x >> 6);  // grid 25000 x 256 exact
    int lane = threadIdx.x & 63;
    unsigned e0 = rowptr[n], e1 = rowptr[n + 1];
    float dn = dinv[n];
    float acc = dn * hin[n * 64 + lane];  // self term (dinv[n]^2 after outer mult)
    for (unsigned e = e0; e < e1; ++e) {
        int src = (int)csr[e];
        acc += dinv[src] * hin[src * 64 + lane];
    }
    float out = dn * acc;
    if (ACT) out = leaky(out + bias[lane], 0.01f);
    hout[n * 64 + lane] = out;
}

// ---- K12: g3 = leaky(agg3 @ W3 + b3)  (N x 64 @ 64 x 128) ----
__global__ void k_gcn2_out(const float* __restrict__ agg3, const float* __restrict__ W3,
                           const float* __restrict__ b3, float* __restrict__ g3) {
    __shared__ float Wf[64 * 128];
    __shared__ float rws[2][64];
    int t = threadIdx.x;  // 256
#pragma unroll
    for (int j = 0; j < 32; ++j) Wf[t + j * 256] = W3[t + j * 256];
    int col = t & 127, sub = t >> 7;
    float bias = b3[col];
    int rbase0 = blockIdx.x * 32;
    for (int p = 0; p < 16; ++p) {
        int rbase = rbase0 + p * 2;
        __syncthreads();
        if (t < 128) {
            int lr = t >> 6, k = t & 63;
            rws[lr][k] = agg3[(rbase + lr) * 64 + k];
        }
        __syncthreads();
        float acc = bias;
#pragma unroll
        for (int k = 0; k < 64; ++k) acc += rws[sub][k] * Wf[k * 128 + col];
        g3[(rbase + sub) * 128 + col] = leaky(acc, 0.01f);
    }
}

// ---- K13: mean-pool using SORTED batch: run-local accumulation, flush on change ----
__global__ void k_pool(const float* __restrict__ g3, const int* __restrict__ batch,
                       float* __restrict__ pooled, float* __restrict__ cnt) {
    int t = threadIdx.x;  // 128
    int n0 = blockIdx.x * 64;
    int n1 = n0 + 64; if (n1 > NND) n1 = NND;
    float acc = 0.f;
    int cur = batch[n0];
    int runStart = n0;
    for (int i = n0; i < n1; ++i) {
        int b = batch[i];
        if (b != cur) {
            atomAdd(&pooled[cur * 128 + t], acc);
            if (t == 0) atomAdd(&cnt[cur], (float)(i - runStart));
            acc = 0.f; cur = b; runStart = i;
        }
        acc += g3[i * 128 + t];
    }
    atomAdd(&pooled[cur * 128 + t], acc);
    if (t == 0) atomAdd(&cnt[cur], (float)(n1 - runStart));
}

// ---- K14: fused sequence branch -> sfc [B,64] ----
__global__ void k_seq(const float* __restrict__ seq, const float* __restrict__ w1, const float* __restrict__ c1b,
                      const float* __restrict__ w2, const float* __restrict__ c2b,
                      const float* __restrict__ g1n, const float* __restrict__ b1n,
                      const float* __restrict__ m1n, const float* __restrict__ v1n,
                      const float* __restrict__ g2n, const float* __restrict__ b2n,
                      const float* __restrict__ m2n, const float* __restrict__ v2n,
                      const float* __restrict__ fcW, const float* __restrict__ fcb,
                      float* __restrict__ sfc) {
    __shared__ float xs[30 * 20];
    __shared__ float y1[64 * 18];
    __shared__ float y2[64 * 16];
    __shared__ float red[4][64];
    int t = threadIdx.x;  // 256
    int b = blockIdx.x;
    for (int idx = t; idx < 600; idx += 256) xs[idx] = seq[b * 600 + idx];
    __syncthreads();
    for (int idx = t; idx < 64 * 18; idx += 256) {
        int o = idx / 18, l = idx - o * 18;
        float acc = c1b[o];
        for (int i = 0; i < 30; ++i)
#pragma unroll
            for (int k = 0; k < 3; ++k)
                acc += xs[i * 20 + l + k] * w1[o * 90 + i * 3 + k];
        float bn = (acc - m1n[o]) * rsqrtf(v1n[o] + 1e-5f) * g1n[o] + b1n[o];
        y1[idx] = leaky(bn, 0.01f);
    }
    __syncthreads();
    for (int idx = t; idx < 64 * 16; idx += 256) {
        int o = idx >> 4, l = idx & 15;
        float acc = c2b[o];
        for (int i = 0; i < 64; ++i)
#pragma unroll
            for (int k = 0; k < 3; ++k)
                acc += y1[i * 18 + l + k] * w2[o * 192 + i * 3 + k];
        float bn = (acc - m2n[o]) * rsqrtf(v2n[o] + 1e-5f) * g2n[o] + b2n[o];
        y2[idx] = leaky(bn, 0.01f);
    }
    __syncthreads();
    {
        int o = t & 63, part = t >> 6;
        float acc = 0.f;
        for (int j = part * 256; j < part * 256 + 256; ++j)
            acc += y2[j] * fcW[j * 64 + o];
        red[part][o] = acc;
    }
    __syncthreads();
    if (t < 64) sfc[b * 64 + t] = red[0][t] + red[1][t] + red[2][t] + red[3][t] + fcb[t];
}

// ---- K15: fusion + classifier -> out [B,1] f32 ----
__global__ void k_final(const float* __restrict__ pooled, const float* __restrict__ cnt,
                        const float* __restrict__ sfc,
                        const float* __restrict__ fusW, const float* __restrict__ fusb,
                        const float* __restrict__ c1W, const float* __restrict__ c1b,
                        const float* __restrict__ c3W, const float* __restrict__ c3b,
                        float* __restrict__ out) {
    __shared__ float comb[192];
    __shared__ float t1[128];
    int t = threadIdx.x;  // 128
    int b = blockIdx.x;
    float invc = 1.f / fmaxf(cnt[b], 1.f);
    comb[t] = pooled[b * 128 + t] * invc;
    if (t < 64) comb[128 + t] = sfc[b * 64 + t];
    __syncthreads();
    float acc = fusb[t];
    for (int k = 0; k < 192; ++k) acc += comb[k] * fusW[k * 128 + t];
    t1[t] = leaky(acc, 0.01f);
    __syncthreads();
    if (t < 64) {
        float a2 = c1b[t];
        for (int k = 0; k < 128; ++k) a2 += t1[k] * c1W[k * 64 + t];
        a2 = leaky(a2, 0.01f);
        float p = a2 * c3W[t];
#pragma unroll
        for (int off = 32; off; off >>= 1) p += __shfl_xor(p, off, 64);
        if (t == 0) out[b] = p + c3b[0];
    }
}

extern "C" void kernel_launch(void* const* d_in, const int* in_sizes, int n_in,
                              void* d_out, int out_size, void* d_ws, size_t ws_size,
                              hipStream_t stream) {
    const float* x     = (const float*)d_in[0];
    const int*   ei    = (const int*)d_in[1];
    const int*   batch = (const int*)d_in[2];
    const float* seq   = (const float*)d_in[3];
    const float* Wg    = (const float*)d_in[4];
    const float* attS  = (const float*)d_in[5];
    const float* attD  = (const float*)d_in[6];
    const float* bg    = (const float*)d_in[7];
    const float* W2    = (const float*)d_in[8];
    const float* b2    = (const float*)d_in[9];
    const float* W3    = (const float*)d_in[10];
    const float* b3    = (const float*)d_in[11];
    const float* c1w   = (const float*)d_in[12];
    const float* c1bb  = (const float*)d_in[13];
    const float* c2w   = (const float*)d_in[14];
    const float* c2bb  = (const float*)d_in[15];
    const float* bn1g  = (const float*)d_in[16];
    const float* bn1b  = (const float*)d_in[17];
    const float* bn1m  = (const float*)d_in[18];
    const float* bn1v  = (const float*)d_in[19];
    const float* bn2g  = (const float*)d_in[20];
    const float* bn2b  = (const float*)d_in[21];
    const float* bn2m  = (const float*)d_in[22];
    const float* bn2v  = (const float*)d_in[23];
    const float* fcW   = (const float*)d_in[24];
    const float* fcb   = (const float*)d_in[25];
    const float* fusW  = (const float*)d_in[26];
    const float* fusb  = (const float*)d_in[27];
    const float* cls1W = (const float*)d_in[28];
    const float* cls1b = (const float*)d_in[29];
    const float* cls3W = (const float*)d_in[30];
    const float* cls3b = (const float*)d_in[31];

    // ---- workspace arena (element offsets, all float4-aligned) ----
    char* wsb = (char*)d_ws;
    const size_t N = NND;
    float*    M      = (float*)wsb;                                  // 80
    float*    a_s    = M + 80;                                       // N*4
    float*    a_d    = a_s + N * 4;                                  // N*4
    float*    inv_s  = a_d + N * 4;                                  // N*4
    float*    dinv   = inv_s + N * 4;                                // N
    unsigned* deg    = (unsigned*)(dinv + N);                        // N+4   } zero block
    float*    pooled = (float*)(deg + N + 4);                        // B*128 }
    float*    cnt    = pooled + (size_t)NB * 128;                    // B     }
    unsigned* rowptr = (unsigned*)(cnt + NB);                        // N+4
    unsigned* cursor = rowptr + N + 4;                               // N
    unsigned* csr    = cursor + N;                                   // NED
    float*    gA     = (float*)(csr + NED);                          // N*128 (g1 -> g3)
    float*    B1     = gA + N * 128;                                 // N*64  (z, h2 -> agg3)
    float*    g2     = B1 + N * 64;                                  // N*64
    float*    sfc    = g2 + N * 64;                                  // B*64
    float*    z      = B1;                                           // alias: z dead before h2 written

    size_t zero_bytes = ((N + 4) + (size_t)NB * 128 + NB) * 4;
    hipMemsetAsync(deg, 0, zero_bytes, stream);

    k_matt<<<1, 128, 0, stream>>>(Wg, attS, attD, M);
    k_att<<<(NND + 255) / 256, 256, 0, stream>>>(x, M, a_s, a_d);
    k_deg<<<(NED + 255) / 256, 256, 0, stream>>>(ei, deg);
    k_scan<<<1, 1024, 0, stream>>>(deg, rowptr, cursor);
    k_fill<<<(NED + 255) / 256, 256, 0, stream>>>(ei, cursor, csr);
    k_denom<<<(NND + 255) / 256, 256, 0, stream>>>(rowptr, csr, a_s, a_d, inv_s, dinv);
    k_gat_g<<<NND / 4, 256, 0, stream>>>(rowptr, csr, x, a_s, a_d, inv_s, z);
    k_gat_out<<<(NND + 63) / 64, 128, 0, stream>>>(z, Wg, bg, gA);
    k_gemm_h2<<<NND / 32, 256, 0, stream>>>(gA, W2, B1);
    k_gcn_g<true><<<NND / 4, 256, 0, stream>>>(rowptr, csr, dinv, B1, b2, g2);
    k_gcn_g<false><<<NND / 4, 256, 0, stream>>>(rowptr, csr, dinv, g2, b2, B1);
    k_gcn2_out<<<NND / 32, 256, 0, stream>>>(B1, W3, b3, gA);
    k_pool<<<(NND + 63) / 64, 128, 0, stream>>>(gA, batch, pooled, cnt);
    k_seq<<<NB, 256, 0, stream>>>(seq, c1w, c1bb, c2w, c2bb, bn1g, bn1b, bn1m, bn1v,
                                  bn2g, bn2b, bn2m, bn2v, fcW, fcb, sfc);
    k_final<<<NB, 128, 0, stream>>>(pooled, cnt, sfc, fusW, fusb, cls1W, cls1b,
                                    cls3W, cls3b, (float*)d_out);
}

// Round 4
// 1073.438 us; speedup vs baseline: 1.9568x; 1.1988x over previous
//
#include <hip/hip_runtime.h>

#define NND 100000
#define NED 1600000
#define NB  1024
#define FEAT 9
#define HC 128
#define SCAN_NBLK ((NND + 255) / 256)   // 391

__device__ __forceinline__ void atomAdd(float* p, float v) {
    __hip_atomic_fetch_add(p, v, __ATOMIC_RELAXED, __HIP_MEMORY_SCOPE_AGENT);
}
__device__ __forceinline__ unsigned atomAddU(unsigned* p, unsigned v) {
    return __hip_atomic_fetch_add(p, v, __ATOMIC_RELAXED, __HIP_MEMORY_SCOPE_AGENT);
}
__device__ __forceinline__ float leaky(float v, float s) { return v >= 0.f ? v : s * v; }

// ---- K1: M_s[f,h] = sum_c Wg[f,h*32+c]*attS[h,c]; same for M_d (one block) ----
__global__ void k_matt(const float* __restrict__ Wg, const float* __restrict__ attS,
                       const float* __restrict__ attD, float* __restrict__ M) {
    int t = threadIdx.x;  // 128, use 72
    if (t >= 72) return;
    int d = t >= 36 ? 1 : 0;
    int q = t - 36 * d;
    int f = q >> 2, h = q & 3;
    const float* av = d ? attD : attS;
    float s = 0.f;
#pragma unroll
    for (int c = 0; c < 32; ++c) s += Wg[f * HC + h * 32 + c] * av[h * 32 + c];
    M[d * 36 + q] = s;
}

// ---- K2: a_s = x @ M_s, a_d = x @ M_d (thread per node) ----
__global__ void k_att(const float* __restrict__ x, const float* __restrict__ M,
                      float* __restrict__ a_s, float* __restrict__ a_d) {
    __shared__ float Ms[36], Md[36];
    int t = threadIdx.x;  // 256
    if (t < 36) Ms[t] = M[t];
    else if (t < 72) Md[t - 36] = M[t];
    __syncthreads();
    int n = blockIdx.x * 256 + t;
    if (n >= NND) return;
    float xv[FEAT];
#pragma unroll
    for (int f = 0; f < FEAT; ++f) xv[f] = x[n * FEAT + f];
    float s0 = 0, s1 = 0, s2 = 0, s3 = 0, d0 = 0, d1 = 0, d2 = 0, d3 = 0;
#pragma unroll
    for (int f = 0; f < FEAT; ++f) {
        float xf = xv[f];
        s0 += xf * Ms[f * 4 + 0]; s1 += xf * Ms[f * 4 + 1];
        s2 += xf * Ms[f * 4 + 2]; s3 += xf * Ms[f * 4 + 3];
        d0 += xf * Md[f * 4 + 0]; d1 += xf * Md[f * 4 + 1];
        d2 += xf * Md[f * 4 + 2]; d3 += xf * Md[f * 4 + 3];
    }
    ((float4*)a_s)[n] = make_float4(s0, s1, s2, s3);
    ((float4*)a_d)[n] = make_float4(d0, d1, d2, d3);
}

// ---- K3: in-degree histogram (real edges only) ----
__global__ void k_deg(const int* __restrict__ ei, unsigned* __restrict__ deg) {
    int e = blockIdx.x * 256 + threadIdx.x;
    if (e < NED) atomAddU(&deg[ei[NED + e]], 1u);
}

// ---- K4a: per-block sums of deg ----
__global__ void k_scanA(const unsigned* __restrict__ deg, unsigned* __restrict__ bsum) {
    __shared__ unsigned s[256];
    int t = threadIdx.x;
    int i = blockIdx.x * 256 + t;
    s[t] = (i < NND) ? deg[i] : 0u;
    __syncthreads();
    for (int off = 128; off; off >>= 1) {
        if (t < off) s[t] += s[t + off];
        __syncthreads();
    }
    if (t == 0) bsum[blockIdx.x] = s[0];
}

// ---- K4b: exclusive scan of 391 block sums (single block, 512 thr) ----
__global__ void k_scanB(const unsigned* __restrict__ bsum, unsigned* __restrict__ boff) {
    __shared__ unsigned s[512];
    int t = threadIdx.x;
    s[t] = (t < SCAN_NBLK) ? bsum[t] : 0u;
    __syncthreads();
    for (int off = 1; off < 512; off <<= 1) {
        unsigned v = (t >= off) ? s[t - off] : 0u;
        __syncthreads();
        s[t] += v;
        __syncthreads();
    }
    if (t < SCAN_NBLK) boff[t] = (t == 0) ? 0u : s[t - 1];
}

// ---- K4c: intra-block exclusive scan + offset -> rowptr, cursor ----
__global__ void k_scanC(const unsigned* __restrict__ deg, const unsigned* __restrict__ boff,
                        unsigned* __restrict__ rowptr, unsigned* __restrict__ cursor) {
    __shared__ unsigned s[256];
    int t = threadIdx.x;
    int i = blockIdx.x * 256 + t;
    unsigned v = (i < NND) ? deg[i] : 0u;
    s[t] = v;
    __syncthreads();
    for (int off = 1; off < 256; off <<= 1) {
        unsigned u = (t >= off) ? s[t - off] : 0u;
        __syncthreads();
        s[t] += u;
        __syncthreads();
    }
    unsigned excl = boff[blockIdx.x] + s[t] - v;
    if (i < NND) { rowptr[i] = excl; cursor[i] = excl; }
    if (i == NND - 1) rowptr[NND] = excl + v;
}

// ---- K5: fill CSR (counting sort by dst) ----
__global__ void k_fill(const int* __restrict__ ei, unsigned* __restrict__ cursor,
                       unsigned* __restrict__ csr) {
    int e = blockIdx.x * 256 + threadIdx.x;
    if (e >= NED) return;
    int src = ei[e], dst = ei[NED + e];
    unsigned pos = atomAddU(&cursor[dst], 1u);
    csr[pos] = (unsigned)src;
}

// ---- K6: softmax denominators (gather) + dinv (thread per node) ----
__global__ void k_denom(const unsigned* __restrict__ rowptr, const unsigned* __restrict__ csr,
                        const float* __restrict__ a_s, const float* __restrict__ a_d,
                        float* __restrict__ inv_s, float* __restrict__ dinv) {
    int n = blockIdx.x * 256 + threadIdx.x;
    if (n >= NND) return;
    unsigned e0 = rowptr[n], e1 = rowptr[n + 1];
    float4 ad = ((const float4*)a_d)[n];
    float4 as = ((const float4*)a_s)[n];
    float s0 = __expf(leaky(as.x + ad.x, 0.2f));
    float s1 = __expf(leaky(as.y + ad.y, 0.2f));
    float s2 = __expf(leaky(as.z + ad.z, 0.2f));
    float s3 = __expf(leaky(as.w + ad.w, 0.2f));
    for (unsigned e = e0; e < e1; ++e) {
        float4 a = ((const float4*)a_s)[csr[e]];
        s0 += __expf(leaky(a.x + ad.x, 0.2f));
        s1 += __expf(leaky(a.y + ad.y, 0.2f));
        s2 += __expf(leaky(a.z + ad.z, 0.2f));
        s3 += __expf(leaky(a.w + ad.w, 0.2f));
    }
    ((float4*)inv_s)[n] = make_float4(1.f / (s0 + 1e-16f), 1.f / (s1 + 1e-16f),
                                      1.f / (s2 + 1e-16f), 1.f / (s3 + 1e-16f));
    dinv[n] = rsqrtf((float)(e1 - e0) + 1.f);
}

// ---- K7: GAT x-space aggregation (gather; wave per node, lanes 0..35) ----
__global__ void k_gat_g(const unsigned* __restrict__ rowptr, const unsigned* __restrict__ csr,
                        const float* __restrict__ x, const float* __restrict__ a_s,
                        const float* __restrict__ a_d, const float* __restrict__ inv_s,
                        float* __restrict__ z) {
    int n = blockIdx.x * 4 + (threadIdx.x >> 6);  // grid 25000 x 256 exact
    int lane = threadIdx.x & 63;
    bool active = lane < 36;
    int h = active ? lane / 9 : 0;
    int f = active ? lane - h * 9 : 0;
    unsigned e0 = rowptr[n], e1 = rowptr[n + 1];
    float adh = a_d[n * 4 + h];
    float ivh = inv_s[n * 4 + h];
    float acc = __expf(leaky(a_s[n * 4 + h] + adh, 0.2f)) * ivh * x[n * FEAT + f];
    for (unsigned e = e0; e < e1; ++e) {
        int src = (int)csr[e];
        float alpha = __expf(leaky(a_s[src * 4 + h] + adh, 0.2f)) * ivh;
        acc += alpha * x[src * FEAT + f];
    }
    if (active) z[n * 36 + lane] = acc;
}

// ---- K8: g1 = leaky(z @ W_head + b_gat) ----
__global__ void k_gat_out(const float* __restrict__ z, const float* __restrict__ Wg,
                          const float* __restrict__ bg, float* __restrict__ g1) {
    __shared__ float Wf[FEAT * HC];
    __shared__ float zs[36];
    int t = threadIdx.x;  // 128
    for (int f = 0; f < FEAT; ++f) Wf[f * HC + t] = Wg[f * HC + t];
    float bias = bg[t];
    int h = t >> 5;
    int i0 = blockIdx.x * 64;
    for (int n = 0; n < 64; ++n) {
        int i = i0 + n;
        if (i >= NND) break;
        __syncthreads();
        if (t < 36) zs[t] = z[i * 36 + t];
        __syncthreads();
        float acc = bias;
#pragma unroll
        for (int f = 0; f < FEAT; ++f) acc += zs[h * 9 + f] * Wf[f * HC + t];
        g1[i * HC + t] = leaky(acc, 0.01f);
    }
}

// ---- K9: h2 = g1 @ W2  (N x 128 @ 128 x 64) ----
__global__ void k_gemm_h2(const float* __restrict__ g1, const float* __restrict__ W2,
                          float* __restrict__ h2) {
    __shared__ float Wf[128 * 64];
    __shared__ float rws[4][128];
    int t = threadIdx.x;  // 256
#pragma unroll
    for (int j = 0; j < 32; ++j) Wf[t + j * 256] = W2[t + j * 256];
    int rbase0 = blockIdx.x * 32;
    int sub = t >> 6, col = t & 63;
    for (int p = 0; p < 8; ++p) {
        int rbase = rbase0 + p * 4;
        __syncthreads();
        { int lr = t >> 7, k = t & 127;        rws[lr][k] = g1[(rbase + lr) * 128 + k]; }
        { int i2 = t + 256; int lr = i2 >> 7, k = i2 & 127; rws[lr][k] = g1[(rbase + lr) * 128 + k]; }
        __syncthreads();
        float acc = 0.f;
#pragma unroll
        for (int k = 0; k < 128; ++k) acc += rws[sub][k] * Wf[k * 64 + col];
        h2[(rbase + sub) * 64 + col] = acc;
    }
}

// ---- K10/K11: GCN aggregation (gather; wave per node, 64 ch) ----
template <bool ACT>
__global__ void k_gcn_g(const unsigned* __restrict__ rowptr, const unsigned* __restrict__ csr,
                        const float* __restrict__ dinv, const float* __restrict__ hin,
                        const float* __restrict__ bias, float* __restrict__ hout) {
    int n = blockIdx.x * 4 + (threadIdx.x >> 6);  // grid 25000 x 256 exact
    int lane = threadIdx.x & 63;
    unsigned e0 = rowptr[n], e1 = rowptr[n + 1];
    float dn = dinv[n];
    float acc = dn * hin[n * 64 + lane];  // self term (dinv[n]^2 after outer mult)
    for (unsigned e = e0; e < e1; ++e) {
        int src = (int)csr[e];
        acc += dinv[src] * hin[src * 64 + lane];
    }
    float out = dn * acc;
    if (ACT) out = leaky(out + bias[lane], 0.01f);
    hout[n * 64 + lane] = out;
}

// ---- K12: g3 = leaky(agg3 @ W3 + b3)  (N x 64 @ 64 x 128) ----
__global__ void k_gcn2_out(const float* __restrict__ agg3, const float* __restrict__ W3,
                           const float* __restrict__ b3, float* __restrict__ g3) {
    __shared__ float Wf[64 * 128];
    __shared__ float rws[2][64];
    int t = threadIdx.x;  // 256
#pragma unroll
    for (int j = 0; j < 32; ++j) Wf[t + j * 256] = W3[t + j * 256];
    int col = t & 127, sub = t >> 7;
    float bias = b3[col];
    int rbase0 = blockIdx.x * 32;
    for (int p = 0; p < 16; ++p) {
        int rbase = rbase0 + p * 2;
        __syncthreads();
        if (t < 128) {
            int lr = t >> 6, k = t & 63;
            rws[lr][k] = agg3[(rbase + lr) * 64 + k];
        }
        __syncthreads();
        float acc = bias;
#pragma unroll
        for (int k = 0; k < 64; ++k) acc += rws[sub][k] * Wf[k * 128 + col];
        g3[(rbase + sub) * 128 + col] = leaky(acc, 0.01f);
    }
}

// ---- K13: mean-pool using SORTED batch: run-local accumulation, flush on change ----
__global__ void k_pool(const float* __restrict__ g3, const int* __restrict__ batch,
                       float* __restrict__ pooled, float* __restrict__ cnt) {
    int t = threadIdx.x;  // 128
    int n0 = blockIdx.x * 64;
    int n1 = n0 + 64; if (n1 > NND) n1 = NND;
    float acc = 0.f;
    int cur = batch[n0];
    int runStart = n0;
    for (int i = n0; i < n1; ++i) {
        int b = batch[i];
        if (b != cur) {
            atomAdd(&pooled[cur * 128 + t], acc);
            if (t == 0) atomAdd(&cnt[cur], (float)(i - runStart));
            acc = 0.f; cur = b; runStart = i;
        }
        acc += g3[i * 128 + t];
    }
    atomAdd(&pooled[cur * 128 + t], acc);
    if (t == 0) atomAdd(&cnt[cur], (float)(n1 - runStart));
}

// ---- K14: fused sequence branch -> sfc [B,64] ----
__global__ void k_seq(const float* __restrict__ seq, const float* __restrict__ w1, const float* __restrict__ c1b,
                      const float* __restrict__ w2, const float* __restrict__ c2b,
                      const float* __restrict__ g1n, const float* __restrict__ b1n,
                      const float* __restrict__ m1n, const float* __restrict__ v1n,
                      const float* __restrict__ g2n, const float* __restrict__ b2n,
                      const float* __restrict__ m2n, const float* __restrict__ v2n,
                      const float* __restrict__ fcW, const float* __restrict__ fcb,
                      float* __restrict__ sfc) {
    __shared__ float xs[30 * 20];
    __shared__ float y1[64 * 18];
    __shared__ float y2[64 * 16];
    __shared__ float red[4][64];
    int t = threadIdx.x;  // 256
    int b = blockIdx.x;
    for (int idx = t; idx < 600; idx += 256) xs[idx] = seq[b * 600 + idx];
    __syncthreads();
    for (int idx = t; idx < 64 * 18; idx += 256) {
        int o = idx / 18, l = idx - o * 18;
        float acc = c1b[o];
        for (int i = 0; i < 30; ++i)
#pragma unroll
            for (int k = 0; k < 3; ++k)
                acc += xs[i * 20 + l + k] * w1[o * 90 + i * 3 + k];
        float bn = (acc - m1n[o]) * rsqrtf(v1n[o] + 1e-5f) * g1n[o] + b1n[o];
        y1[idx] = leaky(bn, 0.01f);
    }
    __syncthreads();
    for (int idx = t; idx < 64 * 16; idx += 256) {
        int o = idx >> 4, l = idx & 15;
        float acc = c2b[o];
        for (int i = 0; i < 64; ++i)
#pragma unroll
            for (int k = 0; k < 3; ++k)
                acc += y1[i * 18 + l + k] * w2[o * 192 + i * 3 + k];
        float bn = (acc - m2n[o]) * rsqrtf(v2n[o] + 1e-5f) * g2n[o] + b2n[o];
        y2[idx] = leaky(bn, 0.01f);
    }
    __syncthreads();
    {
        int o = t & 63, part = t >> 6;
        float acc = 0.f;
        for (int j = part * 256; j < part * 256 + 256; ++j)
            acc += y2[j] * fcW[j * 64 + o];
        red[part][o] = acc;
    }
    __syncthreads();
    if (t < 64) sfc[b * 64 + t] = red[0][t] + red[1][t] + red[2][t] + red[3][t] + fcb[t];
}

// ---- K15: fusion + classifier -> out [B,1] f32 ----
__global__ void k_final(const float* __restrict__ pooled, const float* __restrict__ cnt,
                        const float* __restrict__ sfc,
                        const float* __restrict__ fusW, const float* __restrict__ fusb,
                        const float* __restrict__ c1W, const float* __restrict__ c1b,
                        const float* __restrict__ c3W, const float* __restrict__ c3b,
                        float* __restrict__ out) {
    __shared__ float comb[192];
    __shared__ float t1[128];
    int t = threadIdx.x;  // 128
    int b = blockIdx.x;
    float invc = 1.f / fmaxf(cnt[b], 1.f);
    comb[t] = pooled[b * 128 + t] * invc;
    if (t < 64) comb[128 + t] = sfc[b * 64 + t];
    __syncthreads();
    float acc = fusb[t];
    for (int k = 0; k < 192; ++k) acc += comb[k] * fusW[k * 128 + t];
    t1[t] = leaky(acc, 0.01f);
    __syncthreads();
    if (t < 64) {
        float a2 = c1b[t];
        for (int k = 0; k < 128; ++k) a2 += t1[k] * c1W[k * 64 + t];
        a2 = leaky(a2, 0.01f);
        float p = a2 * c3W[t];
#pragma unroll
        for (int off = 32; off; off >>= 1) p += __shfl_xor(p, off, 64);
        if (t == 0) out[b] = p + c3b[0];
    }
}

extern "C" void kernel_launch(void* const* d_in, const int* in_sizes, int n_in,
                              void* d_out, int out_size, void* d_ws, size_t ws_size,
                              hipStream_t stream) {
    const float* x     = (const float*)d_in[0];
    const int*   ei    = (const int*)d_in[1];
    const int*   batch = (const int*)d_in[2];
    const float* seq   = (const float*)d_in[3];
    const float* Wg    = (const float*)d_in[4];
    const float* attS  = (const float*)d_in[5];
    const float* attD  = (const float*)d_in[6];
    const float* bg    = (const float*)d_in[7];
    const float* W2    = (const float*)d_in[8];
    const float* b2    = (const float*)d_in[9];
    const float* W3    = (const float*)d_in[10];
    const float* b3    = (const float*)d_in[11];
    const float* c1w   = (const float*)d_in[12];
    const float* c1bb  = (const float*)d_in[13];
    const float* c2w   = (const float*)d_in[14];
    const float* c2bb  = (const float*)d_in[15];
    const float* bn1g  = (const float*)d_in[16];
    const float* bn1b  = (const float*)d_in[17];
    const float* bn1m  = (const float*)d_in[18];
    const float* bn1v  = (const float*)d_in[19];
    const float* bn2g  = (const float*)d_in[20];
    const float* bn2b  = (const float*)d_in[21];
    const float* bn2m  = (const float*)d_in[22];
    const float* bn2v  = (const float*)d_in[23];
    const float* fcW   = (const float*)d_in[24];
    const float* fcb   = (const float*)d_in[25];
    const float* fusW  = (const float*)d_in[26];
    const float* fusb  = (const float*)d_in[27];
    const float* cls1W = (const float*)d_in[28];
    const float* cls1b = (const float*)d_in[29];
    const float* cls3W = (const float*)d_in[30];
    const float* cls3b = (const float*)d_in[31];

    // ---- workspace arena (element offsets, all float4-aligned) ----
    char* wsb = (char*)d_ws;
    const size_t N = NND;
    float*    M      = (float*)wsb;                                  // 80
    float*    a_s    = M + 80;                                       // N*4
    float*    a_d    = a_s + N * 4;                                  // N*4
    float*    inv_s  = a_d + N * 4;                                  // N*4
    float*    dinv   = inv_s + N * 4;                                // N
    unsigned* deg    = (unsigned*)(dinv + N);                        // N+4   } zero block
    float*    pooled = (float*)(deg + N + 4);                        // B*128 }
    float*    cnt    = pooled + (size_t)NB * 128;                    // B     }
    unsigned* rowptr = (unsigned*)(cnt + NB);                        // N+4
    unsigned* cursor = rowptr + N + 4;                               // N
    unsigned* bsum   = cursor + N;                                   // 512
    unsigned* boff   = bsum + 512;                                   // 512
    unsigned* csr    = boff + 512;                                   // NED
    float*    gA     = (float*)(csr + NED);                          // N*128 (g1 -> g3)
    float*    B1     = gA + N * 128;                                 // N*64  (z, h2 -> agg3)
    float*    g2     = B1 + N * 64;                                  // N*64
    float*    sfc    = g2 + N * 64;                                  // B*64
    float*    z      = B1;                                           // alias: z dead before h2 written

    size_t zero_bytes = ((N + 4) + (size_t)NB * 128 + NB) * 4;
    hipMemsetAsync(deg, 0, zero_bytes, stream);

    k_matt<<<1, 128, 0, stream>>>(Wg, attS, attD, M);
    k_att<<<(NND + 255) / 256, 256, 0, stream>>>(x, M, a_s, a_d);
    k_deg<<<(NED + 255) / 256, 256, 0, stream>>>(ei, deg);
    k_scanA<<<SCAN_NBLK, 256, 0, stream>>>(deg, bsum);
    k_scanB<<<1, 512, 0, stream>>>(bsum, boff);
    k_scanC<<<SCAN_NBLK, 256, 0, stream>>>(deg, boff, rowptr, cursor);
    k_fill<<<(NED + 255) / 256, 256, 0, stream>>>(ei, cursor, csr);
    k_denom<<<(NND + 255) / 256, 256, 0, stream>>>(rowptr, csr, a_s, a_d, inv_s, dinv);
    k_gat_g<<<NND / 4, 256, 0, stream>>>(rowptr, csr, x, a_s, a_d, inv_s, z);
    k_gat_out<<<(NND + 63) / 64, 128, 0, stream>>>(z, Wg, bg, gA);
    k_gemm_h2<<<NND / 32, 256, 0, stream>>>(gA, W2, B1);
    k_gcn_g<true><<<NND / 4, 256, 0, stream>>>(rowptr, csr, dinv, B1, b2, g2);
    k_gcn_g<false><<<NND / 4, 256, 0, stream>>>(rowptr, csr, dinv, g2, b2, B1);
    k_gcn2_out<<<NND / 32, 256, 0, stream>>>(B1, W3, b3, gA);
    k_pool<<<(NND + 63) / 64, 128, 0, stream>>>(gA, batch, pooled, cnt);
    k_seq<<<NB, 256, 0, stream>>>(seq, c1w, c1bb, c2w, c2bb, bn1g, bn1b, bn1m, bn1v,
                                  bn2g, bn2b, bn2m, bn2v, fcW, fcb, sfc);
    k_final<<<NB, 128, 0, stream>>>(pooled, cnt, sfc, fusW, fusb, cls1W, cls1b,
                                    cls3W, cls3b, (float*)d_out);
}

// Round 5
// 805.807 us; speedup vs baseline: 2.6067x; 1.3321x over previous
//
#include <hip/hip_runtime.h>

#define NND 100000
#define NED 1600000
#define NB  1024
#define FEAT 9
#define HC 128
#define SCAN_NBLK ((NND + 255) / 256)   // 391

typedef unsigned short u16;

__device__ __forceinline__ void atomAdd(float* p, float v) {
    __hip_atomic_fetch_add(p, v, __ATOMIC_RELAXED, __HIP_MEMORY_SCOPE_AGENT);
}
__device__ __forceinline__ unsigned atomAddU(unsigned* p, unsigned v) {
    return __hip_atomic_fetch_add(p, v, __ATOMIC_RELAXED, __HIP_MEMORY_SCOPE_AGENT);
}
__device__ __forceinline__ float leaky(float v, float s) { return v >= 0.f ? v : s * v; }
__device__ __forceinline__ float bf2f(u16 u) {
    union { unsigned i; float f; } x; x.i = ((unsigned)u) << 16; return x.f;
}
__device__ __forceinline__ u16 f2bf(float f) {
    union { float f; unsigned i; } x; x.f = f;
    return (u16)((x.i + 0x7fffu + ((x.i >> 16) & 1u)) >> 16);
}

// ---- K1: M_s[f,h] = sum_c Wg[f,h*32+c]*attS[h,c]; same for M_d (one block) ----
__global__ void k_matt(const float* __restrict__ Wg, const float* __restrict__ attS,
                       const float* __restrict__ attD, float* __restrict__ M) {
    int t = threadIdx.x;  // 128, use 72
    if (t >= 72) return;
    int d = t >= 36 ? 1 : 0;
    int q = t - 36 * d;
    int f = q >> 2, h = q & 3;
    const float* av = d ? attD : attS;
    float s = 0.f;
#pragma unroll
    for (int c = 0; c < 32; ++c) s += Wg[f * HC + h * 32 + c] * av[h * 32 + c];
    M[d * 36 + q] = s;
}

// ---- K2: per-node 64B gather record rec = {x[9], a_s[4], pad} + a_d ----
__global__ void k_att(const float* __restrict__ x, const float* __restrict__ M,
                      float* __restrict__ rec, float* __restrict__ a_d) {
    __shared__ float Ms[36], Md[36];
    int t = threadIdx.x;  // 256
    if (t < 36) Ms[t] = M[t];
    else if (t < 72) Md[t - 36] = M[t];
    __syncthreads();
    int n = blockIdx.x * 256 + t;
    if (n >= NND) return;
    float xv[FEAT];
#pragma unroll
    for (int f = 0; f < FEAT; ++f) xv[f] = x[n * FEAT + f];
    float s0 = 0, s1 = 0, s2 = 0, s3 = 0, d0 = 0, d1 = 0, d2 = 0, d3 = 0;
#pragma unroll
    for (int f = 0; f < FEAT; ++f) {
        float xf = xv[f];
        s0 += xf * Ms[f * 4 + 0]; s1 += xf * Ms[f * 4 + 1];
        s2 += xf * Ms[f * 4 + 2]; s3 += xf * Ms[f * 4 + 3];
        d0 += xf * Md[f * 4 + 0]; d1 += xf * Md[f * 4 + 1];
        d2 += xf * Md[f * 4 + 2]; d3 += xf * Md[f * 4 + 3];
    }
    float4* rp = (float4*)(rec + (size_t)n * 16);
    rp[0] = make_float4(xv[0], xv[1], xv[2], xv[3]);
    rp[1] = make_float4(xv[4], xv[5], xv[6], xv[7]);
    rp[2] = make_float4(xv[8], s0, s1, s2);
    rp[3] = make_float4(s3, 0.f, 0.f, 0.f);
    ((float4*)a_d)[n] = make_float4(d0, d1, d2, d3);
}

// ---- K3: in-degree histogram (real edges only) ----
__global__ void k_deg(const int* __restrict__ ei, unsigned* __restrict__ deg) {
    int e = blockIdx.x * 256 + threadIdx.x;
    if (e < NED) atomAddU(&deg[ei[NED + e]], 1u);
}

// ---- K4a: per-block sums of deg ----
__global__ void k_scanA(const unsigned* __restrict__ deg, unsigned* __restrict__ bsum) {
    __shared__ unsigned s[256];
    int t = threadIdx.x;
    int i = blockIdx.x * 256 + t;
    s[t] = (i < NND) ? deg[i] : 0u;
    __syncthreads();
    for (int off = 128; off; off >>= 1) {
        if (t < off) s[t] += s[t + off];
        __syncthreads();
    }
    if (t == 0) bsum[blockIdx.x] = s[0];
}

// ---- K4b: exclusive scan of 391 block sums (single block, 512 thr) ----
__global__ void k_scanB(const unsigned* __restrict__ bsum, unsigned* __restrict__ boff) {
    __shared__ unsigned s[512];
    int t = threadIdx.x;
    s[t] = (t < SCAN_NBLK) ? bsum[t] : 0u;
    __syncthreads();
    for (int off = 1; off < 512; off <<= 1) {
        unsigned v = (t >= off) ? s[t - off] : 0u;
        __syncthreads();
        s[t] += v;
        __syncthreads();
    }
    if (t < SCAN_NBLK) boff[t] = (t == 0) ? 0u : s[t - 1];
}

// ---- K4c: intra-block exclusive scan + offset -> rowptr, cursor, dinv ----
__global__ void k_scanC(const unsigned* __restrict__ deg, const unsigned* __restrict__ boff,
                        unsigned* __restrict__ rowptr, unsigned* __restrict__ cursor,
                        float* __restrict__ dinv) {
    __shared__ unsigned s[256];
    int t = threadIdx.x;
    int i = blockIdx.x * 256 + t;
    unsigned v = (i < NND) ? deg[i] : 0u;
    s[t] = v;
    __syncthreads();
    for (int off = 1; off < 256; off <<= 1) {
        unsigned u = (t >= off) ? s[t - off] : 0u;
        __syncthreads();
        s[t] += u;
        __syncthreads();
    }
    unsigned excl = boff[blockIdx.x] + s[t] - v;
    if (i < NND) {
        rowptr[i] = excl; cursor[i] = excl;
        dinv[i] = rsqrtf((float)v + 1.f);
    }
    if (i == NND - 1) rowptr[NND] = excl + v;
}

// ---- K5: fill CSR (counting sort by dst) ----
__global__ void k_fill(const int* __restrict__ ei, unsigned* __restrict__ cursor,
                       unsigned* __restrict__ csr) {
    int e = blockIdx.x * 256 + threadIdx.x;
    if (e >= NED) return;
    int src = ei[e], dst = ei[NED + e];
    unsigned pos = atomAddU(&cursor[dst], 1u);
    csr[pos] = (unsigned)src;
}

// ---- K7: GAT aggregation + fused softmax denom (wave per node, lanes 0..35) ----
__global__ void k_gat_g(const unsigned* __restrict__ rowptr, const unsigned* __restrict__ csr,
                        const float* __restrict__ rec, const float* __restrict__ a_d,
                        float* __restrict__ z) {
    int n = blockIdx.x * 4 + (threadIdx.x >> 6);  // grid 25000 x 256 exact
    int lane = threadIdx.x & 63;
    bool active = lane < 36;
    if (!active) return;
    int h = lane / 9, f = lane - h * 9;
    unsigned e0 = rowptr[n], e1 = rowptr[n + 1];
    float adh = a_d[n * 4 + h];
    // self loop
    float ws = __expf(leaky(rec[(size_t)n * 16 + 9 + h] + adh, 0.2f));
    float acc = ws * rec[(size_t)n * 16 + f];
    float den = ws;
    unsigned e = e0;
    for (; e + 4 <= e1; e += 4) {
        size_t s0 = csr[e] * 16u, s1 = csr[e + 1] * 16u, s2 = csr[e + 2] * 16u, s3 = csr[e + 3] * 16u;
        float a0 = rec[s0 + 9 + h], x0 = rec[s0 + f];
        float a1 = rec[s1 + 9 + h], x1 = rec[s1 + f];
        float a2 = rec[s2 + 9 + h], x2 = rec[s2 + f];
        float a3 = rec[s3 + 9 + h], x3 = rec[s3 + f];
        float w0 = __expf(leaky(a0 + adh, 0.2f));
        float w1 = __expf(leaky(a1 + adh, 0.2f));
        float w2 = __expf(leaky(a2 + adh, 0.2f));
        float w3 = __expf(leaky(a3 + adh, 0.2f));
        acc += w0 * x0 + w1 * x1 + w2 * x2 + w3 * x3;
        den += w0 + w1 + w2 + w3;
    }
    for (; e < e1; ++e) {
        size_t s = csr[e] * 16u;
        float w = __expf(leaky(rec[s + 9 + h] + adh, 0.2f));
        acc += w * rec[s + f];
        den += w;
    }
    z[n * 36 + lane] = acc / (den + 1e-16f);
}

// ---- K8: g1 = leaky(z @ W_head + b_gat) ----
__global__ void k_gat_out(const float* __restrict__ z, const float* __restrict__ Wg,
                          const float* __restrict__ bg, float* __restrict__ g1) {
    __shared__ float Wf[FEAT * HC];
    __shared__ float zs[36];
    int t = threadIdx.x;  // 128
    for (int f = 0; f < FEAT; ++f) Wf[f * HC + t] = Wg[f * HC + t];
    float bias = bg[t];
    int h = t >> 5;
    int i0 = blockIdx.x * 64;
    for (int n = 0; n < 64; ++n) {
        int i = i0 + n;
        if (i >= NND) break;
        __syncthreads();
        if (t < 36) zs[t] = z[i * 36 + t];
        __syncthreads();
        float acc = bias;
#pragma unroll
        for (int f = 0; f < FEAT; ++f) acc += zs[h * 9 + f] * Wf[f * HC + t];
        g1[i * HC + t] = leaky(acc, 0.01f);
    }
}

// ---- K9: h2 = g1 @ W2  (N x 128 @ 128 x 64), bf16 output for cheap gather ----
__global__ void k_gemm_h2(const float* __restrict__ g1, const float* __restrict__ W2,
                          u16* __restrict__ h2) {
    __shared__ float Wf[128 * 64];
    __shared__ float rws[4][128];
    int t = threadIdx.x;  // 256
#pragma unroll
    for (int j = 0; j < 32; ++j) Wf[t + j * 256] = W2[t + j * 256];
    int rbase0 = blockIdx.x * 32;
    int sub = t >> 6, col = t & 63;
    for (int p = 0; p < 8; ++p) {
        int rbase = rbase0 + p * 4;
        __syncthreads();
        { int lr = t >> 7, k = t & 127;        rws[lr][k] = g1[(rbase + lr) * 128 + k]; }
        { int i2 = t + 256; int lr = i2 >> 7, k = i2 & 127; rws[lr][k] = g1[(rbase + lr) * 128 + k]; }
        __syncthreads();
        float acc = 0.f;
#pragma unroll
        for (int k = 0; k < 128; ++k) acc += rws[sub][k] * Wf[k * 64 + col];
        h2[(rbase + sub) * 64 + col] = f2bf(acc);
    }
}

// ---- K10/K11: GCN aggregation (gather bf16; wave per node, 64 ch, 4x unroll) ----
// OUTMODE 1: out = bf16(leaky(val + bias)); OUTMODE 0: out = f32 val
template <int OUTMODE>
__global__ void k_gcn_g(const unsigned* __restrict__ rowptr, const unsigned* __restrict__ csr,
                        const float* __restrict__ dinv, const u16* __restrict__ hin,
                        const float* __restrict__ bias, void* __restrict__ hout_) {
    int n = blockIdx.x * 4 + (threadIdx.x >> 6);  // grid 25000 x 256 exact
    int lane = threadIdx.x & 63;
    unsigned e0 = rowptr[n], e1 = rowptr[n + 1];
    float dn = dinv[n];
    float acc = dn * bf2f(hin[(size_t)n * 64 + lane]);  // self term
    unsigned e = e0;
    for (; e + 4 <= e1; e += 4) {
        unsigned s0 = csr[e], s1 = csr[e + 1], s2 = csr[e + 2], s3 = csr[e + 3];
        float d0 = dinv[s0], d1 = dinv[s1], d2 = dinv[s2], d3 = dinv[s3];
        float h0 = bf2f(hin[(size_t)s0 * 64 + lane]);
        float h1 = bf2f(hin[(size_t)s1 * 64 + lane]);
        float h2 = bf2f(hin[(size_t)s2 * 64 + lane]);
        float h3 = bf2f(hin[(size_t)s3 * 64 + lane]);
        acc += d0 * h0 + d1 * h1 + d2 * h2 + d3 * h3;
    }
    for (; e < e1; ++e) {
        unsigned s = csr[e];
        acc += dinv[s] * bf2f(hin[(size_t)s * 64 + lane]);
    }
    float out = dn * acc;
    if (OUTMODE == 1) {
        out = leaky(out + bias[lane], 0.01f);
        ((u16*)hout_)[(size_t)n * 64 + lane] = f2bf(out);
    } else {
        ((float*)hout_)[(size_t)n * 64 + lane] = out;
    }
}

// ---- K12: g3 = leaky(agg3 @ W3 + b3)  (N x 64 @ 64 x 128) ----
__global__ void k_gcn2_out(const float* __restrict__ agg3, const float* __restrict__ W3,
                           const float* __restrict__ b3, float* __restrict__ g3) {
    __shared__ float Wf[64 * 128];
    __shared__ float rws[2][64];
    int t = threadIdx.x;  // 256
#pragma unroll
    for (int j = 0; j < 32; ++j) Wf[t + j * 256] = W3[t + j * 256];
    int col = t & 127, sub = t >> 7;
    float bias = b3[col];
    int rbase0 = blockIdx.x * 32;
    for (int p = 0; p < 16; ++p) {
        int rbase = rbase0 + p * 2;
        __syncthreads();
        if (t < 128) {
            int lr = t >> 6, k = t & 63;
            rws[lr][k] = agg3[(rbase + lr) * 64 + k];
        }
        __syncthreads();
        float acc = bias;
#pragma unroll
        for (int k = 0; k < 64; ++k) acc += rws[sub][k] * Wf[k * 128 + col];
        g3[(rbase + sub) * 128 + col] = leaky(acc, 0.01f);
    }
}

// ---- K13: mean-pool using SORTED batch: run-local accumulation, flush on change ----
__global__ void k_pool(const float* __restrict__ g3, const int* __restrict__ batch,
                       float* __restrict__ pooled, float* __restrict__ cnt) {
    int t = threadIdx.x;  // 128
    int n0 = blockIdx.x * 64;
    int n1 = n0 + 64; if (n1 > NND) n1 = NND;
    float acc = 0.f;
    int cur = batch[n0];
    int runStart = n0;
    for (int i = n0; i < n1; ++i) {
        int b = batch[i];
        if (b != cur) {
            atomAdd(&pooled[cur * 128 + t], acc);
            if (t == 0) atomAdd(&cnt[cur], (float)(i - runStart));
            acc = 0.f; cur = b; runStart = i;
        }
        acc += g3[i * 128 + t];
    }
    atomAdd(&pooled[cur * 128 + t], acc);
    if (t == 0) atomAdd(&cnt[cur], (float)(n1 - runStart));
}

// ---- K14: fused sequence branch -> sfc [B,64] ----
__global__ void k_seq(const float* __restrict__ seq, const float* __restrict__ w1, const float* __restrict__ c1b,
                      const float* __restrict__ w2, const float* __restrict__ c2b,
                      const float* __restrict__ g1n, const float* __restrict__ b1n,
                      const float* __restrict__ m1n, const float* __restrict__ v1n,
                      const float* __restrict__ g2n, const float* __restrict__ b2n,
                      const float* __restrict__ m2n, const float* __restrict__ v2n,
                      const float* __restrict__ fcW, const float* __restrict__ fcb,
                      float* __restrict__ sfc) {
    __shared__ float xs[30 * 20];
    __shared__ float y1[64 * 18];
    __shared__ float y2[64 * 16];
    __shared__ float red[4][64];
    int t = threadIdx.x;  // 256
    int b = blockIdx.x;
    for (int idx = t; idx < 600; idx += 256) xs[idx] = seq[b * 600 + idx];
    __syncthreads();
    for (int idx = t; idx < 64 * 18; idx += 256) {
        int o = idx / 18, l = idx - o * 18;
        float acc = c1b[o];
        for (int i = 0; i < 30; ++i)
#pragma unroll
            for (int k = 0; k < 3; ++k)
                acc += xs[i * 20 + l + k] * w1[o * 90 + i * 3 + k];
        float bn = (acc - m1n[o]) * rsqrtf(v1n[o] + 1e-5f) * g1n[o] + b1n[o];
        y1[idx] = leaky(bn, 0.01f);
    }
    __syncthreads();
    for (int idx = t; idx < 64 * 16; idx += 256) {
        int o = idx >> 4, l = idx & 15;
        float acc = c2b[o];
        for (int i = 0; i < 64; ++i)
#pragma unroll
            for (int k = 0; k < 3; ++k)
                acc += y1[i * 18 + l + k] * w2[o * 192 + i * 3 + k];
        float bn = (acc - m2n[o]) * rsqrtf(v2n[o] + 1e-5f) * g2n[o] + b2n[o];
        y2[idx] = leaky(bn, 0.01f);
    }
    __syncthreads();
    {
        int o = t & 63, part = t >> 6;
        float acc = 0.f;
        for (int j = part * 256; j < part * 256 + 256; ++j)
            acc += y2[j] * fcW[j * 64 + o];
        red[part][o] = acc;
    }
    __syncthreads();
    if (t < 64) sfc[b * 64 + t] = red[0][t] + red[1][t] + red[2][t] + red[3][t] + fcb[t];
}

// ---- K15: fusion + classifier -> out [B,1] f32 ----
__global__ void k_final(const float* __restrict__ pooled, const float* __restrict__ cnt,
                        const float* __restrict__ sfc,
                        const float* __restrict__ fusW, const float* __restrict__ fusb,
                        const float* __restrict__ c1W, const float* __restrict__ c1b,
                        const float* __restrict__ c3W, const float* __restrict__ c3b,
                        float* __restrict__ out) {
    __shared__ float comb[192];
    __shared__ float t1[128];
    int t = threadIdx.x;  // 128
    int b = blockIdx.x;
    float invc = 1.f / fmaxf(cnt[b], 1.f);
    comb[t] = pooled[b * 128 + t] * invc;
    if (t < 64) comb[128 + t] = sfc[b * 64 + t];
    __syncthreads();
    float acc = fusb[t];
    for (int k = 0; k < 192; ++k) acc += comb[k] * fusW[k * 128 + t];
    t1[t] = leaky(acc, 0.01f);
    __syncthreads();
    if (t < 64) {
        float a2 = c1b[t];
        for (int k = 0; k < 128; ++k) a2 += t1[k] * c1W[k * 64 + t];
        a2 = leaky(a2, 0.01f);
        float p = a2 * c3W[t];
#pragma unroll
        for (int off = 32; off; off >>= 1) p += __shfl_xor(p, off, 64);
        if (t == 0) out[b] = p + c3b[0];
    }
}

extern "C" void kernel_launch(void* const* d_in, const int* in_sizes, int n_in,
                              void* d_out, int out_size, void* d_ws, size_t ws_size,
                              hipStream_t stream) {
    const float* x     = (const float*)d_in[0];
    const int*   ei    = (const int*)d_in[1];
    const int*   batch = (const int*)d_in[2];
    const float* seq   = (const float*)d_in[3];
    const float* Wg    = (const float*)d_in[4];
    const float* attS  = (const float*)d_in[5];
    const float* attD  = (const float*)d_in[6];
    const float* bg    = (const float*)d_in[7];
    const float* W2    = (const float*)d_in[8];
    const float* b2    = (const float*)d_in[9];
    const float* W3    = (const float*)d_in[10];
    const float* b3    = (const float*)d_in[11];
    const float* c1w   = (const float*)d_in[12];
    const float* c1bb  = (const float*)d_in[13];
    const float* c2w   = (const float*)d_in[14];
    const float* c2bb  = (const float*)d_in[15];
    const float* bn1g  = (const float*)d_in[16];
    const float* bn1b  = (const float*)d_in[17];
    const float* bn1m  = (const float*)d_in[18];
    const float* bn1v  = (const float*)d_in[19];
    const float* bn2g  = (const float*)d_in[20];
    const float* bn2b  = (const float*)d_in[21];
    const float* bn2m  = (const float*)d_in[22];
    const float* bn2v  = (const float*)d_in[23];
    const float* fcW   = (const float*)d_in[24];
    const float* fcb   = (const float*)d_in[25];
    const float* fusW  = (const float*)d_in[26];
    const float* fusb  = (const float*)d_in[27];
    const float* cls1W = (const float*)d_in[28];
    const float* cls1b = (const float*)d_in[29];
    const float* cls3W = (const float*)d_in[30];
    const float* cls3b = (const float*)d_in[31];

    // ---- workspace arena (float element offsets; 16B alignment maintained) ----
    char* wsb = (char*)d_ws;
    const size_t N = NND;
    float*    M      = (float*)wsb;                                  // 80
    float*    a_d    = M + 80;                                       // N*4
    float*    rec    = a_d + N * 4;                                  // N*16 (x9 + a_s4 + pad3)
    float*    dinv   = rec + N * 16;                                 // N
    unsigned* deg    = (unsigned*)(dinv + N);                        // N+4   } zero block
    float*    pooled = (float*)(deg + N + 4);                        // B*128 }
    float*    cnt    = pooled + (size_t)NB * 128;                    // B     }
    unsigned* rowptr = (unsigned*)(cnt + NB);                        // N+4
    unsigned* cursor = rowptr + N + 4;                               // N
    unsigned* bsum   = cursor + N;                                   // 512
    unsigned* boff   = bsum + 512;                                   // 512
    unsigned* csr    = boff + 512;                                   // NED
    float*    gA     = (float*)(csr + NED);                          // N*128 (g1 -> g3)
    float*    agg3   = gA + N * 128;                                 // N*64 f32 (aliases z)
    u16*      h2b    = (u16*)(agg3 + N * 64);                        // N*64 bf16
    u16*      g2b    = h2b + N * 64;                                 // N*64 bf16
    float*    sfc    = (float*)(g2b + N * 64);                       // B*64
    float*    z      = agg3;                                         // z dead before agg3 written

    size_t zero_bytes = ((N + 4) + (size_t)NB * 128 + NB) * 4;
    hipMemsetAsync(deg, 0, zero_bytes, stream);

    k_matt<<<1, 128, 0, stream>>>(Wg, attS, attD, M);
    k_att<<<(NND + 255) / 256, 256, 0, stream>>>(x, M, rec, a_d);
    k_deg<<<(NED + 255) / 256, 256, 0, stream>>>(ei, deg);
    k_scanA<<<SCAN_NBLK, 256, 0, stream>>>(deg, bsum);
    k_scanB<<<1, 512, 0, stream>>>(bsum, boff);
    k_scanC<<<SCAN_NBLK, 256, 0, stream>>>(deg, boff, rowptr, cursor, dinv);
    k_fill<<<(NED + 255) / 256, 256, 0, stream>>>(ei, cursor, csr);
    k_gat_g<<<NND / 4, 256, 0, stream>>>(rowptr, csr, rec, a_d, z);
    k_gat_out<<<(NND + 63) / 64, 128, 0, stream>>>(z, Wg, bg, gA);
    k_gemm_h2<<<NND / 32, 256, 0, stream>>>(gA, W2, h2b);
    k_gcn_g<1><<<NND / 4, 256, 0, stream>>>(rowptr, csr, dinv, h2b, b2, (void*)g2b);
    k_gcn_g<0><<<NND / 4, 256, 0, stream>>>(rowptr, csr, dinv, g2b, b2, (void*)agg3);
    k_gcn2_out<<<NND / 32, 256, 0, stream>>>(agg3, W3, b3, gA);
    k_pool<<<(NND + 63) / 64, 128, 0, stream>>>(gA, batch, pooled, cnt);
    k_seq<<<NB, 256, 0, stream>>>(seq, c1w, c1bb, c2w, c2bb, bn1g, bn1b, bn1m, bn1v,
                                  bn2g, bn2b, bn2m, bn2v, fcW, fcb, sfc);
    k_final<<<NB, 128, 0, stream>>>(pooled, cnt, sfc, fusW, fusb, cls1W, cls1b,
                                    cls3W, cls3b, (float*)d_out);
}

// Round 6
// 779.313 us; speedup vs baseline: 2.6953x; 1.0340x over previous
//
#include <hip/hip_runtime.h>

#define NND 100000
#define NED 1600000
#define NB  1024
#define FEAT 9
#define HC 128
#define SCAN_NBLK ((NND + 255) / 256)        // 391
#define NBUCK ((NND + 511) / 512)            // 196 buckets of 512 nodes
#define BINCHUNK 4096
#define BIN_NBLK ((NED + BINCHUNK - 1) / BINCHUNK)  // 391

typedef unsigned short u16;

__device__ __forceinline__ void atomAdd(float* p, float v) {
    __hip_atomic_fetch_add(p, v, __ATOMIC_RELAXED, __HIP_MEMORY_SCOPE_AGENT);
}
__device__ __forceinline__ unsigned atomAddU(unsigned* p, unsigned v) {
    return __hip_atomic_fetch_add(p, v, __ATOMIC_RELAXED, __HIP_MEMORY_SCOPE_AGENT);
}
__device__ __forceinline__ float leaky(float v, float s) { return v >= 0.f ? v : s * v; }
__device__ __forceinline__ float bf2f(u16 u) {
    union { unsigned i; float f; } x; x.i = ((unsigned)u) << 16; return x.f;
}
__device__ __forceinline__ u16 f2bf(float f) {
    union { float f; unsigned i; } x; x.f = f;
    return (u16)((x.i + 0x7fffu + ((x.i >> 16) & 1u)) >> 16);
}

// ---- K1: M_s[f,h] = sum_c Wg[f,h*32+c]*attS[h,c]; same for M_d (one block) ----
__global__ void k_matt(const float* __restrict__ Wg, const float* __restrict__ attS,
                       const float* __restrict__ attD, float* __restrict__ M) {
    int t = threadIdx.x;  // 128, use 72
    if (t >= 72) return;
    int d = t >= 36 ? 1 : 0;
    int q = t - 36 * d;
    int f = q >> 2, h = q & 3;
    const float* av = d ? attD : attS;
    float s = 0.f;
#pragma unroll
    for (int c = 0; c < 32; ++c) s += Wg[f * HC + h * 32 + c] * av[h * 32 + c];
    M[d * 36 + q] = s;
}

// ---- K2: per-node 32B bf16 record rec = {x[9], a_s[4], pad[3]} + a_d f32 ----
__global__ void k_att(const float* __restrict__ x, const float* __restrict__ M,
                      u16* __restrict__ rec, float* __restrict__ a_d) {
    __shared__ float Ms[36], Md[36];
    int t = threadIdx.x;  // 256
    if (t < 36) Ms[t] = M[t];
    else if (t < 72) Md[t - 36] = M[t];
    __syncthreads();
    int n = blockIdx.x * 256 + t;
    if (n >= NND) return;
    float xv[FEAT];
#pragma unroll
    for (int f = 0; f < FEAT; ++f) xv[f] = x[n * FEAT + f];
    float s0 = 0, s1 = 0, s2 = 0, s3 = 0, d0 = 0, d1 = 0, d2 = 0, d3 = 0;
#pragma unroll
    for (int f = 0; f < FEAT; ++f) {
        float xf = xv[f];
        s0 += xf * Ms[f * 4 + 0]; s1 += xf * Ms[f * 4 + 1];
        s2 += xf * Ms[f * 4 + 2]; s3 += xf * Ms[f * 4 + 3];
        d0 += xf * Md[f * 4 + 0]; d1 += xf * Md[f * 4 + 1];
        d2 += xf * Md[f * 4 + 2]; d3 += xf * Md[f * 4 + 3];
    }
    u16 v[16];
#pragma unroll
    for (int f = 0; f < FEAT; ++f) v[f] = f2bf(xv[f]);
    v[9] = f2bf(s0); v[10] = f2bf(s1); v[11] = f2bf(s2); v[12] = f2bf(s3);
    v[13] = 0; v[14] = 0; v[15] = 0;
    unsigned pk[8];
#pragma unroll
    for (int i = 0; i < 8; ++i) pk[i] = (unsigned)v[2 * i] | ((unsigned)v[2 * i + 1] << 16);
    uint4* rp = (uint4*)(rec + (size_t)n * 16);
    rp[0] = make_uint4(pk[0], pk[1], pk[2], pk[3]);
    rp[1] = make_uint4(pk[4], pk[5], pk[6], pk[7]);
    ((float4*)a_d)[n] = make_float4(d0, d1, d2, d3);
}

// ---- K3: in-degree histogram + bucket histogram (1024 thr) ----
__global__ void k_degbkt(const int* __restrict__ ei, unsigned* __restrict__ deg,
                         unsigned* __restrict__ bktCnt) {
    __shared__ unsigned h[NBUCK];
    int t = threadIdx.x;
    if (t < NBUCK) h[t] = 0;
    __syncthreads();
    int e = blockIdx.x * 1024 + t;
    if (e < NED) {
        int d = ei[NED + e];
        atomAddU(&deg[d], 1u);
        atomicAdd(&h[d >> 9], 1u);
    }
    __syncthreads();
    if (t < NBUCK && h[t]) atomAddU(&bktCnt[t], h[t]);
}

// ---- K4a: per-block sums of deg ----
__global__ void k_scanA(const unsigned* __restrict__ deg, unsigned* __restrict__ bsum) {
    __shared__ unsigned s[256];
    int t = threadIdx.x;
    int i = blockIdx.x * 256 + t;
    s[t] = (i < NND) ? deg[i] : 0u;
    __syncthreads();
    for (int off = 128; off; off >>= 1) {
        if (t < off) s[t] += s[t + off];
        __syncthreads();
    }
    if (t == 0) bsum[blockIdx.x] = s[0];
}

// ---- K4b: scan block sums -> boff; scan bucket counts -> bktBase/bktCursor ----
__global__ void k_scanB(const unsigned* __restrict__ bsum, unsigned* __restrict__ boff,
                        const unsigned* __restrict__ bktCnt, unsigned* __restrict__ bktBase,
                        unsigned* __restrict__ bktCursor) {
    __shared__ unsigned s[512];
    __shared__ unsigned s2[256];
    int t = threadIdx.x;  // 512
    s[t] = (t < SCAN_NBLK) ? bsum[t] : 0u;
    if (t < 256) s2[t] = (t < NBUCK) ? bktCnt[t] : 0u;
    __syncthreads();
    for (int off = 1; off < 512; off <<= 1) {
        unsigned v = (t >= off) ? s[t - off] : 0u;
        unsigned v2 = (t < 256 && t >= off) ? s2[t - off] : 0u;
        __syncthreads();
        s[t] += v;
        if (t < 256) s2[t] += v2;
        __syncthreads();
    }
    if (t < SCAN_NBLK) boff[t] = (t == 0) ? 0u : s[t - 1];
    if (t < NBUCK) {
        unsigned bb = (t == 0) ? 0u : s2[t - 1];
        bktBase[t] = bb; bktCursor[t] = bb;
    }
}

// ---- K4c: intra-block exclusive scan + offset -> rowptr, cursor, dinv ----
__global__ void k_scanC(const unsigned* __restrict__ deg, const unsigned* __restrict__ boff,
                        unsigned* __restrict__ rowptr, unsigned* __restrict__ cursor,
                        float* __restrict__ dinv) {
    __shared__ unsigned s[256];
    int t = threadIdx.x;
    int i = blockIdx.x * 256 + t;
    unsigned v = (i < NND) ? deg[i] : 0u;
    s[t] = v;
    __syncthreads();
    for (int off = 1; off < 256; off <<= 1) {
        unsigned u = (t >= off) ? s[t - off] : 0u;
        __syncthreads();
        s[t] += u;
        __syncthreads();
    }
    unsigned excl = boff[blockIdx.x] + s[t] - v;
    if (i < NND) {
        rowptr[i] = excl; cursor[i] = excl;
        dinv[i] = rsqrtf((float)v + 1.f);
    }
    if (i == NND - 1) rowptr[NND] = excl + v;
}

// ---- K5a: bin edges into bucket-major staging (block-local contiguous runs) ----
__global__ __launch_bounds__(256) void k_bin(const int* __restrict__ ei,
                                             unsigned* __restrict__ bktCursor,
                                             uint2* __restrict__ staging) {
    __shared__ unsigned hist[NBUCK];
    __shared__ unsigned gbase[NBUCK];
    int t = threadIdx.x;
    if (t < NBUCK) hist[t] = 0;
    __syncthreads();
    int base = blockIdx.x * BINCHUNK;
    int lim = NED - base;
    int srcv[16], dstv[16];
#pragma unroll
    for (int k = 0; k < 16; ++k) {
        int i = t + k * 256;
        if (i < lim) {
            srcv[k] = ei[base + i];
            dstv[k] = ei[NED + base + i];
            atomicAdd(&hist[dstv[k] >> 9], 1u);
        } else dstv[k] = -1;
    }
    __syncthreads();
    if (t < NBUCK) {
        unsigned c = hist[t];
        gbase[t] = c ? atomAddU(&bktCursor[t], c) : 0u;
    }
    __syncthreads();
    if (t < NBUCK) hist[t] = 0;
    __syncthreads();
#pragma unroll
    for (int k = 0; k < 16; ++k) {
        if (dstv[k] >= 0) {
            int b = dstv[k] >> 9;
            unsigned off = atomicAdd(&hist[b], 1u);
            staging[gbase[b] + off] = make_uint2((unsigned)srcv[k], (unsigned)dstv[k]);
        }
    }
}

// ---- K5b: place staged edges into csr (one block per bucket -> L2-local) ----
__global__ void k_place(const unsigned* __restrict__ bktBase, const unsigned* __restrict__ bktCnt,
                        const uint2* __restrict__ staging, unsigned* __restrict__ cursor,
                        unsigned* __restrict__ csr) {
    int b = blockIdx.x;
    unsigned lo = bktBase[b], n = bktCnt[b];
    for (unsigned i = threadIdx.x; i < n; i += 256) {
        uint2 p = staging[lo + i];
        unsigned pos = atomAddU(&cursor[p.y], 1u);
        csr[pos] = p.x;
    }
}

// ---- K7: GAT aggregation + fused softmax denom (wave per node, lanes 0..35) ----
__global__ void k_gat_g(const unsigned* __restrict__ rowptr, const unsigned* __restrict__ csr,
                        const u16* __restrict__ rec, const float* __restrict__ a_d,
                        float* __restrict__ z) {
    int n = blockIdx.x * 4 + (threadIdx.x >> 6);  // grid 25000 x 256 exact
    int lane = threadIdx.x & 63;
    if (lane >= 36) return;
    int h = lane / 9, f = lane - h * 9;
    unsigned e0 = rowptr[n], e1 = rowptr[n + 1];
    float adh = a_d[n * 4 + h];
    size_t q = (size_t)n * 16;
    float ws = __expf(leaky(bf2f(rec[q + 9 + h]) + adh, 0.2f));
    float acc = ws * bf2f(rec[q + f]);
    float den = ws;
    unsigned e = e0;
    for (; e + 4 <= e1; e += 4) {
        size_t s0 = (size_t)csr[e] * 16, s1 = (size_t)csr[e + 1] * 16;
        size_t s2 = (size_t)csr[e + 2] * 16, s3 = (size_t)csr[e + 3] * 16;
        float a0 = bf2f(rec[s0 + 9 + h]), x0 = bf2f(rec[s0 + f]);
        float a1 = bf2f(rec[s1 + 9 + h]), x1 = bf2f(rec[s1 + f]);
        float a2 = bf2f(rec[s2 + 9 + h]), x2 = bf2f(rec[s2 + f]);
        float a3 = bf2f(rec[s3 + 9 + h]), x3 = bf2f(rec[s3 + f]);
        float w0 = __expf(leaky(a0 + adh, 0.2f));
        float w1 = __expf(leaky(a1 + adh, 0.2f));
        float w2 = __expf(leaky(a2 + adh, 0.2f));
        float w3 = __expf(leaky(a3 + adh, 0.2f));
        acc += w0 * x0 + w1 * x1 + w2 * x2 + w3 * x3;
        den += w0 + w1 + w2 + w3;
    }
    for (; e < e1; ++e) {
        size_t s = (size_t)csr[e] * 16;
        float w = __expf(leaky(bf2f(rec[s + 9 + h]) + adh, 0.2f));
        acc += w * bf2f(rec[s + f]);
        den += w;
    }
    z[n * 36 + lane] = acc / (den + 1e-16f);
}

// ---- K8: g1 = leaky(z @ W_head + b_gat) ----
__global__ void k_gat_out(const float* __restrict__ z, const float* __restrict__ Wg,
                          const float* __restrict__ bg, float* __restrict__ g1) {
    __shared__ float Wf[FEAT * HC];
    __shared__ float zs[36];
    int t = threadIdx.x;  // 128
    for (int f = 0; f < FEAT; ++f) Wf[f * HC + t] = Wg[f * HC + t];
    float bias = bg[t];
    int h = t >> 5;
    int i0 = blockIdx.x * 64;
    for (int n = 0; n < 64; ++n) {
        int i = i0 + n;
        if (i >= NND) break;
        __syncthreads();
        if (t < 36) zs[t] = z[i * 36 + t];
        __syncthreads();
        float acc = bias;
#pragma unroll
        for (int f = 0; f < FEAT; ++f) acc += zs[h * 9 + f] * Wf[f * HC + t];
        g1[i * HC + t] = leaky(acc, 0.01f);
    }
}

// ---- K9: h2s = bf16(dinv * (g1 @ W2))  (N x 128 @ 128 x 64) ----
__global__ void k_gemm_h2(const float* __restrict__ g1, const float* __restrict__ W2,
                          const float* __restrict__ dinv, u16* __restrict__ h2) {
    __shared__ float Wf[128 * 64];
    __shared__ float rws[4][128];
    int t = threadIdx.x;  // 256
#pragma unroll
    for (int j = 0; j < 32; ++j) Wf[t + j * 256] = W2[t + j * 256];
    int rbase0 = blockIdx.x * 32;
    int sub = t >> 6, col = t & 63;
    for (int p = 0; p < 8; ++p) {
        int rbase = rbase0 + p * 4;
        __syncthreads();
        { int lr = t >> 7, k = t & 127;        rws[lr][k] = g1[(rbase + lr) * 128 + k]; }
        { int i2 = t + 256; int lr = i2 >> 7, k = i2 & 127; rws[lr][k] = g1[(rbase + lr) * 128 + k]; }
        __syncthreads();
        float acc = 0.f;
#pragma unroll
        for (int k = 0; k < 128; ++k) acc += rws[sub][k] * Wf[k * 64 + col];
        int row = rbase + sub;
        h2[(size_t)row * 64 + col] = f2bf(dinv[row] * acc);
    }
}

// ---- K10/K11: GCN aggregation (pre-scaled bf16 gather; wave per node, 64 ch) ----
// input hin is dinv-prescaled. OUTMODE 1: store bf16(dinv*leaky(dn*acc+b)); 0: f32 dn*acc
template <int OUTMODE>
__global__ void k_gcn_g(const unsigned* __restrict__ rowptr, const unsigned* __restrict__ csr,
                        const float* __restrict__ dinv, const u16* __restrict__ hin,
                        const float* __restrict__ bias, void* __restrict__ hout_) {
    int n = blockIdx.x * 4 + (threadIdx.x >> 6);  // grid 25000 x 256 exact
    int lane = threadIdx.x & 63;
    unsigned e0 = rowptr[n], e1 = rowptr[n + 1];
    float acc = bf2f(hin[(size_t)n * 64 + lane]);  // self term (pre-scaled)
    unsigned e = e0;
    for (; e + 4 <= e1; e += 4) {
        unsigned s0 = csr[e], s1 = csr[e + 1], s2 = csr[e + 2], s3 = csr[e + 3];
        float h0 = bf2f(hin[(size_t)s0 * 64 + lane]);
        float h1 = bf2f(hin[(size_t)s1 * 64 + lane]);
        float h2 = bf2f(hin[(size_t)s2 * 64 + lane]);
        float h3 = bf2f(hin[(size_t)s3 * 64 + lane]);
        acc += h0 + h1 + h2 + h3;
    }
    for (; e < e1; ++e) acc += bf2f(hin[(size_t)csr[e] * 64 + lane]);
    float dn = dinv[n];
    float out = dn * acc;
    if (OUTMODE == 1) {
        out = leaky(out + bias[lane], 0.01f);
        ((u16*)hout_)[(size_t)n * 64 + lane] = f2bf(dn * out);  // pre-scale for layer 2
    } else {
        ((float*)hout_)[(size_t)n * 64 + lane] = out;
    }
}

// ---- K12: g3 = leaky(agg3 @ W3 + b3)  (N x 64 @ 64 x 128) ----
__global__ void k_gcn2_out(const float* __restrict__ agg3, const float* __restrict__ W3,
                           const float* __restrict__ b3, float* __restrict__ g3) {
    __shared__ float Wf[64 * 128];
    __shared__ float rws[2][64];
    int t = threadIdx.x;  // 256
#pragma unroll
    for (int j = 0; j < 32; ++j) Wf[t + j * 256] = W3[t + j * 256];
    int col = t & 127, sub = t >> 7;
    float bias = b3[col];
    int rbase0 = blockIdx.x * 32;
    for (int p = 0; p < 16; ++p) {
        int rbase = rbase0 + p * 2;
        __syncthreads();
        if (t < 128) {
            int lr = t >> 6, k = t & 63;
            rws[lr][k] = agg3[(rbase + lr) * 64 + k];
        }
        __syncthreads();
        float acc = bias;
#pragma unroll
        for (int k = 0; k < 64; ++k) acc += rws[sub][k] * Wf[k * 128 + col];
        g3[(rbase + sub) * 128 + col] = leaky(acc, 0.01f);
    }
}

// ---- K13: mean-pool using SORTED batch: run-local accumulation, flush on change ----
__global__ void k_pool(const float* __restrict__ g3, const int* __restrict__ batch,
                       float* __restrict__ pooled, float* __restrict__ cnt) {
    int t = threadIdx.x;  // 128
    int n0 = blockIdx.x * 64;
    int n1 = n0 + 64; if (n1 > NND) n1 = NND;
    float acc = 0.f;
    int cur = batch[n0];
    int runStart = n0;
    for (int i = n0; i < n1; ++i) {
        int b = batch[i];
        if (b != cur) {
            atomAdd(&pooled[cur * 128 + t], acc);
            if (t == 0) atomAdd(&cnt[cur], (float)(i - runStart));
            acc = 0.f; cur = b; runStart = i;
        }
        acc += g3[i * 128 + t];
    }
    atomAdd(&pooled[cur * 128 + t], acc);
    if (t == 0) atomAdd(&cnt[cur], (float)(n1 - runStart));
}

// ---- K14: fused sequence branch -> sfc [B,64] ----
__global__ void k_seq(const float* __restrict__ seq, const float* __restrict__ w1, const float* __restrict__ c1b,
                      const float* __restrict__ w2, const float* __restrict__ c2b,
                      const float* __restrict__ g1n, const float* __restrict__ b1n,
                      const float* __restrict__ m1n, const float* __restrict__ v1n,
                      const float* __restrict__ g2n, const float* __restrict__ b2n,
                      const float* __restrict__ m2n, const float* __restrict__ v2n,
                      const float* __restrict__ fcW, const float* __restrict__ fcb,
                      float* __restrict__ sfc) {
    __shared__ float xs[30 * 20];
    __shared__ float y1[64 * 18];
    __shared__ float y2[64 * 16];
    __shared__ float red[4][64];
    int t = threadIdx.x;  // 256
    int b = blockIdx.x;
    for (int idx = t; idx < 600; idx += 256) xs[idx] = seq[b * 600 + idx];
    __syncthreads();
    for (int idx = t; idx < 64 * 18; idx += 256) {
        int o = idx / 18, l = idx - o * 18;
        float acc = c1b[o];
        for (int i = 0; i < 30; ++i)
#pragma unroll
            for (int k = 0; k < 3; ++k)
                acc += xs[i * 20 + l + k] * w1[o * 90 + i * 3 + k];
        float bn = (acc - m1n[o]) * rsqrtf(v1n[o] + 1e-5f) * g1n[o] + b1n[o];
        y1[idx] = leaky(bn, 0.01f);
    }
    __syncthreads();
    for (int idx = t; idx < 64 * 16; idx += 256) {
        int o = idx >> 4, l = idx & 15;
        float acc = c2b[o];
        for (int i = 0; i < 64; ++i)
#pragma unroll
            for (int k = 0; k < 3; ++k)
                acc += y1[i * 18 + l + k] * w2[o * 192 + i * 3 + k];
        float bn = (acc - m2n[o]) * rsqrtf(v2n[o] + 1e-5f) * g2n[o] + b2n[o];
        y2[idx] = leaky(bn, 0.01f);
    }
    __syncthreads();
    {
        int o = t & 63, part = t >> 6;
        float acc = 0.f;
        for (int j = part * 256; j < part * 256 + 256; ++j)
            acc += y2[j] * fcW[j * 64 + o];
        red[part][o] = acc;
    }
    __syncthreads();
    if (t < 64) sfc[b * 64 + t] = red[0][t] + red[1][t] + red[2][t] + red[3][t] + fcb[t];
}

// ---- K15: fusion + classifier -> out [B,1] f32 ----
__global__ void k_final(const float* __restrict__ pooled, const float* __restrict__ cnt,
                        const float* __restrict__ sfc,
                        const float* __restrict__ fusW, const float* __restrict__ fusb,
                        const float* __restrict__ c1W, const float* __restrict__ c1b,
                        const float* __restrict__ c3W, const float* __restrict__ c3b,
                        float* __restrict__ out) {
    __shared__ float comb[192];
    __shared__ float t1[128];
    int t = threadIdx.x;  // 128
    int b = blockIdx.x;
    float invc = 1.f / fmaxf(cnt[b], 1.f);
    comb[t] = pooled[b * 128 + t] * invc;
    if (t < 64) comb[128 + t] = sfc[b * 64 + t];
    __syncthreads();
    float acc = fusb[t];
    for (int k = 0; k < 192; ++k) acc += comb[k] * fusW[k * 128 + t];
    t1[t] = leaky(acc, 0.01f);
    __syncthreads();
    if (t < 64) {
        float a2 = c1b[t];
        for (int k = 0; k < 128; ++k) a2 += t1[k] * c1W[k * 64 + t];
        a2 = leaky(a2, 0.01f);
        float p = a2 * c3W[t];
#pragma unroll
        for (int off = 32; off; off >>= 1) p += __shfl_xor(p, off, 64);
        if (t == 0) out[b] = p + c3b[0];
    }
}

extern "C" void kernel_launch(void* const* d_in, const int* in_sizes, int n_in,
                              void* d_out, int out_size, void* d_ws, size_t ws_size,
                              hipStream_t stream) {
    const float* x     = (const float*)d_in[0];
    const int*   ei    = (const int*)d_in[1];
    const int*   batch = (const int*)d_in[2];
    const float* seq   = (const float*)d_in[3];
    const float* Wg    = (const float*)d_in[4];
    const float* attS  = (const float*)d_in[5];
    const float* attD  = (const float*)d_in[6];
    const float* bg    = (const float*)d_in[7];
    const float* W2    = (const float*)d_in[8];
    const float* b2    = (const float*)d_in[9];
    const float* W3    = (const float*)d_in[10];
    const float* b3    = (const float*)d_in[11];
    const float* c1w   = (const float*)d_in[12];
    const float* c1bb  = (const float*)d_in[13];
    const float* c2w   = (const float*)d_in[14];
    const float* c2bb  = (const float*)d_in[15];
    const float* bn1g  = (const float*)d_in[16];
    const float* bn1b  = (const float*)d_in[17];
    const float* bn1m  = (const float*)d_in[18];
    const float* bn1v  = (const float*)d_in[19];
    const float* bn2g  = (const float*)d_in[20];
    const float* bn2b  = (const float*)d_in[21];
    const float* bn2m  = (const float*)d_in[22];
    const float* bn2v  = (const float*)d_in[23];
    const float* fcW   = (const float*)d_in[24];
    const float* fcb   = (const float*)d_in[25];
    const float* fusW  = (const float*)d_in[26];
    const float* fusb  = (const float*)d_in[27];
    const float* cls1W = (const float*)d_in[28];
    const float* cls1b = (const float*)d_in[29];
    const float* cls3W = (const float*)d_in[30];
    const float* cls3b = (const float*)d_in[31];

    // ---- workspace arena ----
    char* wsb = (char*)d_ws;
    const size_t N = NND;
    float*    M      = (float*)wsb;                                  // 80
    float*    a_d    = M + 80;                                       // N*4 f32
    u16*      rec    = (u16*)(a_d + N * 4);                          // N*16 u16 (32B/node)
    float*    dinv   = (float*)(rec + N * 16);                       // N
    unsigned* deg    = (unsigned*)(dinv + N);                        // N+4   } zero block
    unsigned* bktCnt = deg + N + 4;                                  // 256   }
    float*    pooled = (float*)(bktCnt + 256);                       // B*128 }
    float*    cnt    = pooled + (size_t)NB * 128;                    // B     }
    unsigned* rowptr = (unsigned*)(cnt + NB);                        // N+4
    unsigned* cursor = rowptr + N + 4;                               // N
    unsigned* bsum   = cursor + N;                                   // 512
    unsigned* boff   = bsum + 512;                                   // 512
    unsigned* bktBase= boff + 512;                                   // 256
    unsigned* bktCur = bktBase + 256;                                // 256
    uint2*    staging= (uint2*)(bktCur + 256);                       // NED uint2 (12.8MB)
    unsigned* csr    = (unsigned*)(staging + NED);                   // NED
    float*    gA     = (float*)(csr + NED);                          // N*128 f32 (g1 -> g3)
    float*    agg3   = gA + N * 128;                                 // N*64 f32 (aliases z)
    u16*      g2b    = (u16*)(agg3 + N * 64);                        // N*64 bf16
    float*    sfc    = (float*)(g2b + N * 64);                       // B*64
    float*    z      = agg3;                                         // z (N*36 f32) dead before agg3
    u16*      h2b    = (u16*)staging;                                // staging dead after k_place

    size_t zero_bytes = ((N + 4) + 256 + (size_t)NB * 128 + NB) * 4;
    hipMemsetAsync(deg, 0, zero_bytes, stream);

    k_matt<<<1, 128, 0, stream>>>(Wg, attS, attD, M);
    k_att<<<(NND + 255) / 256, 256, 0, stream>>>(x, M, rec, a_d);
    k_degbkt<<<(NED + 1023) / 1024, 1024, 0, stream>>>(ei, deg, bktCnt);
    k_scanA<<<SCAN_NBLK, 256, 0, stream>>>(deg, bsum);
    k_scanB<<<1, 512, 0, stream>>>(bsum, boff, bktCnt, bktBase, bktCur);
    k_scanC<<<SCAN_NBLK, 256, 0, stream>>>(deg, boff, rowptr, cursor, dinv);
    k_bin<<<BIN_NBLK, 256, 0, stream>>>(ei, bktCur, staging);
    k_place<<<NBUCK, 256, 0, stream>>>(bktBase, bktCnt, staging, cursor, csr);
    k_gat_g<<<NND / 4, 256, 0, stream>>>(rowptr, csr, rec, a_d, z);
    k_gat_out<<<(NND + 63) / 64, 128, 0, stream>>>(z, Wg, bg, gA);
    k_gemm_h2<<<NND / 32, 256, 0, stream>>>(gA, W2, dinv, h2b);
    k_gcn_g<1><<<NND / 4, 256, 0, stream>>>(rowptr, csr, dinv, h2b, b2, (void*)g2b);
    k_gcn_g<0><<<NND / 4, 256, 0, stream>>>(rowptr, csr, dinv, g2b, b2, (void*)agg3);
    k_gcn2_out<<<NND / 32, 256, 0, stream>>>(agg3, W3, b3, gA);
    k_pool<<<(NND + 63) / 64, 128, 0, stream>>>(gA, batch, pooled, cnt);
    k_seq<<<NB, 256, 0, stream>>>(seq, c1w, c1bb, c2w, c2bb, bn1g, bn1b, bn1m, bn1v,
                                  bn2g, bn2b, bn2m, bn2v, fcW, fcb, sfc);
    k_final<<<NB, 128, 0, stream>>>(pooled, cnt, sfc, fusW, fusb, cls1W, cls1b,
                                    cls3W, cls3b, (float*)d_out);
}

// Round 7
// 655.670 us; speedup vs baseline: 3.2036x; 1.1886x over previous
//
#include <hip/hip_runtime.h>

#define NND 100000
#define NED 1600000
#define NB  1024
#define FEAT 9
#define HC 128
#define NBUCK ((NND + 511) / 512)            // 196 buckets of 512 nodes
#define BINCHUNK 4096
#define BIN_NBLK ((NED + BINCHUNK - 1) / BINCHUNK)  // 391

typedef unsigned short u16;

__device__ __forceinline__ void atomAdd(float* p, float v) {
    __hip_atomic_fetch_add(p, v, __ATOMIC_RELAXED, __HIP_MEMORY_SCOPE_AGENT);
}
__device__ __forceinline__ unsigned atomAddU(unsigned* p, unsigned v) {
    return __hip_atomic_fetch_add(p, v, __ATOMIC_RELAXED, __HIP_MEMORY_SCOPE_AGENT);
}
__device__ __forceinline__ float leaky(float v, float s) { return v >= 0.f ? v : s * v; }
__device__ __forceinline__ float bf2f(u16 u) {
    union { unsigned i; float f; } x; x.i = ((unsigned)u) << 16; return x.f;
}
__device__ __forceinline__ u16 f2bf(float f) {
    union { float f; unsigned i; } x; x.f = f;
    return (u16)((x.i + 0x7fffu + ((x.i >> 16) & 1u)) >> 16);
}

// ---- K1: M_s[f,h] = sum_c Wg[f,h*32+c]*attS[h,c]; same for M_d (one block) ----
__global__ void k_matt(const float* __restrict__ Wg, const float* __restrict__ attS,
                       const float* __restrict__ attD, float* __restrict__ M) {
    int t = threadIdx.x;  // 128, use 72
    if (t >= 72) return;
    int d = t >= 36 ? 1 : 0;
    int q = t - 36 * d;
    int f = q >> 2, h = q & 3;
    const float* av = d ? attD : attS;
    float s = 0.f;
#pragma unroll
    for (int c = 0; c < 32; ++c) s += Wg[f * HC + h * 32 + c] * av[h * 32 + c];
    M[d * 36 + q] = s;
}

// ---- K2: per-node 32B bf16 record rec = {x[9], a_s[4], pad[3]} + a_d f32 ----
__global__ void k_att(const float* __restrict__ x, const float* __restrict__ M,
                      u16* __restrict__ rec, float* __restrict__ a_d) {
    __shared__ float Ms[36], Md[36];
    int t = threadIdx.x;  // 256
    if (t < 36) Ms[t] = M[t];
    else if (t < 72) Md[t - 36] = M[t];
    __syncthreads();
    int n = blockIdx.x * 256 + t;
    if (n >= NND) return;
    float xv[FEAT];
#pragma unroll
    for (int f = 0; f < FEAT; ++f) xv[f] = x[n * FEAT + f];
    float s0 = 0, s1 = 0, s2 = 0, s3 = 0, d0 = 0, d1 = 0, d2 = 0, d3 = 0;
#pragma unroll
    for (int f = 0; f < FEAT; ++f) {
        float xf = xv[f];
        s0 += xf * Ms[f * 4 + 0]; s1 += xf * Ms[f * 4 + 1];
        s2 += xf * Ms[f * 4 + 2]; s3 += xf * Ms[f * 4 + 3];
        d0 += xf * Md[f * 4 + 0]; d1 += xf * Md[f * 4 + 1];
        d2 += xf * Md[f * 4 + 2]; d3 += xf * Md[f * 4 + 3];
    }
    u16 v[16];
#pragma unroll
    for (int f = 0; f < FEAT; ++f) v[f] = f2bf(xv[f]);
    v[9] = f2bf(s0); v[10] = f2bf(s1); v[11] = f2bf(s2); v[12] = f2bf(s3);
    v[13] = 0; v[14] = 0; v[15] = 0;
    unsigned pk[8];
#pragma unroll
    for (int i = 0; i < 8; ++i) pk[i] = (unsigned)v[2 * i] | ((unsigned)v[2 * i + 1] << 16);
    uint4* rp = (uint4*)(rec + (size_t)n * 16);
    rp[0] = make_uint4(pk[0], pk[1], pk[2], pk[3]);
    rp[1] = make_uint4(pk[4], pk[5], pk[6], pk[7]);
    ((float4*)a_d)[n] = make_float4(d0, d1, d2, d3);
}

// ---- K3: bucket-count histogram only (LDS-merged) ----
__global__ void k_bktcnt(const int* __restrict__ ei, unsigned* __restrict__ bktCnt) {
    __shared__ unsigned h[NBUCK];
    int t = threadIdx.x;  // 1024
    if (t < NBUCK) h[t] = 0;
    __syncthreads();
    int base = blockIdx.x * 4096;
#pragma unroll
    for (int k = 0; k < 4; ++k) {
        int i = base + t + k * 1024;
        if (i < NED) atomicAdd(&h[ei[NED + i] >> 9], 1u);
    }
    __syncthreads();
    if (t < NBUCK && h[t]) atomAddU(&bktCnt[t], h[t]);
}

// ---- K4: scan 196 bucket counts -> bktBase, bktCur; rowptr[NND]=NED ----
__global__ void k_scanBkt(const unsigned* __restrict__ bktCnt, unsigned* __restrict__ bktBase,
                          unsigned* __restrict__ bktCur, unsigned* __restrict__ rowptr) {
    __shared__ unsigned s[256];
    int t = threadIdx.x;  // 256
    s[t] = (t < NBUCK) ? bktCnt[t] : 0u;
    __syncthreads();
    for (int off = 1; off < 256; off <<= 1) {
        unsigned v = (t >= off) ? s[t - off] : 0u;
        __syncthreads();
        s[t] += v;
        __syncthreads();
    }
    if (t < NBUCK) {
        unsigned bb = (t == 0) ? 0u : s[t - 1];
        bktBase[t] = bb; bktCur[t] = bb;
    }
    if (t == 0) rowptr[NND] = NED;
}

// ---- K5: bin edges into bucket-major staging, packed (dstLocal<<17)|src ----
__global__ __launch_bounds__(256) void k_bin(const int* __restrict__ ei,
                                             unsigned* __restrict__ bktCursor,
                                             unsigned* __restrict__ staging) {
    __shared__ unsigned hist[NBUCK];
    __shared__ unsigned gbase[NBUCK];
    int t = threadIdx.x;
    if (t < NBUCK) hist[t] = 0;
    __syncthreads();
    int base = blockIdx.x * BINCHUNK;
    int lim = NED - base;
    int srcv[16], dstv[16];
#pragma unroll
    for (int k = 0; k < 16; ++k) {
        int i = t + k * 256;
        if (i < lim) {
            srcv[k] = ei[base + i];
            dstv[k] = ei[NED + base + i];
            atomicAdd(&hist[dstv[k] >> 9], 1u);
        } else dstv[k] = -1;
    }
    __syncthreads();
    if (t < NBUCK) {
        unsigned c = hist[t];
        gbase[t] = c ? atomAddU(&bktCursor[t], c) : 0u;
    }
    __syncthreads();
    if (t < NBUCK) hist[t] = 0;
    __syncthreads();
#pragma unroll
    for (int k = 0; k < 16; ++k) {
        if (dstv[k] >= 0) {
            int bk = dstv[k] >> 9;
            unsigned off = atomicAdd(&hist[bk], 1u);
            staging[gbase[bk] + off] = ((unsigned)(dstv[k] & 511) << 17) | (unsigned)srcv[k];
        }
    }
}

// ---- K6: per-bucket CSR build: LDS hist + scan -> rowptr/dinv; LDS cursor scatter ----
__global__ __launch_bounds__(512) void k_place(const unsigned* __restrict__ bktBase,
                                               const unsigned* __restrict__ bktCnt,
                                               const unsigned* __restrict__ staging,
                                               unsigned* __restrict__ csr,
                                               unsigned* __restrict__ rowptr,
                                               float* __restrict__ dinv) {
    __shared__ unsigned lh[512];
    __shared__ unsigned ls[512];
    int b = blockIdx.x, t = threadIdx.x;
    unsigned lo = bktBase[b], n = bktCnt[b];
    lh[t] = 0;
    __syncthreads();
    for (unsigned i = t; i < n; i += 512) atomicAdd(&lh[staging[lo + i] >> 17], 1u);
    __syncthreads();
    unsigned v = lh[t];
    ls[t] = v;
    __syncthreads();
    for (int off = 1; off < 512; off <<= 1) {
        unsigned u = (t >= off) ? ls[t - off] : 0u;
        __syncthreads();
        ls[t] += u;
        __syncthreads();
    }
    unsigned excl = ls[t] - v;
    int node = b * 512 + t;
    if (node < NND) {
        rowptr[node] = lo + excl;
        dinv[node] = rsqrtf((float)v + 1.f);
    }
    __syncthreads();
    lh[t] = excl;  // reuse as local cursor
    __syncthreads();
    for (unsigned i = t; i < n; i += 512) {
        unsigned p = staging[lo + i];
        unsigned pos = atomicAdd(&lh[p >> 17], 1u);
        csr[lo + pos] = p & 0x1FFFFu;
    }
}

// ---- K7: GAT aggregation + fused softmax denom (wave per node, lanes 0..35) ----
__global__ void k_gat_g(const unsigned* __restrict__ rowptr, const unsigned* __restrict__ csr,
                        const u16* __restrict__ rec, const float* __restrict__ a_d,
                        float* __restrict__ z) {
    int n = blockIdx.x * 4 + (threadIdx.x >> 6);  // grid 25000 x 256 exact
    int lane = threadIdx.x & 63;
    if (lane >= 36) return;
    int h = lane / 9, f = lane - h * 9;
    unsigned e0 = rowptr[n], e1 = rowptr[n + 1];
    float adh = a_d[n * 4 + h];
    size_t q = (size_t)n * 16;
    float ws = __expf(leaky(bf2f(rec[q + 9 + h]) + adh, 0.2f));
    float acc = ws * bf2f(rec[q + f]);
    float den = ws;
    unsigned e = e0;
    for (; e + 4 <= e1; e += 4) {
        size_t s0 = (size_t)csr[e] * 16, s1 = (size_t)csr[e + 1] * 16;
        size_t s2 = (size_t)csr[e + 2] * 16, s3 = (size_t)csr[e + 3] * 16;
        float a0 = bf2f(rec[s0 + 9 + h]), x0 = bf2f(rec[s0 + f]);
        float a1 = bf2f(rec[s1 + 9 + h]), x1 = bf2f(rec[s1 + f]);
        float a2 = bf2f(rec[s2 + 9 + h]), x2 = bf2f(rec[s2 + f]);
        float a3 = bf2f(rec[s3 + 9 + h]), x3 = bf2f(rec[s3 + f]);
        float w0 = __expf(leaky(a0 + adh, 0.2f));
        float w1 = __expf(leaky(a1 + adh, 0.2f));
        float w2 = __expf(leaky(a2 + adh, 0.2f));
        float w3 = __expf(leaky(a3 + adh, 0.2f));
        acc += w0 * x0 + w1 * x1 + w2 * x2 + w3 * x3;
        den += w0 + w1 + w2 + w3;
    }
    for (; e < e1; ++e) {
        size_t s = (size_t)csr[e] * 16;
        float w = __expf(leaky(bf2f(rec[s + 9 + h]) + adh, 0.2f));
        acc += w * bf2f(rec[s + f]);
        den += w;
    }
    z[n * 36 + lane] = acc / (den + 1e-16f);
}

// ---- K8: g1 = bf16(leaky(z @ W_head + b_gat)) ----
__global__ void k_gat_out(const float* __restrict__ z, const float* __restrict__ Wg,
                          const float* __restrict__ bg, u16* __restrict__ g1) {
    __shared__ float Wf[FEAT * HC];
    __shared__ float zs[36];
    int t = threadIdx.x;  // 128
    for (int f = 0; f < FEAT; ++f) Wf[f * HC + t] = Wg[f * HC + t];
    float bias = bg[t];
    int h = t >> 5;
    int i0 = blockIdx.x * 64;
    for (int n = 0; n < 64; ++n) {
        int i = i0 + n;
        if (i >= NND) break;
        __syncthreads();
        if (t < 36) zs[t] = z[i * 36 + t];
        __syncthreads();
        float acc = bias;
#pragma unroll
        for (int f = 0; f < FEAT; ++f) acc += zs[h * 9 + f] * Wf[f * HC + t];
        g1[(size_t)i * HC + t] = f2bf(leaky(acc, 0.01f));
    }
}

// ---- K9: h2s = bf16(dinv * (g1 @ W2))  (N x 128 @ 128 x 64), g1 bf16 ----
__global__ void k_gemm_h2(const u16* __restrict__ g1, const float* __restrict__ W2,
                          const float* __restrict__ dinv, u16* __restrict__ h2) {
    __shared__ float Wf[128 * 64];
    __shared__ float rws[4][128];
    int t = threadIdx.x;  // 256
#pragma unroll
    for (int j = 0; j < 32; ++j) Wf[t + j * 256] = W2[t + j * 256];
    int rbase0 = blockIdx.x * 32;
    int sub = t >> 6, col = t & 63;
    for (int p = 0; p < 8; ++p) {
        int rbase = rbase0 + p * 4;
        __syncthreads();
        { int lr = t >> 7, k = t & 127;        rws[lr][k] = bf2f(g1[(size_t)(rbase + lr) * 128 + k]); }
        { int i2 = t + 256; int lr = i2 >> 7, k = i2 & 127; rws[lr][k] = bf2f(g1[(size_t)(rbase + lr) * 128 + k]); }
        __syncthreads();
        float acc = 0.f;
#pragma unroll
        for (int k = 0; k < 128; ++k) acc += rws[sub][k] * Wf[k * 64 + col];
        int row = rbase + sub;
        h2[(size_t)row * 64 + col] = f2bf(dinv[row] * acc);
    }
}

// ---- K10/K11: GCN aggregation (pre-scaled bf16 gather; wave per node, 64 ch) ----
template <int OUTMODE>
__global__ void k_gcn_g(const unsigned* __restrict__ rowptr, const unsigned* __restrict__ csr,
                        const float* __restrict__ dinv, const u16* __restrict__ hin,
                        const float* __restrict__ bias, void* __restrict__ hout_) {
    int n = blockIdx.x * 4 + (threadIdx.x >> 6);  // grid 25000 x 256 exact
    int lane = threadIdx.x & 63;
    unsigned e0 = rowptr[n], e1 = rowptr[n + 1];
    float acc = bf2f(hin[(size_t)n * 64 + lane]);  // self term (pre-scaled)
    unsigned e = e0;
    for (; e + 4 <= e1; e += 4) {
        unsigned s0 = csr[e], s1 = csr[e + 1], s2 = csr[e + 2], s3 = csr[e + 3];
        float h0 = bf2f(hin[(size_t)s0 * 64 + lane]);
        float h1 = bf2f(hin[(size_t)s1 * 64 + lane]);
        float h2 = bf2f(hin[(size_t)s2 * 64 + lane]);
        float h3 = bf2f(hin[(size_t)s3 * 64 + lane]);
        acc += h0 + h1 + h2 + h3;
    }
    for (; e < e1; ++e) acc += bf2f(hin[(size_t)csr[e] * 64 + lane]);
    float dn = dinv[n];
    float out = dn * acc;
    if (OUTMODE == 1) {
        out = leaky(out + bias[lane], 0.01f);
        ((u16*)hout_)[(size_t)n * 64 + lane] = f2bf(dn * out);  // pre-scale for layer 2
    } else {
        ((float*)hout_)[(size_t)n * 64 + lane] = out;
    }
}

// ---- K12: g3 = leaky(agg3 @ W3 + b3)  (N x 64 @ 64 x 128) ----
__global__ void k_gcn2_out(const float* __restrict__ agg3, const float* __restrict__ W3,
                           const float* __restrict__ b3, float* __restrict__ g3) {
    __shared__ float Wf[64 * 128];
    __shared__ float rws[2][64];
    int t = threadIdx.x;  // 256
#pragma unroll
    for (int j = 0; j < 32; ++j) Wf[t + j * 256] = W3[t + j * 256];
    int col = t & 127, sub = t >> 7;
    float bias = b3[col];
    int rbase0 = blockIdx.x * 32;
    for (int p = 0; p < 16; ++p) {
        int rbase = rbase0 + p * 2;
        __syncthreads();
        if (t < 128) {
            int lr = t >> 6, k = t & 63;
            rws[lr][k] = agg3[(rbase + lr) * 64 + k];
        }
        __syncthreads();
        float acc = bias;
#pragma unroll
        for (int k = 0; k < 64; ++k) acc += rws[sub][k] * Wf[k * 128 + col];
        g3[(rbase + sub) * 128 + col] = leaky(acc, 0.01f);
    }
}

// ---- K13: mean-pool using SORTED batch: run-local accumulation, flush on change ----
__global__ void k_pool(const float* __restrict__ g3, const int* __restrict__ batch,
                       float* __restrict__ pooled, float* __restrict__ cnt) {
    int t = threadIdx.x;  // 128
    int n0 = blockIdx.x * 64;
    int n1 = n0 + 64; if (n1 > NND) n1 = NND;
    float acc = 0.f;
    int cur = batch[n0];
    int runStart = n0;
    for (int i = n0; i < n1; ++i) {
        int b = batch[i];
        if (b != cur) {
            atomAdd(&pooled[cur * 128 + t], acc);
            if (t == 0) atomAdd(&cnt[cur], (float)(i - runStart));
            acc = 0.f; cur = b; runStart = i;
        }
        acc += g3[i * 128 + t];
    }
    atomAdd(&pooled[cur * 128 + t], acc);
    if (t == 0) atomAdd(&cnt[cur], (float)(n1 - runStart));
}

// ---- K14: fused sequence branch -> sfc [B,64] ----
__global__ void k_seq(const float* __restrict__ seq, const float* __restrict__ w1, const float* __restrict__ c1b,
                      const float* __restrict__ w2, const float* __restrict__ c2b,
                      const float* __restrict__ g1n, const float* __restrict__ b1n,
                      const float* __restrict__ m1n, const float* __restrict__ v1n,
                      const float* __restrict__ g2n, const float* __restrict__ b2n,
                      const float* __restrict__ m2n, const float* __restrict__ v2n,
                      const float* __restrict__ fcW, const float* __restrict__ fcb,
                      float* __restrict__ sfc) {
    __shared__ float xs[30 * 20];
    __shared__ float y1[64 * 18];
    __shared__ float y2[64 * 16];
    __shared__ float red[4][64];
    int t = threadIdx.x;  // 256
    int b = blockIdx.x;
    for (int idx = t; idx < 600; idx += 256) xs[idx] = seq[b * 600 + idx];
    __syncthreads();
    for (int idx = t; idx < 64 * 18; idx += 256) {
        int o = idx / 18, l = idx - o * 18;
        float acc = c1b[o];
        for (int i = 0; i < 30; ++i)
#pragma unroll
            for (int k = 0; k < 3; ++k)
                acc += xs[i * 20 + l + k] * w1[o * 90 + i * 3 + k];
        float bn = (acc - m1n[o]) * rsqrtf(v1n[o] + 1e-5f) * g1n[o] + b1n[o];
        y1[idx] = leaky(bn, 0.01f);
    }
    __syncthreads();
    for (int idx = t; idx < 64 * 16; idx += 256) {
        int o = idx >> 4, l = idx & 15;
        float acc = c2b[o];
        for (int i = 0; i < 64; ++i)
#pragma unroll
            for (int k = 0; k < 3; ++k)
                acc += y1[i * 18 + l + k] * w2[o * 192 + i * 3 + k];
        float bn = (acc - m2n[o]) * rsqrtf(v2n[o] + 1e-5f) * g2n[o] + b2n[o];
        y2[idx] = leaky(bn, 0.01f);
    }
    __syncthreads();
    {
        int o = t & 63, part = t >> 6;
        float acc = 0.f;
        for (int j = part * 256; j < part * 256 + 256; ++j)
            acc += y2[j] * fcW[j * 64 + o];
        red[part][o] = acc;
    }
    __syncthreads();
    if (t < 64) sfc[b * 64 + t] = red[0][t] + red[1][t] + red[2][t] + red[3][t] + fcb[t];
}

// ---- K15: fusion + classifier -> out [B,1] f32 ----
__global__ void k_final(const float* __restrict__ pooled, const float* __restrict__ cnt,
                        const float* __restrict__ sfc,
                        const float* __restrict__ fusW, const float* __restrict__ fusb,
                        const float* __restrict__ c1W, const float* __restrict__ c1b,
                        const float* __restrict__ c3W, const float* __restrict__ c3b,
                        float* __restrict__ out) {
    __shared__ float comb[192];
    __shared__ float t1[128];
    int t = threadIdx.x;  // 128
    int b = blockIdx.x;
    float invc = 1.f / fmaxf(cnt[b], 1.f);
    comb[t] = pooled[b * 128 + t] * invc;
    if (t < 64) comb[128 + t] = sfc[b * 64 + t];
    __syncthreads();
    float acc = fusb[t];
    for (int k = 0; k < 192; ++k) acc += comb[k] * fusW[k * 128 + t];
    t1[t] = leaky(acc, 0.01f);
    __syncthreads();
    if (t < 64) {
        float a2 = c1b[t];
        for (int k = 0; k < 128; ++k) a2 += t1[k] * c1W[k * 64 + t];
        a2 = leaky(a2, 0.01f);
        float p = a2 * c3W[t];
#pragma unroll
        for (int off = 32; off; off >>= 1) p += __shfl_xor(p, off, 64);
        if (t == 0) out[b] = p + c3b[0];
    }
}

extern "C" void kernel_launch(void* const* d_in, const int* in_sizes, int n_in,
                              void* d_out, int out_size, void* d_ws, size_t ws_size,
                              hipStream_t stream) {
    const float* x     = (const float*)d_in[0];
    const int*   ei    = (const int*)d_in[1];
    const int*   batch = (const int*)d_in[2];
    const float* seq   = (const float*)d_in[3];
    const float* Wg    = (const float*)d_in[4];
    const float* attS  = (const float*)d_in[5];
    const float* attD  = (const float*)d_in[6];
    const float* bg    = (const float*)d_in[7];
    const float* W2    = (const float*)d_in[8];
    const float* b2    = (const float*)d_in[9];
    const float* W3    = (const float*)d_in[10];
    const float* b3    = (const float*)d_in[11];
    const float* c1w   = (const float*)d_in[12];
    const float* c1bb  = (const float*)d_in[13];
    const float* c2w   = (const float*)d_in[14];
    const float* c2bb  = (const float*)d_in[15];
    const float* bn1g  = (const float*)d_in[16];
    const float* bn1b  = (const float*)d_in[17];
    const float* bn1m  = (const float*)d_in[18];
    const float* bn1v  = (const float*)d_in[19];
    const float* bn2g  = (const float*)d_in[20];
    const float* bn2b  = (const float*)d_in[21];
    const float* bn2m  = (const float*)d_in[22];
    const float* bn2v  = (const float*)d_in[23];
    const float* fcW   = (const float*)d_in[24];
    const float* fcb   = (const float*)d_in[25];
    const float* fusW  = (const float*)d_in[26];
    const float* fusb  = (const float*)d_in[27];
    const float* cls1W = (const float*)d_in[28];
    const float* cls1b = (const float*)d_in[29];
    const float* cls3W = (const float*)d_in[30];
    const float* cls3b = (const float*)d_in[31];

    // ---- workspace arena ----
    char* wsb = (char*)d_ws;
    const size_t N = NND;
    float*    M      = (float*)wsb;                                  // 80
    float*    a_d    = M + 80;                                       // N*4 f32
    u16*      rec    = (u16*)(a_d + N * 4);                          // N*16 u16 (32B/node)
    float*    dinv   = (float*)(rec + N * 16);                       // N
    unsigned* bktCnt = (unsigned*)(dinv + N);                        // 256   } zero block
    float*    pooled = (float*)(bktCnt + 256);                       // B*128 }
    float*    cnt    = pooled + (size_t)NB * 128;                    // B     }
    unsigned* bktBase= (unsigned*)(cnt + NB);                        // 256
    unsigned* bktCur = bktBase + 256;                                // 256
    unsigned* rowptr = bktCur + 256;                                 // N+4
    unsigned* staging= rowptr + N + 4;                               // NED u32 (6.4MB)
    unsigned* csr    = staging + NED;                                // NED u32 (6.4MB)
    float*    gA     = (float*)(csr + NED);                          // N*128 f32 region (g1 bf16 -> g3 f32)
    float*    agg3   = gA + N * 128;                                 // N*64 f32 (aliases z)
    u16*      g2b    = (u16*)(agg3 + N * 64);                        // N*64 bf16
    u16*      h2b    = g2b + N * 64;                                 // N*64 bf16
    float*    sfc    = (float*)(h2b + N * 64);                       // B*64
    float*    z      = agg3;                                         // z (N*36 f32) dead before agg3
    u16*      g1b    = (u16*)gA;                                     // g1 bf16, dead before g3 written

    size_t zero_bytes = (256 + (size_t)NB * 128 + NB) * 4;
    hipMemsetAsync(bktCnt, 0, zero_bytes, stream);

    k_matt<<<1, 128, 0, stream>>>(Wg, attS, attD, M);
    k_att<<<(NND + 255) / 256, 256, 0, stream>>>(x, M, rec, a_d);
    k_bktcnt<<<(NED + 4095) / 4096, 1024, 0, stream>>>(ei, bktCnt);
    k_scanBkt<<<1, 256, 0, stream>>>(bktCnt, bktBase, bktCur, rowptr);
    k_bin<<<BIN_NBLK, 256, 0, stream>>>(ei, bktCur, staging);
    k_place<<<NBUCK, 512, 0, stream>>>(bktBase, bktCnt, staging, csr, rowptr, dinv);
    k_gat_g<<<NND / 4, 256, 0, stream>>>(rowptr, csr, rec, a_d, z);
    k_gat_out<<<(NND + 63) / 64, 128, 0, stream>>>(z, Wg, bg, g1b);
    k_gemm_h2<<<NND / 32, 256, 0, stream>>>(g1b, W2, dinv, h2b);
    k_gcn_g<1><<<NND / 4, 256, 0, stream>>>(rowptr, csr, dinv, h2b, b2, (void*)g2b);
    k_gcn_g<0><<<NND / 4, 256, 0, stream>>>(rowptr, csr, dinv, g2b, b2, (void*)agg3);
    k_gcn2_out<<<NND / 32, 256, 0, stream>>>(agg3, W3, b3, gA);
    k_pool<<<(NND + 63) / 64, 128, 0, stream>>>(gA, batch, pooled, cnt);
    k_seq<<<NB, 256, 0, stream>>>(seq, c1w, c1bb, c2w, c2bb, bn1g, bn1b, bn1m, bn1v,
                                  bn2g, bn2b, bn2m, bn2v, fcW, fcb, sfc);
    k_final<<<NB, 128, 0, stream>>>(pooled, cnt, sfc, fusW, fusb, cls1W, cls1b,
                                    cls3W, cls3b, (float*)d_out);
}

// Round 8
// 609.032 us; speedup vs baseline: 3.4489x; 1.0766x over previous
//
#include <hip/hip_runtime.h>

#define NND 100000
#define NED 1600000
#define NB  1024
#define FEAT 9
#define HC 128
#define NBUCK ((NND + 511) / 512)            // 196 buckets of 512 nodes
#define BINCHUNK 4096
#define BIN_NBLK ((NED + BINCHUNK - 1) / BINCHUNK)  // 391

typedef unsigned short u16;

__device__ __forceinline__ void atomAdd(float* p, float v) {
    __hip_atomic_fetch_add(p, v, __ATOMIC_RELAXED, __HIP_MEMORY_SCOPE_AGENT);
}
__device__ __forceinline__ unsigned atomAddU(unsigned* p, unsigned v) {
    return __hip_atomic_fetch_add(p, v, __ATOMIC_RELAXED, __HIP_MEMORY_SCOPE_AGENT);
}
__device__ __forceinline__ float leaky(float v, float s) { return v >= 0.f ? v : s * v; }
__device__ __forceinline__ float bf2f(u16 u) {
    union { unsigned i; float f; } x; x.i = ((unsigned)u) << 16; return x.f;
}
__device__ __forceinline__ u16 f2bf(float f) {
    union { float f; unsigned i; } x; x.f = f;
    return (u16)((x.i + 0x7fffu + ((x.i >> 16) & 1u)) >> 16);
}

// ---- K1: M_s[f,h] = sum_c Wg[f,h*32+c]*attS[h,c]; same for M_d (one block) ----
__global__ void k_matt(const float* __restrict__ Wg, const float* __restrict__ attS,
                       const float* __restrict__ attD, float* __restrict__ M) {
    int t = threadIdx.x;  // 128, use 72
    if (t >= 72) return;
    int d = t >= 36 ? 1 : 0;
    int q = t - 36 * d;
    int f = q >> 2, h = q & 3;
    const float* av = d ? attD : attS;
    float s = 0.f;
#pragma unroll
    for (int c = 0; c < 32; ++c) s += Wg[f * HC + h * 32 + c] * av[h * 32 + c];
    M[d * 36 + q] = s;
}

// ---- K2: per-node 32B bf16 record rec = {x[9], a_s[4], pad[3]} + a_d f32 ----
__global__ void k_att(const float* __restrict__ x, const float* __restrict__ M,
                      u16* __restrict__ rec, float* __restrict__ a_d) {
    __shared__ float Ms[36], Md[36];
    int t = threadIdx.x;  // 256
    if (t < 36) Ms[t] = M[t];
    else if (t < 72) Md[t - 36] = M[t];
    __syncthreads();
    int n = blockIdx.x * 256 + t;
    if (n >= NND) return;
    float xv[FEAT];
#pragma unroll
    for (int f = 0; f < FEAT; ++f) xv[f] = x[n * FEAT + f];
    float s0 = 0, s1 = 0, s2 = 0, s3 = 0, d0 = 0, d1 = 0, d2 = 0, d3 = 0;
#pragma unroll
    for (int f = 0; f < FEAT; ++f) {
        float xf = xv[f];
        s0 += xf * Ms[f * 4 + 0]; s1 += xf * Ms[f * 4 + 1];
        s2 += xf * Ms[f * 4 + 2]; s3 += xf * Ms[f * 4 + 3];
        d0 += xf * Md[f * 4 + 0]; d1 += xf * Md[f * 4 + 1];
        d2 += xf * Md[f * 4 + 2]; d3 += xf * Md[f * 4 + 3];
    }
    u16 v[16];
#pragma unroll
    for (int f = 0; f < FEAT; ++f) v[f] = f2bf(xv[f]);
    v[9] = f2bf(s0); v[10] = f2bf(s1); v[11] = f2bf(s2); v[12] = f2bf(s3);
    v[13] = 0; v[14] = 0; v[15] = 0;
    unsigned pk[8];
#pragma unroll
    for (int i = 0; i < 8; ++i) pk[i] = (unsigned)v[2 * i] | ((unsigned)v[2 * i + 1] << 16);
    uint4* rp = (uint4*)(rec + (size_t)n * 16);
    rp[0] = make_uint4(pk[0], pk[1], pk[2], pk[3]);
    rp[1] = make_uint4(pk[4], pk[5], pk[6], pk[7]);
    ((float4*)a_d)[n] = make_float4(d0, d1, d2, d3);
}

// ---- K3: bucket-count histogram only (LDS-merged) ----
__global__ void k_bktcnt(const int* __restrict__ ei, unsigned* __restrict__ bktCnt) {
    __shared__ unsigned h[NBUCK];
    int t = threadIdx.x;  // 1024
    if (t < NBUCK) h[t] = 0;
    __syncthreads();
    int base = blockIdx.x * 4096;
#pragma unroll
    for (int k = 0; k < 4; ++k) {
        int i = base + t + k * 1024;
        if (i < NED) atomicAdd(&h[ei[NED + i] >> 9], 1u);
    }
    __syncthreads();
    if (t < NBUCK && h[t]) atomAddU(&bktCnt[t], h[t]);
}

// ---- K4: scan 196 bucket counts -> bktBase, bktCur; rowptr[NND]=NED ----
__global__ void k_scanBkt(const unsigned* __restrict__ bktCnt, unsigned* __restrict__ bktBase,
                          unsigned* __restrict__ bktCur, unsigned* __restrict__ rowptr) {
    __shared__ unsigned s[256];
    int t = threadIdx.x;  // 256
    s[t] = (t < NBUCK) ? bktCnt[t] : 0u;
    __syncthreads();
    for (int off = 1; off < 256; off <<= 1) {
        unsigned v = (t >= off) ? s[t - off] : 0u;
        __syncthreads();
        s[t] += v;
        __syncthreads();
    }
    if (t < NBUCK) {
        unsigned bb = (t == 0) ? 0u : s[t - 1];
        bktBase[t] = bb; bktCur[t] = bb;
    }
    if (t == 0) rowptr[NND] = NED;
}

// ---- K5: bin edges into bucket-major staging, packed (dstLocal<<17)|src ----
__global__ __launch_bounds__(256) void k_bin(const int* __restrict__ ei,
                                             unsigned* __restrict__ bktCursor,
                                             unsigned* __restrict__ staging) {
    __shared__ unsigned hist[NBUCK];
    __shared__ unsigned gbase[NBUCK];
    int t = threadIdx.x;
    if (t < NBUCK) hist[t] = 0;
    __syncthreads();
    int base = blockIdx.x * BINCHUNK;
    int lim = NED - base;
    int srcv[16], dstv[16];
#pragma unroll
    for (int k = 0; k < 16; ++k) {
        int i = t + k * 256;
        if (i < lim) {
            srcv[k] = ei[base + i];
            dstv[k] = ei[NED + base + i];
            atomicAdd(&hist[dstv[k] >> 9], 1u);
        } else dstv[k] = -1;
    }
    __syncthreads();
    if (t < NBUCK) {
        unsigned c = hist[t];
        gbase[t] = c ? atomAddU(&bktCursor[t], c) : 0u;
    }
    __syncthreads();
    if (t < NBUCK) hist[t] = 0;
    __syncthreads();
#pragma unroll
    for (int k = 0; k < 16; ++k) {
        if (dstv[k] >= 0) {
            int bk = dstv[k] >> 9;
            unsigned off = atomicAdd(&hist[bk], 1u);
            staging[gbase[bk] + off] = ((unsigned)(dstv[k] & 511) << 17) | (unsigned)srcv[k];
        }
    }
}

// ---- K6: per-bucket CSR build: LDS hist + scan -> rowptr/dinv; LDS cursor scatter ----
__global__ __launch_bounds__(512) void k_place(const unsigned* __restrict__ bktBase,
                                               const unsigned* __restrict__ bktCnt,
                                               const unsigned* __restrict__ staging,
                                               unsigned* __restrict__ csr,
                                               unsigned* __restrict__ rowptr,
                                               float* __restrict__ dinv) {
    __shared__ unsigned lh[512];
    __shared__ unsigned ls[512];
    int b = blockIdx.x, t = threadIdx.x;
    unsigned lo = bktBase[b], n = bktCnt[b];
    lh[t] = 0;
    __syncthreads();
    for (unsigned i = t; i < n; i += 512) atomicAdd(&lh[staging[lo + i] >> 17], 1u);
    __syncthreads();
    unsigned v = lh[t];
    ls[t] = v;
    __syncthreads();
    for (int off = 1; off < 512; off <<= 1) {
        unsigned u = (t >= off) ? ls[t - off] : 0u;
        __syncthreads();
        ls[t] += u;
        __syncthreads();
    }
    unsigned excl = ls[t] - v;
    int node = b * 512 + t;
    if (node < NND) {
        rowptr[node] = lo + excl;
        dinv[node] = rsqrtf((float)v + 1.f);
    }
    __syncthreads();
    lh[t] = excl;  // reuse as local cursor
    __syncthreads();
    for (unsigned i = t; i < n; i += 512) {
        unsigned p = staging[lo + i];
        unsigned pos = atomicAdd(&lh[p >> 17], 1u);
        csr[lo + pos] = p & 0x1FFFFu;
    }
}

// ---- K7: GAT aggregation + fused softmax denom (wave per node, lanes 0..35) ----
__global__ void k_gat_g(const unsigned* __restrict__ rowptr, const unsigned* __restrict__ csr,
                        const u16* __restrict__ rec, const float* __restrict__ a_d,
                        float* __restrict__ z) {
    int n = blockIdx.x * 4 + (threadIdx.x >> 6);  // grid 25000 x 256 exact
    int lane = threadIdx.x & 63;
    if (lane >= 36) return;
    int h = lane / 9, f = lane - h * 9;
    unsigned e0 = rowptr[n], e1 = rowptr[n + 1];
    float adh = a_d[n * 4 + h];
    size_t q = (size_t)n * 16;
    float ws = __expf(leaky(bf2f(rec[q + 9 + h]) + adh, 0.2f));
    float acc = ws * bf2f(rec[q + f]);
    float den = ws;
    unsigned e = e0;
    for (; e + 4 <= e1; e += 4) {
        size_t s0 = (size_t)csr[e] * 16, s1 = (size_t)csr[e + 1] * 16;
        size_t s2 = (size_t)csr[e + 2] * 16, s3 = (size_t)csr[e + 3] * 16;
        float a0 = bf2f(rec[s0 + 9 + h]), x0 = bf2f(rec[s0 + f]);
        float a1 = bf2f(rec[s1 + 9 + h]), x1 = bf2f(rec[s1 + f]);
        float a2 = bf2f(rec[s2 + 9 + h]), x2 = bf2f(rec[s2 + f]);
        float a3 = bf2f(rec[s3 + 9 + h]), x3 = bf2f(rec[s3 + f]);
        float w0 = __expf(leaky(a0 + adh, 0.2f));
        float w1 = __expf(leaky(a1 + adh, 0.2f));
        float w2 = __expf(leaky(a2 + adh, 0.2f));
        float w3 = __expf(leaky(a3 + adh, 0.2f));
        acc += w0 * x0 + w1 * x1 + w2 * x2 + w3 * x3;
        den += w0 + w1 + w2 + w3;
    }
    for (; e < e1; ++e) {
        size_t s = (size_t)csr[e] * 16;
        float w = __expf(leaky(bf2f(rec[s + 9 + h]) + adh, 0.2f));
        acc += w * bf2f(rec[s + f]);
        den += w;
    }
    z[n * 36 + lane] = acc / (den + 1e-16f);
}

// ---- K8: g1 = bf16(leaky(z @ W_head + b_gat)) ----
__global__ void k_gat_out(const float* __restrict__ z, const float* __restrict__ Wg,
                          const float* __restrict__ bg, u16* __restrict__ g1) {
    __shared__ float Wf[FEAT * HC];
    __shared__ float zs[36];
    int t = threadIdx.x;  // 128
    for (int f = 0; f < FEAT; ++f) Wf[f * HC + t] = Wg[f * HC + t];
    float bias = bg[t];
    int h = t >> 5;
    int i0 = blockIdx.x * 64;
    for (int n = 0; n < 64; ++n) {
        int i = i0 + n;
        if (i >= NND) break;
        __syncthreads();
        if (t < 36) zs[t] = z[i * 36 + t];
        __syncthreads();
        float acc = bias;
#pragma unroll
        for (int f = 0; f < FEAT; ++f) acc += zs[h * 9 + f] * Wf[f * HC + t];
        g1[(size_t)i * HC + t] = f2bf(leaky(acc, 0.01f));
    }
}

// ---- K9: h2s = bf16(dinv * (g1 @ W2))  (N x 128 @ 128 x 64), g1 bf16 ----
__global__ void k_gemm_h2(const u16* __restrict__ g1, const float* __restrict__ W2,
                          const float* __restrict__ dinv, u16* __restrict__ h2) {
    __shared__ float Wf[128 * 64];
    __shared__ float rws[4][128];
    int t = threadIdx.x;  // 256
#pragma unroll
    for (int j = 0; j < 32; ++j) Wf[t + j * 256] = W2[t + j * 256];
    int rbase0 = blockIdx.x * 32;
    int sub = t >> 6, col = t & 63;
    for (int p = 0; p < 8; ++p) {
        int rbase = rbase0 + p * 4;
        __syncthreads();
        { int lr = t >> 7, k = t & 127;        rws[lr][k] = bf2f(g1[(size_t)(rbase + lr) * 128 + k]); }
        { int i2 = t + 256; int lr = i2 >> 7, k = i2 & 127; rws[lr][k] = bf2f(g1[(size_t)(rbase + lr) * 128 + k]); }
        __syncthreads();
        float acc = 0.f;
#pragma unroll
        for (int k = 0; k < 128; ++k) acc += rws[sub][k] * Wf[k * 64 + col];
        int row = rbase + sub;
        h2[(size_t)row * 64 + col] = f2bf(dinv[row] * acc);
    }
}

// ---- K10/K11: GCN aggregation (pre-scaled bf16 gather; wave per node, 64 ch) ----
// OUTMODE 1: bf16(dinv*leaky(dn*acc+bias)); OUTMODE 0: bf16(dn*acc)
template <int OUTMODE>
__global__ void k_gcn_g(const unsigned* __restrict__ rowptr, const unsigned* __restrict__ csr,
                        const float* __restrict__ dinv, const u16* __restrict__ hin,
                        const float* __restrict__ bias, u16* __restrict__ hout) {
    int n = blockIdx.x * 4 + (threadIdx.x >> 6);  // grid 25000 x 256 exact
    int lane = threadIdx.x & 63;
    unsigned e0 = rowptr[n], e1 = rowptr[n + 1];
    float acc = bf2f(hin[(size_t)n * 64 + lane]);  // self term (pre-scaled)
    unsigned e = e0;
    for (; e + 4 <= e1; e += 4) {
        unsigned s0 = csr[e], s1 = csr[e + 1], s2 = csr[e + 2], s3 = csr[e + 3];
        float h0 = bf2f(hin[(size_t)s0 * 64 + lane]);
        float h1 = bf2f(hin[(size_t)s1 * 64 + lane]);
        float h2 = bf2f(hin[(size_t)s2 * 64 + lane]);
        float h3 = bf2f(hin[(size_t)s3 * 64 + lane]);
        acc += h0 + h1 + h2 + h3;
    }
    for (; e < e1; ++e) acc += bf2f(hin[(size_t)csr[e] * 64 + lane]);
    float dn = dinv[n];
    float out = dn * acc;
    if (OUTMODE == 1) {
        out = leaky(out + bias[lane], 0.01f);
        hout[(size_t)n * 64 + lane] = f2bf(dn * out);  // pre-scale for layer 2
    } else {
        hout[(size_t)n * 64 + lane] = f2bf(out);
    }
}

// ---- K12: fused GEMM + mean-pool: pooled[b] += leaky(agg3 @ W3 + b3) per node ----
// 128 threads = 128 cols; W3 column in 64 VGPRs; 64 node-rows staged in LDS once.
__global__ __launch_bounds__(128) void k_gcn2_pool(const u16* __restrict__ agg3,
                                                   const float* __restrict__ W3,
                                                   const float* __restrict__ b3,
                                                   const int* __restrict__ batch,
                                                   float* __restrict__ pooled,
                                                   float* __restrict__ cnt) {
    __shared__ float rows[64][64];
    __shared__ int bts[64];
    int t = threadIdx.x;  // 128
    int n0 = blockIdx.x * 64;
    int nn = NND - n0; if (nn > 64) nn = 64;
    const unsigned* srcp = (const unsigned*)(agg3 + (size_t)n0 * 64);
    for (int i = t; i < nn * 32; i += 128) {
        unsigned u = srcp[i];
        ((float*)rows)[2 * i]     = bf2f((u16)(u & 0xffffu));
        ((float*)rows)[2 * i + 1] = bf2f((u16)(u >> 16));
    }
    if (t < nn) bts[t] = batch[n0 + t];
    float w[64];
#pragma unroll
    for (int k = 0; k < 64; ++k) w[k] = W3[k * 128 + t];
    float bc = b3[t];
    __syncthreads();
    float pacc = 0.f, pcnt = 0.f;
    int curb = -1;
    for (int j = 0; j < nn; ++j) {
        const float4* r4 = (const float4*)rows[j];
        float acc = bc;
#pragma unroll
        for (int kk = 0; kk < 16; ++kk) {
            float4 r = r4[kk];
            acc += r.x * w[4 * kk] + r.y * w[4 * kk + 1] + r.z * w[4 * kk + 2] + r.w * w[4 * kk + 3];
        }
        float g = leaky(acc, 0.01f);
        int b = bts[j];
        if (b != curb) {
            if (curb >= 0) {
                atomAdd(&pooled[curb * 128 + t], pacc);
                if (t == 0) atomAdd(&cnt[curb], pcnt);
            }
            curb = b; pacc = 0.f; pcnt = 0.f;
        }
        pacc += g; pcnt += 1.f;
    }
    if (curb >= 0) {
        atomAdd(&pooled[curb * 128 + t], pacc);
        if (t == 0) atomAdd(&cnt[curb], pcnt);
    }
}

// ---- K14: fused sequence branch -> sfc [B,64] ----
__global__ void k_seq(const float* __restrict__ seq, const float* __restrict__ w1, const float* __restrict__ c1b,
                      const float* __restrict__ w2, const float* __restrict__ c2b,
                      const float* __restrict__ g1n, const float* __restrict__ b1n,
                      const float* __restrict__ m1n, const float* __restrict__ v1n,
                      const float* __restrict__ g2n, const float* __restrict__ b2n,
                      const float* __restrict__ m2n, const float* __restrict__ v2n,
                      const float* __restrict__ fcW, const float* __restrict__ fcb,
                      float* __restrict__ sfc) {
    __shared__ float xs[30 * 20];
    __shared__ float y1[64 * 18];
    __shared__ float y2[64 * 16];
    __shared__ float red[4][64];
    int t = threadIdx.x;  // 256
    int b = blockIdx.x;
    for (int idx = t; idx < 600; idx += 256) xs[idx] = seq[b * 600 + idx];
    __syncthreads();
    for (int idx = t; idx < 64 * 18; idx += 256) {
        int o = idx / 18, l = idx - o * 18;
        float acc = c1b[o];
        for (int i = 0; i < 30; ++i)
#pragma unroll
            for (int k = 0; k < 3; ++k)
                acc += xs[i * 20 + l + k] * w1[o * 90 + i * 3 + k];
        float bn = (acc - m1n[o]) * rsqrtf(v1n[o] + 1e-5f) * g1n[o] + b1n[o];
        y1[idx] = leaky(bn, 0.01f);
    }
    __syncthreads();
    for (int idx = t; idx < 64 * 16; idx += 256) {
        int o = idx >> 4, l = idx & 15;
        float acc = c2b[o];
        for (int i = 0; i < 64; ++i)
#pragma unroll
            for (int k = 0; k < 3; ++k)
                acc += y1[i * 18 + l + k] * w2[o * 192 + i * 3 + k];
        float bn = (acc - m2n[o]) * rsqrtf(v2n[o] + 1e-5f) * g2n[o] + b2n[o];
        y2[idx] = leaky(bn, 0.01f);
    }
    __syncthreads();
    {
        int o = t & 63, part = t >> 6;
        float acc = 0.f;
        for (int j = part * 256; j < part * 256 + 256; ++j)
            acc += y2[j] * fcW[j * 64 + o];
        red[part][o] = acc;
    }
    __syncthreads();
    if (t < 64) sfc[b * 64 + t] = red[0][t] + red[1][t] + red[2][t] + red[3][t] + fcb[t];
}

// ---- K15: fusion + classifier -> out [B,1] f32 ----
__global__ void k_final(const float* __restrict__ pooled, const float* __restrict__ cnt,
                        const float* __restrict__ sfc,
                        const float* __restrict__ fusW, const float* __restrict__ fusb,
                        const float* __restrict__ c1W, const float* __restrict__ c1b,
                        const float* __restrict__ c3W, const float* __restrict__ c3b,
                        float* __restrict__ out) {
    __shared__ float comb[192];
    __shared__ float t1[128];
    int t = threadIdx.x;  // 128
    int b = blockIdx.x;
    float invc = 1.f / fmaxf(cnt[b], 1.f);
    comb[t] = pooled[b * 128 + t] * invc;
    if (t < 64) comb[128 + t] = sfc[b * 64 + t];
    __syncthreads();
    float acc = fusb[t];
    for (int k = 0; k < 192; ++k) acc += comb[k] * fusW[k * 128 + t];
    t1[t] = leaky(acc, 0.01f);
    __syncthreads();
    if (t < 64) {
        float a2 = c1b[t];
        for (int k = 0; k < 128; ++k) a2 += t1[k] * c1W[k * 64 + t];
        a2 = leaky(a2, 0.01f);
        float p = a2 * c3W[t];
#pragma unroll
        for (int off = 32; off; off >>= 1) p += __shfl_xor(p, off, 64);
        if (t == 0) out[b] = p + c3b[0];
    }
}

extern "C" void kernel_launch(void* const* d_in, const int* in_sizes, int n_in,
                              void* d_out, int out_size, void* d_ws, size_t ws_size,
                              hipStream_t stream) {
    const float* x     = (const float*)d_in[0];
    const int*   ei    = (const int*)d_in[1];
    const int*   batch = (const int*)d_in[2];
    const float* seq   = (const float*)d_in[3];
    const float* Wg    = (const float*)d_in[4];
    const float* attS  = (const float*)d_in[5];
    const float* attD  = (const float*)d_in[6];
    const float* bg    = (const float*)d_in[7];
    const float* W2    = (const float*)d_in[8];
    const float* b2    = (const float*)d_in[9];
    const float* W3    = (const float*)d_in[10];
    const float* b3    = (const float*)d_in[11];
    const float* c1w   = (const float*)d_in[12];
    const float* c1bb  = (const float*)d_in[13];
    const float* c2w   = (const float*)d_in[14];
    const float* c2bb  = (const float*)d_in[15];
    const float* bn1g  = (const float*)d_in[16];
    const float* bn1b  = (const float*)d_in[17];
    const float* bn1m  = (const float*)d_in[18];
    const float* bn1v  = (const float*)d_in[19];
    const float* bn2g  = (const float*)d_in[20];
    const float* bn2b  = (const float*)d_in[21];
    const float* bn2m  = (const float*)d_in[22];
    const float* bn2v  = (const float*)d_in[23];
    const float* fcW   = (const float*)d_in[24];
    const float* fcb   = (const float*)d_in[25];
    const float* fusW  = (const float*)d_in[26];
    const float* fusb  = (const float*)d_in[27];
    const float* cls1W = (const float*)d_in[28];
    const float* cls1b = (const float*)d_in[29];
    const float* cls3W = (const float*)d_in[30];
    const float* cls3b = (const float*)d_in[31];

    // ---- workspace arena ----
    char* wsb = (char*)d_ws;
    const size_t N = NND;
    float*    M      = (float*)wsb;                                  // 80
    float*    a_d    = M + 80;                                       // N*4 f32
    u16*      rec    = (u16*)(a_d + N * 4);                          // N*16 u16 (32B/node)
    float*    dinv   = (float*)(rec + N * 16);                       // N
    unsigned* bktCnt = (unsigned*)(dinv + N);                        // 256   } zero block
    float*    pooled = (float*)(bktCnt + 256);                       // B*128 }
    float*    cnt    = pooled + (size_t)NB * 128;                    // B     }
    unsigned* bktBase= (unsigned*)(cnt + NB);                        // 256
    unsigned* bktCur = bktBase + 256;                                // 256
    unsigned* rowptr = bktCur + 256;                                 // N+4
    unsigned* staging= rowptr + N + 4;                               // NED u32 (6.4MB)
    unsigned* csr    = staging + NED;                                // NED u32 (6.4MB)
    float*    z      = (float*)(csr + NED);                          // N*36 f32
    u16*      g1b    = (u16*)(z + N * 36);                           // N*128 bf16
    u16*      h2b    = g1b + N * 128;                                // N*64 bf16
    u16*      g2b    = h2b + N * 64;                                 // N*64 bf16
    u16*      agg3b  = g2b + N * 64;                                 // N*64 bf16
    float*    sfc    = (float*)(agg3b + N * 64);                     // B*64

    size_t zero_bytes = (256 + (size_t)NB * 128 + NB) * 4;
    hipMemsetAsync(bktCnt, 0, zero_bytes, stream);

    k_matt<<<1, 128, 0, stream>>>(Wg, attS, attD, M);
    k_att<<<(NND + 255) / 256, 256, 0, stream>>>(x, M, rec, a_d);
    k_bktcnt<<<(NED + 4095) / 4096, 1024, 0, stream>>>(ei, bktCnt);
    k_scanBkt<<<1, 256, 0, stream>>>(bktCnt, bktBase, bktCur, rowptr);
    k_bin<<<BIN_NBLK, 256, 0, stream>>>(ei, bktCur, staging);
    k_place<<<NBUCK, 512, 0, stream>>>(bktBase, bktCnt, staging, csr, rowptr, dinv);
    k_gat_g<<<NND / 4, 256, 0, stream>>>(rowptr, csr, rec, a_d, z);
    k_gat_out<<<(NND + 63) / 64, 128, 0, stream>>>(z, Wg, bg, g1b);
    k_gemm_h2<<<NND / 32, 256, 0, stream>>>(g1b, W2, dinv, h2b);
    k_gcn_g<1><<<NND / 4, 256, 0, stream>>>(rowptr, csr, dinv, h2b, b2, g2b);
    k_gcn_g<0><<<NND / 4, 256, 0, stream>>>(rowptr, csr, dinv, g2b, b2, agg3b);
    k_gcn2_pool<<<(NND + 63) / 64, 128, 0, stream>>>(agg3b, W3, b3, batch, pooled, cnt);
    k_seq<<<NB, 256, 0, stream>>>(seq, c1w, c1bb, c2w, c2bb, bn1g, bn1b, bn1m, bn1v,
                                  bn2g, bn2b, bn2m, bn2v, fcW, fcb, sfc);
    k_final<<<NB, 128, 0, stream>>>(pooled, cnt, sfc, fusW, fusb, cls1W, cls1b,
                                    cls3W, cls3b, (float*)d_out);
}

// Round 9
// 602.632 us; speedup vs baseline: 3.4855x; 1.0106x over previous
//
#include <hip/hip_runtime.h>

#define NND 100000
#define NED 1600000
#define NB  1024
#define FEAT 9
#define HC 128
#define NBUCK ((NND + 511) / 512)            // 196 buckets of 512 nodes
#define BINCHUNK 4096
#define BIN_NBLK ((NED + BINCHUNK - 1) / BINCHUNK)  // 391

typedef unsigned short u16;

__device__ __forceinline__ void atomAdd(float* p, float v) {
    __hip_atomic_fetch_add(p, v, __ATOMIC_RELAXED, __HIP_MEMORY_SCOPE_AGENT);
}
__device__ __forceinline__ unsigned atomAddU(unsigned* p, unsigned v) {
    return __hip_atomic_fetch_add(p, v, __ATOMIC_RELAXED, __HIP_MEMORY_SCOPE_AGENT);
}
__device__ __forceinline__ float leaky(float v, float s) { return v >= 0.f ? v : s * v; }
__device__ __forceinline__ float bf2f(u16 u) {
    union { unsigned i; float f; } x; x.i = ((unsigned)u) << 16; return x.f;
}
__device__ __forceinline__ u16 f2bf(float f) {
    union { float f; unsigned i; } x; x.f = f;
    return (u16)((x.i + 0x7fffu + ((x.i >> 16) & 1u)) >> 16);
}
__device__ __forceinline__ float bflo(unsigned u) {
    union { unsigned i; float f; } x; x.i = u << 16; return x.f;
}
__device__ __forceinline__ float bfhi(unsigned u) {
    union { unsigned i; float f; } x; x.i = u & 0xffff0000u; return x.f;
}

// ---- K1: M_s[f,h] = sum_c Wg[f,h*32+c]*attS[h,c]; same for M_d (one block) ----
__global__ void k_matt(const float* __restrict__ Wg, const float* __restrict__ attS,
                       const float* __restrict__ attD, float* __restrict__ M) {
    int t = threadIdx.x;  // 128, use 72
    if (t >= 72) return;
    int d = t >= 36 ? 1 : 0;
    int q = t - 36 * d;
    int f = q >> 2, h = q & 3;
    const float* av = d ? attD : attS;
    float s = 0.f;
#pragma unroll
    for (int c = 0; c < 32; ++c) s += Wg[f * HC + h * 32 + c] * av[h * 32 + c];
    M[d * 36 + q] = s;
}

// ---- K2: per-node 32B bf16 record rec = {x[9], a_s[4], pad[3]} + a_d f32 ----
__global__ void k_att(const float* __restrict__ x, const float* __restrict__ M,
                      u16* __restrict__ rec, float* __restrict__ a_d) {
    __shared__ float Ms[36], Md[36];
    int t = threadIdx.x;  // 256
    if (t < 36) Ms[t] = M[t];
    else if (t < 72) Md[t - 36] = M[t];
    __syncthreads();
    int n = blockIdx.x * 256 + t;
    if (n >= NND) return;
    float xv[FEAT];
#pragma unroll
    for (int f = 0; f < FEAT; ++f) xv[f] = x[n * FEAT + f];
    float s0 = 0, s1 = 0, s2 = 0, s3 = 0, d0 = 0, d1 = 0, d2 = 0, d3 = 0;
#pragma unroll
    for (int f = 0; f < FEAT; ++f) {
        float xf = xv[f];
        s0 += xf * Ms[f * 4 + 0]; s1 += xf * Ms[f * 4 + 1];
        s2 += xf * Ms[f * 4 + 2]; s3 += xf * Ms[f * 4 + 3];
        d0 += xf * Md[f * 4 + 0]; d1 += xf * Md[f * 4 + 1];
        d2 += xf * Md[f * 4 + 2]; d3 += xf * Md[f * 4 + 3];
    }
    u16 v[16];
#pragma unroll
    for (int f = 0; f < FEAT; ++f) v[f] = f2bf(xv[f]);
    v[9] = f2bf(s0); v[10] = f2bf(s1); v[11] = f2bf(s2); v[12] = f2bf(s3);
    v[13] = 0; v[14] = 0; v[15] = 0;
    unsigned pk[8];
#pragma unroll
    for (int i = 0; i < 8; ++i) pk[i] = (unsigned)v[2 * i] | ((unsigned)v[2 * i + 1] << 16);
    uint4* rp = (uint4*)(rec + (size_t)n * 16);
    rp[0] = make_uint4(pk[0], pk[1], pk[2], pk[3]);
    rp[1] = make_uint4(pk[4], pk[5], pk[6], pk[7]);
    ((float4*)a_d)[n] = make_float4(d0, d1, d2, d3);
}

// ---- K3: bucket-count histogram only (LDS-merged) ----
__global__ void k_bktcnt(const int* __restrict__ ei, unsigned* __restrict__ bktCnt) {
    __shared__ unsigned h[NBUCK];
    int t = threadIdx.x;  // 1024
    if (t < NBUCK) h[t] = 0;
    __syncthreads();
    int base = blockIdx.x * 4096;
#pragma unroll
    for (int k = 0; k < 4; ++k) {
        int i = base + t + k * 1024;
        if (i < NED) atomicAdd(&h[ei[NED + i] >> 9], 1u);
    }
    __syncthreads();
    if (t < NBUCK && h[t]) atomAddU(&bktCnt[t], h[t]);
}

// ---- K4: scan 196 bucket counts -> bktBase, bktCur; rowptr[NND]=NED ----
__global__ void k_scanBkt(const unsigned* __restrict__ bktCnt, unsigned* __restrict__ bktBase,
                          unsigned* __restrict__ bktCur, unsigned* __restrict__ rowptr) {
    __shared__ unsigned s[256];
    int t = threadIdx.x;  // 256
    s[t] = (t < NBUCK) ? bktCnt[t] : 0u;
    __syncthreads();
    for (int off = 1; off < 256; off <<= 1) {
        unsigned v = (t >= off) ? s[t - off] : 0u;
        __syncthreads();
        s[t] += v;
        __syncthreads();
    }
    if (t < NBUCK) {
        unsigned bb = (t == 0) ? 0u : s[t - 1];
        bktBase[t] = bb; bktCur[t] = bb;
    }
    if (t == 0) rowptr[NND] = NED;
}

// ---- K5: bin edges into bucket-major staging, packed (dstLocal<<17)|src ----
__global__ __launch_bounds__(256) void k_bin(const int* __restrict__ ei,
                                             unsigned* __restrict__ bktCursor,
                                             unsigned* __restrict__ staging) {
    __shared__ unsigned hist[NBUCK];
    __shared__ unsigned gbase[NBUCK];
    int t = threadIdx.x;
    if (t < NBUCK) hist[t] = 0;
    __syncthreads();
    int base = blockIdx.x * BINCHUNK;
    int lim = NED - base;
    int srcv[16], dstv[16];
#pragma unroll
    for (int k = 0; k < 16; ++k) {
        int i = t + k * 256;
        if (i < lim) {
            srcv[k] = ei[base + i];
            dstv[k] = ei[NED + base + i];
            atomicAdd(&hist[dstv[k] >> 9], 1u);
        } else dstv[k] = -1;
    }
    __syncthreads();
    if (t < NBUCK) {
        unsigned c = hist[t];
        gbase[t] = c ? atomAddU(&bktCursor[t], c) : 0u;
    }
    __syncthreads();
    if (t < NBUCK) hist[t] = 0;
    __syncthreads();
#pragma unroll
    for (int k = 0; k < 16; ++k) {
        if (dstv[k] >= 0) {
            int bk = dstv[k] >> 9;
            unsigned off = atomicAdd(&hist[bk], 1u);
            staging[gbase[bk] + off] = ((unsigned)(dstv[k] & 511) << 17) | (unsigned)srcv[k];
        }
    }
}

// ---- K6: per-bucket CSR build: LDS hist + scan -> rowptr/dinv; LDS cursor scatter ----
__global__ __launch_bounds__(512) void k_place(const unsigned* __restrict__ bktBase,
                                               const unsigned* __restrict__ bktCnt,
                                               const unsigned* __restrict__ staging,
                                               unsigned* __restrict__ csr,
                                               unsigned* __restrict__ rowptr,
                                               float* __restrict__ dinv) {
    __shared__ unsigned lh[512];
    __shared__ unsigned ls[512];
    int b = blockIdx.x, t = threadIdx.x;
    unsigned lo = bktBase[b], n = bktCnt[b];
    lh[t] = 0;
    __syncthreads();
    for (unsigned i = t; i < n; i += 512) atomicAdd(&lh[staging[lo + i] >> 17], 1u);
    __syncthreads();
    unsigned v = lh[t];
    ls[t] = v;
    __syncthreads();
    for (int off = 1; off < 512; off <<= 1) {
        unsigned u = (t >= off) ? ls[t - off] : 0u;
        __syncthreads();
        ls[t] += u;
        __syncthreads();
    }
    unsigned excl = ls[t] - v;
    int node = b * 512 + t;
    if (node < NND) {
        rowptr[node] = lo + excl;
        dinv[node] = rsqrtf((float)v + 1.f);
    }
    __syncthreads();
    lh[t] = excl;  // reuse as local cursor
    __syncthreads();
    for (unsigned i = t; i < n; i += 512) {
        unsigned p = staging[lo + i];
        unsigned pos = atomicAdd(&lh[p >> 17], 1u);
        csr[lo + pos] = p & 0x1FFFFu;
    }
}

// ---- K7: GAT aggregation + fused denom; 7 groups of 36 lanes per 256-thr block ----
__global__ __launch_bounds__(256) void k_gat_g(const unsigned* __restrict__ rowptr,
                                               const unsigned* __restrict__ csr,
                                               const u16* __restrict__ rec,
                                               const float* __restrict__ a_d,
                                               float* __restrict__ z) {
    int t = threadIdx.x;
    if (t >= 252) return;
    int g = t / 36, r = t - g * 36;
    int n = blockIdx.x * 7 + g;
    if (n >= NND) return;
    int h = r / 9, f = r - h * 9;
    unsigned e0 = rowptr[n], e1 = rowptr[n + 1];
    float adh = a_d[n * 4 + h];
    size_t q = (size_t)n * 16;
    float ws = __expf(leaky(bf2f(rec[q + 9 + h]) + adh, 0.2f));
    float acc = ws * bf2f(rec[q + f]);
    float den = ws;
    unsigned e = e0;
    for (; e + 4 <= e1; e += 4) {
        size_t s0 = (size_t)csr[e] * 16, s1 = (size_t)csr[e + 1] * 16;
        size_t s2 = (size_t)csr[e + 2] * 16, s3 = (size_t)csr[e + 3] * 16;
        float a0 = bf2f(rec[s0 + 9 + h]), x0 = bf2f(rec[s0 + f]);
        float a1 = bf2f(rec[s1 + 9 + h]), x1 = bf2f(rec[s1 + f]);
        float a2 = bf2f(rec[s2 + 9 + h]), x2 = bf2f(rec[s2 + f]);
        float a3 = bf2f(rec[s3 + 9 + h]), x3 = bf2f(rec[s3 + f]);
        float w0 = __expf(leaky(a0 + adh, 0.2f));
        float w1 = __expf(leaky(a1 + adh, 0.2f));
        float w2 = __expf(leaky(a2 + adh, 0.2f));
        float w3 = __expf(leaky(a3 + adh, 0.2f));
        acc += w0 * x0 + w1 * x1 + w2 * x2 + w3 * x3;
        den += w0 + w1 + w2 + w3;
    }
    for (; e < e1; ++e) {
        size_t s = (size_t)csr[e] * 16;
        float w = __expf(leaky(bf2f(rec[s + 9 + h]) + adh, 0.2f));
        acc += w * bf2f(rec[s + f]);
        den += w;
    }
    z[n * 36 + r] = acc / (den + 1e-16f);
}

// ---- K8: g1 = bf16(leaky(z @ W_head + b_gat)) ----
__global__ void k_gat_out(const float* __restrict__ z, const float* __restrict__ Wg,
                          const float* __restrict__ bg, u16* __restrict__ g1) {
    __shared__ float Wf[FEAT * HC];
    __shared__ float zs[36];
    int t = threadIdx.x;  // 128
    for (int f = 0; f < FEAT; ++f) Wf[f * HC + t] = Wg[f * HC + t];
    float bias = bg[t];
    int h = t >> 5;
    int i0 = blockIdx.x * 64;
    for (int n = 0; n < 64; ++n) {
        int i = i0 + n;
        if (i >= NND) break;
        __syncthreads();
        if (t < 36) zs[t] = z[i * 36 + t];
        __syncthreads();
        float acc = bias;
#pragma unroll
        for (int f = 0; f < FEAT; ++f) acc += zs[h * 9 + f] * Wf[f * HC + t];
        g1[(size_t)i * HC + t] = f2bf(leaky(acc, 0.01f));
    }
}

// ---- K9: h2s = bf16(dinv * (g1 @ W2)); W2 col in VGPRs, rows bf16 in LDS ----
// 256 thr = 4 waves; wave wv handles rows wv*16..+16 of the 64 staged rows.
__global__ __launch_bounds__(256) void k_gemm_h2(const u16* __restrict__ g1,
                                                 const float* __restrict__ W2,
                                                 const float* __restrict__ dinv,
                                                 u16* __restrict__ h2) {
    __shared__ u16 rows[64 * 128];  // 16 KB
    int t = threadIdx.x;
    int n0 = blockIdx.x * 64;
    const uint4* src = (const uint4*)(g1 + (size_t)n0 * 128);  // 1024 uint4
    uint4* dstS = (uint4*)rows;
    dstS[t] = src[t];
    dstS[t + 256] = src[t + 256];
    dstS[t + 512] = src[t + 512];
    dstS[t + 768] = src[t + 768];
    int col = t & 63;
    int wv = t >> 6;
    float w[128];
#pragma unroll
    for (int k = 0; k < 128; ++k) w[k] = W2[k * 64 + col];
    __syncthreads();
    int j0 = wv * 16;
    for (int j = j0; j < j0 + 16; ++j) {
        int row = n0 + j;
        if (row >= NND) break;
        const uint4* r4 = (const uint4*)(rows + j * 128);
        float acc = 0.f;
#pragma unroll
        for (int qq = 0; qq < 16; ++qq) {
            uint4 u = r4[qq];
            acc += bflo(u.x) * w[8 * qq]     + bfhi(u.x) * w[8 * qq + 1]
                 + bflo(u.y) * w[8 * qq + 2] + bfhi(u.y) * w[8 * qq + 3]
                 + bflo(u.z) * w[8 * qq + 4] + bfhi(u.z) * w[8 * qq + 5]
                 + bflo(u.w) * w[8 * qq + 6] + bfhi(u.w) * w[8 * qq + 7];
        }
        h2[(size_t)row * 64 + col] = f2bf(dinv[row] * acc);
    }
}

// ---- K10/K11: GCN aggregation (pre-scaled bf16 gather; wave per node, 64 ch) ----
// OUTMODE 1: bf16(dinv*leaky(dn*acc+bias)); OUTMODE 0: bf16(dn*acc)
template <int OUTMODE>
__global__ void k_gcn_g(const unsigned* __restrict__ rowptr, const unsigned* __restrict__ csr,
                        const float* __restrict__ dinv, const u16* __restrict__ hin,
                        const float* __restrict__ bias, u16* __restrict__ hout) {
    int n = blockIdx.x * 4 + (threadIdx.x >> 6);  // grid 25000 x 256 exact
    int lane = threadIdx.x & 63;
    unsigned e0 = rowptr[n], e1 = rowptr[n + 1];
    float acc = bf2f(hin[(size_t)n * 64 + lane]);  // self term (pre-scaled)
    unsigned e = e0;
    for (; e + 4 <= e1; e += 4) {
        unsigned s0 = csr[e], s1 = csr[e + 1], s2 = csr[e + 2], s3 = csr[e + 3];
        float h0 = bf2f(hin[(size_t)s0 * 64 + lane]);
        float h1 = bf2f(hin[(size_t)s1 * 64 + lane]);
        float h2 = bf2f(hin[(size_t)s2 * 64 + lane]);
        float h3 = bf2f(hin[(size_t)s3 * 64 + lane]);
        acc += h0 + h1 + h2 + h3;
    }
    for (; e < e1; ++e) acc += bf2f(hin[(size_t)csr[e] * 64 + lane]);
    float dn = dinv[n];
    float out = dn * acc;
    if (OUTMODE == 1) {
        out = leaky(out + bias[lane], 0.01f);
        hout[(size_t)n * 64 + lane] = f2bf(dn * out);  // pre-scale for layer 2
    } else {
        hout[(size_t)n * 64 + lane] = f2bf(out);
    }
}

// ---- K12: fused GEMM + mean-pool: pooled[b] += leaky(agg3 @ W3 + b3) per node ----
__global__ __launch_bounds__(128) void k_gcn2_pool(const u16* __restrict__ agg3,
                                                   const float* __restrict__ W3,
                                                   const float* __restrict__ b3,
                                                   const int* __restrict__ batch,
                                                   float* __restrict__ pooled,
                                                   float* __restrict__ cnt) {
    __shared__ float rows[64][64];
    __shared__ int bts[64];
    int t = threadIdx.x;  // 128
    int n0 = blockIdx.x * 64;
    int nn = NND - n0; if (nn > 64) nn = 64;
    const unsigned* srcp = (const unsigned*)(agg3 + (size_t)n0 * 64);
    for (int i = t; i < nn * 32; i += 128) {
        unsigned u = srcp[i];
        ((float*)rows)[2 * i]     = bf2f((u16)(u & 0xffffu));
        ((float*)rows)[2 * i + 1] = bf2f((u16)(u >> 16));
    }
    if (t < nn) bts[t] = batch[n0 + t];
    float w[64];
#pragma unroll
    for (int k = 0; k < 64; ++k) w[k] = W3[k * 128 + t];
    float bc = b3[t];
    __syncthreads();
    float pacc = 0.f, pcnt = 0.f;
    int curb = -1;
    for (int j = 0; j < nn; ++j) {
        const float4* r4 = (const float4*)rows[j];
        float acc = bc;
#pragma unroll
        for (int kk = 0; kk < 16; ++kk) {
            float4 r = r4[kk];
            acc += r.x * w[4 * kk] + r.y * w[4 * kk + 1] + r.z * w[4 * kk + 2] + r.w * w[4 * kk + 3];
        }
        float g = leaky(acc, 0.01f);
        int b = bts[j];
        if (b != curb) {
            if (curb >= 0) {
                atomAdd(&pooled[curb * 128 + t], pacc);
                if (t == 0) atomAdd(&cnt[curb], pcnt);
            }
            curb = b; pacc = 0.f; pcnt = 0.f;
        }
        pacc += g; pcnt += 1.f;
    }
    if (curb >= 0) {
        atomAdd(&pooled[curb * 128 + t], pacc);
        if (t == 0) atomAdd(&cnt[curb], pcnt);
    }
}

// ---- K14: fused sequence branch -> sfc [B,64] ----
__global__ void k_seq(const float* __restrict__ seq, const float* __restrict__ w1, const float* __restrict__ c1b,
                      const float* __restrict__ w2, const float* __restrict__ c2b,
                      const float* __restrict__ g1n, const float* __restrict__ b1n,
                      const float* __restrict__ m1n, const float* __restrict__ v1n,
                      const float* __restrict__ g2n, const float* __restrict__ b2n,
                      const float* __restrict__ m2n, const float* __restrict__ v2n,
                      const float* __restrict__ fcW, const float* __restrict__ fcb,
                      float* __restrict__ sfc) {
    __shared__ float xs[30 * 20];
    __shared__ float y1[64 * 18];
    __shared__ float y2[64 * 16];
    __shared__ float red[4][64];
    int t = threadIdx.x;  // 256
    int b = blockIdx.x;
    for (int idx = t; idx < 600; idx += 256) xs[idx] = seq[b * 600 + idx];
    __syncthreads();
    for (int idx = t; idx < 64 * 18; idx += 256) {
        int o = idx / 18, l = idx - o * 18;
        float acc = c1b[o];
        for (int i = 0; i < 30; ++i)
#pragma unroll
            for (int k = 0; k < 3; ++k)
                acc += xs[i * 20 + l + k] * w1[o * 90 + i * 3 + k];
        float bn = (acc - m1n[o]) * rsqrtf(v1n[o] + 1e-5f) * g1n[o] + b1n[o];
        y1[idx] = leaky(bn, 0.01f);
    }
    __syncthreads();
    for (int idx = t; idx < 64 * 16; idx += 256) {
        int o = idx >> 4, l = idx & 15;
        float acc = c2b[o];
        for (int i = 0; i < 64; ++i)
#pragma unroll
            for (int k = 0; k < 3; ++k)
                acc += y1[i * 18 + l + k] * w2[o * 192 + i * 3 + k];
        float bn = (acc - m2n[o]) * rsqrtf(v2n[o] + 1e-5f) * g2n[o] + b2n[o];
        y2[idx] = leaky(bn, 0.01f);
    }
    __syncthreads();
    {
        int o = t & 63, part = t >> 6;
        float acc = 0.f;
        for (int j = part * 256; j < part * 256 + 256; ++j)
            acc += y2[j] * fcW[j * 64 + o];
        red[part][o] = acc;
    }
    __syncthreads();
    if (t < 64) sfc[b * 64 + t] = red[0][t] + red[1][t] + red[2][t] + red[3][t] + fcb[t];
}

// ---- K15: fusion + classifier -> out [B,1] f32 ----
__global__ void k_final(const float* __restrict__ pooled, const float* __restrict__ cnt,
                        const float* __restrict__ sfc,
                        const float* __restrict__ fusW, const float* __restrict__ fusb,
                        const float* __restrict__ c1W, const float* __restrict__ c1b,
                        const float* __restrict__ c3W, const float* __restrict__ c3b,
                        float* __restrict__ out) {
    __shared__ float comb[192];
    __shared__ float t1[128];
    int t = threadIdx.x;  // 128
    int b = blockIdx.x;
    float invc = 1.f / fmaxf(cnt[b], 1.f);
    comb[t] = pooled[b * 128 + t] * invc;
    if (t < 64) comb[128 + t] = sfc[b * 64 + t];
    __syncthreads();
    float acc = fusb[t];
    for (int k = 0; k < 192; ++k) acc += comb[k] * fusW[k * 128 + t];
    t1[t] = leaky(acc, 0.01f);
    __syncthreads();
    if (t < 64) {
        float a2 = c1b[t];
        for (int k = 0; k < 128; ++k) a2 += t1[k] * c1W[k * 64 + t];
        a2 = leaky(a2, 0.01f);
        float p = a2 * c3W[t];
#pragma unroll
        for (int off = 32; off; off >>= 1) p += __shfl_xor(p, off, 64);
        if (t == 0) out[b] = p + c3b[0];
    }
}

extern "C" void kernel_launch(void* const* d_in, const int* in_sizes, int n_in,
                              void* d_out, int out_size, void* d_ws, size_t ws_size,
                              hipStream_t stream) {
    const float* x     = (const float*)d_in[0];
    const int*   ei    = (const int*)d_in[1];
    const int*   batch = (const int*)d_in[2];
    const float* seq   = (const float*)d_in[3];
    const float* Wg    = (const float*)d_in[4];
    const float* attS  = (const float*)d_in[5];
    const float* attD  = (const float*)d_in[6];
    const float* bg    = (const float*)d_in[7];
    const float* W2    = (const float*)d_in[8];
    const float* b2    = (const float*)d_in[9];
    const float* W3    = (const float*)d_in[10];
    const float* b3    = (const float*)d_in[11];
    const float* c1w   = (const float*)d_in[12];
    const float* c1bb  = (const float*)d_in[13];
    const float* c2w   = (const float*)d_in[14];
    const float* c2bb  = (const float*)d_in[15];
    const float* bn1g  = (const float*)d_in[16];
    const float* bn1b  = (const float*)d_in[17];
    const float* bn1m  = (const float*)d_in[18];
    const float* bn1v  = (const float*)d_in[19];
    const float* bn2g  = (const float*)d_in[20];
    const float* bn2b  = (const float*)d_in[21];
    const float* bn2m  = (const float*)d_in[22];
    const float* bn2v  = (const float*)d_in[23];
    const float* fcW   = (const float*)d_in[24];
    const float* fcb   = (const float*)d_in[25];
    const float* fusW  = (const float*)d_in[26];
    const float* fusb  = (const float*)d_in[27];
    const float* cls1W = (const float*)d_in[28];
    const float* cls1b = (const float*)d_in[29];
    const float* cls3W = (const float*)d_in[30];
    const float* cls3b = (const float*)d_in[31];

    // ---- workspace arena ----
    char* wsb = (char*)d_ws;
    const size_t N = NND;
    float*    M      = (float*)wsb;                                  // 80
    float*    a_d    = M + 80;                                       // N*4 f32
    u16*      rec    = (u16*)(a_d + N * 4);                          // N*16 u16 (32B/node)
    float*    dinv   = (float*)(rec + N * 16);                       // N
    unsigned* bktCnt = (unsigned*)(dinv + N);                        // 256   } zero block
    float*    pooled = (float*)(bktCnt + 256);                       // B*128 }
    float*    cnt    = pooled + (size_t)NB * 128;                    // B     }
    unsigned* bktBase= (unsigned*)(cnt + NB);                        // 256
    unsigned* bktCur = bktBase + 256;                                // 256
    unsigned* rowptr = bktCur + 256;                                 // N+4
    unsigned* staging= rowptr + N + 4;                               // NED u32 (6.4MB)
    unsigned* csr    = staging + NED;                                // NED u32 (6.4MB)
    float*    z      = (float*)(csr + NED);                          // N*36 f32
    u16*      g1b    = (u16*)(z + N * 36);                           // N*128 bf16
    u16*      h2b    = g1b + N * 128;                                // N*64 bf16 (+ slack: g_h2 may over-read staging)
    u16*      g2b    = h2b + N * 64;                                 // N*64 bf16
    u16*      agg3b  = g2b + N * 64;                                 // N*64 bf16
    float*    sfc    = (float*)(agg3b + N * 64);                     // B*64

    size_t zero_bytes = (256 + (size_t)NB * 128 + NB) * 4;
    hipMemsetAsync(bktCnt, 0, zero_bytes, stream);

    k_matt<<<1, 128, 0, stream>>>(Wg, attS, attD, M);
    k_att<<<(NND + 255) / 256, 256, 0, stream>>>(x, M, rec, a_d);
    k_bktcnt<<<(NED + 4095) / 4096, 1024, 0, stream>>>(ei, bktCnt);
    k_scanBkt<<<1, 256, 0, stream>>>(bktCnt, bktBase, bktCur, rowptr);
    k_bin<<<BIN_NBLK, 256, 0, stream>>>(ei, bktCur, staging);
    k_place<<<NBUCK, 512, 0, stream>>>(bktBase, bktCnt, staging, csr, rowptr, dinv);
    k_gat_g<<<(NND + 6) / 7, 256, 0, stream>>>(rowptr, csr, rec, a_d, z);
    k_gat_out<<<(NND + 63) / 64, 128, 0, stream>>>(z, Wg, bg, g1b);
    k_gemm_h2<<<(NND + 63) / 64, 256, 0, stream>>>(g1b, W2, dinv, h2b);
    k_gcn_g<1><<<NND / 4, 256, 0, stream>>>(rowptr, csr, dinv, h2b, b2, g2b);
    k_gcn_g<0><<<NND / 4, 256, 0, stream>>>(rowptr, csr, dinv, g2b, b2, agg3b);
    k_gcn2_pool<<<(NND + 63) / 64, 128, 0, stream>>>(agg3b, W3, b3, batch, pooled, cnt);
    k_seq<<<NB, 256, 0, stream>>>(seq, c1w, c1bb, c2w, c2bb, bn1g, bn1b, bn1m, bn1v,
                                  bn2g, bn2b, bn2m, bn2v, fcW, fcb, sfc);
    k_final<<<NB, 128, 0, stream>>>(pooled, cnt, sfc, fusW, fusb, cls1W, cls1b,
                                    cls3W, cls3b, (float*)d_out);
}

// Round 10
// 505.154 us; speedup vs baseline: 4.1581x; 1.1930x over previous
//
#include <hip/hip_runtime.h>

#define NND 100000
#define NED 1600000
#define NB  1024
#define FEAT 9
#define HC 128
#define NBUCK ((NND + 511) / 512)            // 196 buckets of 512 nodes
#define BINCHUNK 4096
#define BIN_NBLK ((NED + BINCHUNK - 1) / BINCHUNK)  // 391

typedef unsigned short u16;

__device__ __forceinline__ void atomAdd(float* p, float v) {
    __hip_atomic_fetch_add(p, v, __ATOMIC_RELAXED, __HIP_MEMORY_SCOPE_AGENT);
}
__device__ __forceinline__ unsigned atomAddU(unsigned* p, unsigned v) {
    return __hip_atomic_fetch_add(p, v, __ATOMIC_RELAXED, __HIP_MEMORY_SCOPE_AGENT);
}
__device__ __forceinline__ float leaky(float v, float s) { return v >= 0.f ? v : s * v; }
__device__ __forceinline__ float bf2f(u16 u) {
    union { unsigned i; float f; } x; x.i = ((unsigned)u) << 16; return x.f;
}
__device__ __forceinline__ u16 f2bf(float f) {
    union { float f; unsigned i; } x; x.f = f;
    return (u16)((x.i + 0x7fffu + ((x.i >> 16) & 1u)) >> 16);
}

// ---- K1: M_s[f,h] = sum_c Wg[f,h*32+c]*attS[h,c]; same for M_d (one block) ----
__global__ void k_matt(const float* __restrict__ Wg, const float* __restrict__ attS,
                       const float* __restrict__ attD, float* __restrict__ M) {
    int t = threadIdx.x;  // 128, use 72
    if (t >= 72) return;
    int d = t >= 36 ? 1 : 0;
    int q = t - 36 * d;
    int f = q >> 2, h = q & 3;
    const float* av = d ? attD : attS;
    float s = 0.f;
#pragma unroll
    for (int c = 0; c < 32; ++c) s += Wg[f * HC + h * 32 + c] * av[h * 32 + c];
    M[d * 36 + q] = s;
}

// ---- K1b: w2t[n][k] = bf16(W2[k][n]) for MFMA B-fragments ----
__global__ void k_w2t(const float* __restrict__ W2, u16* __restrict__ w2t) {
    int i = blockIdx.x * 256 + threadIdx.x;  // 8192
    int n = i >> 7, k = i & 127;
    w2t[i] = f2bf(W2[k * 64 + n]);
}

// ---- K2: per-node 32B bf16 record rec = {x[9], a_s[4], pad[3]} + a_d f32 ----
__global__ void k_att(const float* __restrict__ x, const float* __restrict__ M,
                      u16* __restrict__ rec, float* __restrict__ a_d) {
    __shared__ float Ms[36], Md[36];
    int t = threadIdx.x;  // 256
    if (t < 36) Ms[t] = M[t];
    else if (t < 72) Md[t - 36] = M[t];
    __syncthreads();
    int n = blockIdx.x * 256 + t;
    if (n >= NND) return;
    float xv[FEAT];
#pragma unroll
    for (int f = 0; f < FEAT; ++f) xv[f] = x[n * FEAT + f];
    float s0 = 0, s1 = 0, s2 = 0, s3 = 0, d0 = 0, d1 = 0, d2 = 0, d3 = 0;
#pragma unroll
    for (int f = 0; f < FEAT; ++f) {
        float xf = xv[f];
        s0 += xf * Ms[f * 4 + 0]; s1 += xf * Ms[f * 4 + 1];
        s2 += xf * Ms[f * 4 + 2]; s3 += xf * Ms[f * 4 + 3];
        d0 += xf * Md[f * 4 + 0]; d1 += xf * Md[f * 4 + 1];
        d2 += xf * Md[f * 4 + 2]; d3 += xf * Md[f * 4 + 3];
    }
    u16 v[16];
#pragma unroll
    for (int f = 0; f < FEAT; ++f) v[f] = f2bf(xv[f]);
    v[9] = f2bf(s0); v[10] = f2bf(s1); v[11] = f2bf(s2); v[12] = f2bf(s3);
    v[13] = 0; v[14] = 0; v[15] = 0;
    unsigned pk[8];
#pragma unroll
    for (int i = 0; i < 8; ++i) pk[i] = (unsigned)v[2 * i] | ((unsigned)v[2 * i + 1] << 16);
    uint4* rp = (uint4*)(rec + (size_t)n * 16);
    rp[0] = make_uint4(pk[0], pk[1], pk[2], pk[3]);
    rp[1] = make_uint4(pk[4], pk[5], pk[6], pk[7]);
    ((float4*)a_d)[n] = make_float4(d0, d1, d2, d3);
}

// ---- K3: bucket-count histogram only (LDS-merged) ----
__global__ void k_bktcnt(const int* __restrict__ ei, unsigned* __restrict__ bktCnt) {
    __shared__ unsigned h[NBUCK];
    int t = threadIdx.x;  // 1024
    if (t < NBUCK) h[t] = 0;
    __syncthreads();
    int base = blockIdx.x * 4096;
#pragma unroll
    for (int k = 0; k < 4; ++k) {
        int i = base + t + k * 1024;
        if (i < NED) atomicAdd(&h[ei[NED + i] >> 9], 1u);
    }
    __syncthreads();
    if (t < NBUCK && h[t]) atomAddU(&bktCnt[t], h[t]);
}

// ---- K4: scan 196 bucket counts -> bktBase, bktCur; rowptr[NND]=NED ----
__global__ void k_scanBkt(const unsigned* __restrict__ bktCnt, unsigned* __restrict__ bktBase,
                          unsigned* __restrict__ bktCur, unsigned* __restrict__ rowptr) {
    __shared__ unsigned s[256];
    int t = threadIdx.x;  // 256
    s[t] = (t < NBUCK) ? bktCnt[t] : 0u;
    __syncthreads();
    for (int off = 1; off < 256; off <<= 1) {
        unsigned v = (t >= off) ? s[t - off] : 0u;
        __syncthreads();
        s[t] += v;
        __syncthreads();
    }
    if (t < NBUCK) {
        unsigned bb = (t == 0) ? 0u : s[t - 1];
        bktBase[t] = bb; bktCur[t] = bb;
    }
    if (t == 0) rowptr[NND] = NED;
}

// ---- K5: bin edges into bucket-major staging, packed (dstLocal<<17)|src ----
__global__ __launch_bounds__(256) void k_bin(const int* __restrict__ ei,
                                             unsigned* __restrict__ bktCursor,
                                             unsigned* __restrict__ staging) {
    __shared__ unsigned hist[NBUCK];
    __shared__ unsigned gbase[NBUCK];
    int t = threadIdx.x;
    if (t < NBUCK) hist[t] = 0;
    __syncthreads();
    int base = blockIdx.x * BINCHUNK;
    int lim = NED - base;
    int srcv[16], dstv[16];
#pragma unroll
    for (int k = 0; k < 16; ++k) {
        int i = t + k * 256;
        if (i < lim) {
            srcv[k] = ei[base + i];
            dstv[k] = ei[NED + base + i];
            atomicAdd(&hist[dstv[k] >> 9], 1u);
        } else dstv[k] = -1;
    }
    __syncthreads();
    if (t < NBUCK) {
        unsigned c = hist[t];
        gbase[t] = c ? atomAddU(&bktCursor[t], c) : 0u;
    }
    __syncthreads();
    if (t < NBUCK) hist[t] = 0;
    __syncthreads();
#pragma unroll
    for (int k = 0; k < 16; ++k) {
        if (dstv[k] >= 0) {
            int bk = dstv[k] >> 9;
            unsigned off = atomicAdd(&hist[bk], 1u);
            staging[gbase[bk] + off] = ((unsigned)(dstv[k] & 511) << 17) | (unsigned)srcv[k];
        }
    }
}

// ---- K6: per-bucket CSR build: LDS hist + scan -> rowptr/dinv; LDS cursor scatter ----
__global__ __launch_bounds__(512) void k_place(const unsigned* __restrict__ bktBase,
                                               const unsigned* __restrict__ bktCnt,
                                               const unsigned* __restrict__ staging,
                                               unsigned* __restrict__ csr,
                                               unsigned* __restrict__ rowptr,
                                               float* __restrict__ dinv) {
    __shared__ unsigned lh[512];
    __shared__ unsigned ls[512];
    int b = blockIdx.x, t = threadIdx.x;
    unsigned lo = bktBase[b], n = bktCnt[b];
    lh[t] = 0;
    __syncthreads();
    for (unsigned i = t; i < n; i += 512) atomicAdd(&lh[staging[lo + i] >> 17], 1u);
    __syncthreads();
    unsigned v = lh[t];
    ls[t] = v;
    __syncthreads();
    for (int off = 1; off < 512; off <<= 1) {
        unsigned u = (t >= off) ? ls[t - off] : 0u;
        __syncthreads();
        ls[t] += u;
        __syncthreads();
    }
    unsigned excl = ls[t] - v;
    int node = b * 512 + t;
    if (node < NND) {
        rowptr[node] = lo + excl;
        dinv[node] = rsqrtf((float)v + 1.f);
    }
    __syncthreads();
    lh[t] = excl;  // reuse as local cursor
    __syncthreads();
    for (unsigned i = t; i < n; i += 512) {
        unsigned p = staging[lo + i];
        unsigned pos = atomicAdd(&lh[p >> 17], 1u);
        csr[lo + pos] = p & 0x1FFFFu;
    }
}

// ---- K7: GAT aggregation + fused denom; 7 groups of 36 lanes per 256-thr block ----
__global__ __launch_bounds__(256) void k_gat_g(const unsigned* __restrict__ rowptr,
                                               const unsigned* __restrict__ csr,
                                               const u16* __restrict__ rec,
                                               const float* __restrict__ a_d,
                                               float* __restrict__ z) {
    int t = threadIdx.x;
    if (t >= 252) return;
    int g = t / 36, r = t - g * 36;
    int n = blockIdx.x * 7 + g;
    if (n >= NND) return;
    int h = r / 9, f = r - h * 9;
    unsigned e0 = rowptr[n], e1 = rowptr[n + 1];
    float adh = a_d[n * 4 + h];
    size_t q = (size_t)n * 16;
    float ws = __expf(leaky(bf2f(rec[q + 9 + h]) + adh, 0.2f));
    float acc = ws * bf2f(rec[q + f]);
    float den = ws;
    unsigned e = e0;
    for (; e + 4 <= e1; e += 4) {
        size_t s0 = (size_t)csr[e] * 16, s1 = (size_t)csr[e + 1] * 16;
        size_t s2 = (size_t)csr[e + 2] * 16, s3 = (size_t)csr[e + 3] * 16;
        float a0 = bf2f(rec[s0 + 9 + h]), x0 = bf2f(rec[s0 + f]);
        float a1 = bf2f(rec[s1 + 9 + h]), x1 = bf2f(rec[s1 + f]);
        float a2 = bf2f(rec[s2 + 9 + h]), x2 = bf2f(rec[s2 + f]);
        float a3 = bf2f(rec[s3 + 9 + h]), x3 = bf2f(rec[s3 + f]);
        float w0 = __expf(leaky(a0 + adh, 0.2f));
        float w1 = __expf(leaky(a1 + adh, 0.2f));
        float w2 = __expf(leaky(a2 + adh, 0.2f));
        float w3 = __expf(leaky(a3 + adh, 0.2f));
        acc += w0 * x0 + w1 * x1 + w2 * x2 + w3 * x3;
        den += w0 + w1 + w2 + w3;
    }
    for (; e < e1; ++e) {
        size_t s = (size_t)csr[e] * 16;
        float w = __expf(leaky(bf2f(rec[s + 9 + h]) + adh, 0.2f));
        acc += w * bf2f(rec[s + f]);
        den += w;
    }
    z[n * 36 + r] = acc / (den + 1e-16f);
}

// ---- K9: fused g1 + MFMA GEMM: h2 = bf16(dinv*(leaky(z@Whead+bg) @ W2)) ----
// 64 rows/block; g1 tile in LDS bf16 [64][136] (pad -> 2-way bank alias, 16B rows);
// wave wv: 16-row tile, 4 col tiles, K=128 via 4x mfma_f32_16x16x32_bf16.
typedef __attribute__((ext_vector_type(8))) short bfrag;
typedef __attribute__((ext_vector_type(4))) float ffrag;
__global__ __launch_bounds__(256) void k_fused_h2(const float* __restrict__ z,
                                                  const float* __restrict__ Wg,
                                                  const float* __restrict__ bg,
                                                  const u16* __restrict__ w2t,
                                                  const float* __restrict__ dinv,
                                                  u16* __restrict__ h2) {
    __shared__ float zL[64 * 36];
    __shared__ float Wf[FEAT * HC];
    __shared__ float bgs[HC];
    __shared__ u16 g1L[64 * 136];
    int t = threadIdx.x;
    int n0 = blockIdx.x * 64;
    for (int i = t; i < 64 * 36; i += 256) {
        int row = i / 36;
        zL[i] = (n0 + row < NND) ? z[(size_t)(n0 + row) * 36 + (i - row * 36)] : 0.f;
    }
    for (int i = t; i < FEAT * HC; i += 256) Wf[i] = Wg[i];
    if (t < HC) bgs[t] = bg[t];
    __syncthreads();
    for (int e = t; e < 64 * 128; e += 256) {
        int row = e >> 7, col = e & 127;
        int h = col >> 5;
        float acc = bgs[col];
        const float* zr = zL + row * 36 + h * 9;
#pragma unroll
        for (int f = 0; f < 9; ++f) acc += zr[f] * Wf[f * 128 + col];
        g1L[row * 136 + col] = f2bf(leaky(acc, 0.01f));
    }
    __syncthreads();
    int l = t & 63, wv = t >> 6;
    int mr = l & 15, quad = l >> 4;
    union U { uint4 u; bfrag v; };
    bfrag a[4];
#pragma unroll
    for (int ks = 0; ks < 4; ++ks) {
        U uu; uu.u = *(const uint4*)(g1L + (wv * 16 + mr) * 136 + ks * 32 + quad * 8);
        a[ks] = uu.v;
    }
    ffrag acc[4];
#pragma unroll
    for (int ct = 0; ct < 4; ++ct) acc[ct] = (ffrag){0.f, 0.f, 0.f, 0.f};
#pragma unroll
    for (int ct = 0; ct < 4; ++ct) {
#pragma unroll
        for (int ks = 0; ks < 4; ++ks) {
            U ub; ub.u = *(const uint4*)(w2t + (ct * 16 + mr) * 128 + ks * 32 + quad * 8);
            acc[ct] = __builtin_amdgcn_mfma_f32_16x16x32_bf16(a[ks], ub.v, acc[ct], 0, 0, 0);
        }
    }
    int rbase = n0 + wv * 16 + quad * 4;
    if (rbase < NND) {  // NND%4==0 -> all 4 rows valid
        float4 d4 = *(const float4*)(dinv + rbase);
        const float dv[4] = {d4.x, d4.y, d4.z, d4.w};
#pragma unroll
        for (int ct = 0; ct < 4; ++ct)
#pragma unroll
            for (int r = 0; r < 4; ++r)
                h2[(size_t)(rbase + r) * 64 + ct * 16 + mr] = f2bf(dv[r] * acc[ct][r]);
    }
}

// ---- K10/K11: GCN aggregation (pre-scaled bf16 gather; wave per node, 64 ch) ----
// OUTMODE 1: bf16(dinv*leaky(dn*acc+bias)); OUTMODE 0: bf16(dn*acc)
template <int OUTMODE>
__global__ void k_gcn_g(const unsigned* __restrict__ rowptr, const unsigned* __restrict__ csr,
                        const float* __restrict__ dinv, const u16* __restrict__ hin,
                        const float* __restrict__ bias, u16* __restrict__ hout) {
    int n = blockIdx.x * 4 + (threadIdx.x >> 6);  // grid 25000 x 256 exact
    int lane = threadIdx.x & 63;
    unsigned e0 = rowptr[n], e1 = rowptr[n + 1];
    float acc = bf2f(hin[(size_t)n * 64 + lane]);  // self term (pre-scaled)
    unsigned e = e0;
    for (; e + 4 <= e1; e += 4) {
        unsigned s0 = csr[e], s1 = csr[e + 1], s2 = csr[e + 2], s3 = csr[e + 3];
        float h0 = bf2f(hin[(size_t)s0 * 64 + lane]);
        float h1 = bf2f(hin[(size_t)s1 * 64 + lane]);
        float h2 = bf2f(hin[(size_t)s2 * 64 + lane]);
        float h3 = bf2f(hin[(size_t)s3 * 64 + lane]);
        acc += h0 + h1 + h2 + h3;
    }
    for (; e < e1; ++e) acc += bf2f(hin[(size_t)csr[e] * 64 + lane]);
    float dn = dinv[n];
    float out = dn * acc;
    if (OUTMODE == 1) {
        out = leaky(out + bias[lane], 0.01f);
        hout[(size_t)n * 64 + lane] = f2bf(dn * out);  // pre-scale for layer 2
    } else {
        hout[(size_t)n * 64 + lane] = f2bf(out);
    }
}

// ---- K12: fused GEMM + mean-pool: pooled[b] += leaky(agg3 @ W3 + b3) per node ----
__global__ __launch_bounds__(128) void k_gcn2_pool(const u16* __restrict__ agg3,
                                                   const float* __restrict__ W3,
                                                   const float* __restrict__ b3,
                                                   const int* __restrict__ batch,
                                                   float* __restrict__ pooled,
                                                   float* __restrict__ cnt) {
    __shared__ float rows[64][64];
    __shared__ int bts[64];
    int t = threadIdx.x;  // 128
    int n0 = blockIdx.x * 64;
    int nn = NND - n0; if (nn > 64) nn = 64;
    const unsigned* srcp = (const unsigned*)(agg3 + (size_t)n0 * 64);
    for (int i = t; i < nn * 32; i += 128) {
        unsigned u = srcp[i];
        ((float*)rows)[2 * i]     = bf2f((u16)(u & 0xffffu));
        ((float*)rows)[2 * i + 1] = bf2f((u16)(u >> 16));
    }
    if (t < nn) bts[t] = batch[n0 + t];
    float w[64];
#pragma unroll
    for (int k = 0; k < 64; ++k) w[k] = W3[k * 128 + t];
    float bc = b3[t];
    __syncthreads();
    float pacc = 0.f, pcnt = 0.f;
    int curb = -1;
    for (int j = 0; j < nn; ++j) {
        const float4* r4 = (const float4*)rows[j];
        float acc = bc;
#pragma unroll
        for (int kk = 0; kk < 16; ++kk) {
            float4 r = r4[kk];
            acc += r.x * w[4 * kk] + r.y * w[4 * kk + 1] + r.z * w[4 * kk + 2] + r.w * w[4 * kk + 3];
        }
        float g = leaky(acc, 0.01f);
        int b = bts[j];
        if (b != curb) {
            if (curb >= 0) {
                atomAdd(&pooled[curb * 128 + t], pacc);
                if (t == 0) atomAdd(&cnt[curb], pcnt);
            }
            curb = b; pacc = 0.f; pcnt = 0.f;
        }
        pacc += g; pcnt += 1.f;
    }
    if (curb >= 0) {
        atomAdd(&pooled[curb * 128 + t], pacc);
        if (t == 0) atomAdd(&cnt[curb], pcnt);
    }
}

// ---- K14: fused sequence branch -> sfc [B,64] ----
__global__ void k_seq(const float* __restrict__ seq, const float* __restrict__ w1, const float* __restrict__ c1b,
                      const float* __restrict__ w2, const float* __restrict__ c2b,
                      const float* __restrict__ g1n, const float* __restrict__ b1n,
                      const float* __restrict__ m1n, const float* __restrict__ v1n,
                      const float* __restrict__ g2n, const float* __restrict__ b2n,
                      const float* __restrict__ m2n, const float* __restrict__ v2n,
                      const float* __restrict__ fcW, const float* __restrict__ fcb,
                      float* __restrict__ sfc) {
    __shared__ float xs[30 * 20];
    __shared__ float y1[64 * 18];
    __shared__ float y2[64 * 16];
    __shared__ float red[4][64];
    int t = threadIdx.x;  // 256
    int b = blockIdx.x;
    for (int idx = t; idx < 600; idx += 256) xs[idx] = seq[b * 600 + idx];
    __syncthreads();
    for (int idx = t; idx < 64 * 18; idx += 256) {
        int o = idx / 18, l = idx - o * 18;
        float acc = c1b[o];
        for (int i = 0; i < 30; ++i)
#pragma unroll
            for (int k = 0; k < 3; ++k)
                acc += xs[i * 20 + l + k] * w1[o * 90 + i * 3 + k];
        float bn = (acc - m1n[o]) * rsqrtf(v1n[o] + 1e-5f) * g1n[o] + b1n[o];
        y1[idx] = leaky(bn, 0.01f);
    }
    __syncthreads();
    for (int idx = t; idx < 64 * 16; idx += 256) {
        int o = idx >> 4, l = idx & 15;
        float acc = c2b[o];
        for (int i = 0; i < 64; ++i)
#pragma unroll
            for (int k = 0; k < 3; ++k)
                acc += y1[i * 18 + l + k] * w2[o * 192 + i * 3 + k];
        float bn = (acc - m2n[o]) * rsqrtf(v2n[o] + 1e-5f) * g2n[o] + b2n[o];
        y2[idx] = leaky(bn, 0.01f);
    }
    __syncthreads();
    {
        int o = t & 63, part = t >> 6;
        float acc = 0.f;
        for (int j = part * 256; j < part * 256 + 256; ++j)
            acc += y2[j] * fcW[j * 64 + o];
        red[part][o] = acc;
    }
    __syncthreads();
    if (t < 64) sfc[b * 64 + t] = red[0][t] + red[1][t] + red[2][t] + red[3][t] + fcb[t];
}

// ---- K15: fusion + classifier -> out [B,1] f32 ----
__global__ void k_final(const float* __restrict__ pooled, const float* __restrict__ cnt,
                        const float* __restrict__ sfc,
                        const float* __restrict__ fusW, const float* __restrict__ fusb,
                        const float* __restrict__ c1W, const float* __restrict__ c1b,
                        const float* __restrict__ c3W, const float* __restrict__ c3b,
                        float* __restrict__ out) {
    __shared__ float comb[192];
    __shared__ float t1[128];
    int t = threadIdx.x;  // 128
    int b = blockIdx.x;
    float invc = 1.f / fmaxf(cnt[b], 1.f);
    comb[t] = pooled[b * 128 + t] * invc;
    if (t < 64) comb[128 + t] = sfc[b * 64 + t];
    __syncthreads();
    float acc = fusb[t];
    for (int k = 0; k < 192; ++k) acc += comb[k] * fusW[k * 128 + t];
    t1[t] = leaky(acc, 0.01f);
    __syncthreads();
    if (t < 64) {
        float a2 = c1b[t];
        for (int k = 0; k < 128; ++k) a2 += t1[k] * c1W[k * 64 + t];
        a2 = leaky(a2, 0.01f);
        float p = a2 * c3W[t];
#pragma unroll
        for (int off = 32; off; off >>= 1) p += __shfl_xor(p, off, 64);
        if (t == 0) out[b] = p + c3b[0];
    }
}

extern "C" void kernel_launch(void* const* d_in, const int* in_sizes, int n_in,
                              void* d_out, int out_size, void* d_ws, size_t ws_size,
                              hipStream_t stream) {
    const float* x     = (const float*)d_in[0];
    const int*   ei    = (const int*)d_in[1];
    const int*   batch = (const int*)d_in[2];
    const float* seq   = (const float*)d_in[3];
    const float* Wg    = (const float*)d_in[4];
    const float* attS  = (const float*)d_in[5];
    const float* attD  = (const float*)d_in[6];
    const float* bg    = (const float*)d_in[7];
    const float* W2    = (const float*)d_in[8];
    const float* b2    = (const float*)d_in[9];
    const float* W3    = (const float*)d_in[10];
    const float* b3    = (const float*)d_in[11];
    const float* c1w   = (const float*)d_in[12];
    const float* c1bb  = (const float*)d_in[13];
    const float* c2w   = (const float*)d_in[14];
    const float* c2bb  = (const float*)d_in[15];
    const float* bn1g  = (const float*)d_in[16];
    const float* bn1b  = (const float*)d_in[17];
    const float* bn1m  = (const float*)d_in[18];
    const float* bn1v  = (const float*)d_in[19];
    const float* bn2g  = (const float*)d_in[20];
    const float* bn2b  = (const float*)d_in[21];
    const float* bn2m  = (const float*)d_in[22];
    const float* bn2v  = (const float*)d_in[23];
    const float* fcW   = (const float*)d_in[24];
    const float* fcb   = (const float*)d_in[25];
    const float* fusW  = (const float*)d_in[26];
    const float* fusb  = (const float*)d_in[27];
    const float* cls1W = (const float*)d_in[28];
    const float* cls1b = (const float*)d_in[29];
    const float* cls3W = (const float*)d_in[30];
    const float* cls3b = (const float*)d_in[31];

    // ---- workspace arena ----
    char* wsb = (char*)d_ws;
    const size_t N = NND;
    float*    M      = (float*)wsb;                                  // 80
    float*    a_d    = M + 80;                                       // N*4 f32
    u16*      rec    = (u16*)(a_d + N * 4);                          // N*16 u16 (32B/node)
    float*    dinv   = (float*)(rec + N * 16);                       // N
    unsigned* bktCnt = (unsigned*)(dinv + N);                        // 256   } zero block
    float*    pooled = (float*)(bktCnt + 256);                       // B*128 }
    float*    cnt    = pooled + (size_t)NB * 128;                    // B     }
    unsigned* bktBase= (unsigned*)(cnt + NB);                        // 256
    unsigned* bktCur = bktBase + 256;                                // 256
    unsigned* rowptr = bktCur + 256;                                 // N+4
    u16*      w2t    = (u16*)(rowptr + N + 4);                       // 8192 u16
    unsigned* staging= (unsigned*)(w2t + 8192);                      // NED u32 (6.4MB)
    unsigned* csr    = staging + NED;                                // NED u32 (6.4MB)
    float*    z      = (float*)(csr + NED);                          // N*36 f32 (+64 pad)
    u16*      h2b    = (u16*)(z + N * 36 + 64);                      // N*64 bf16
    u16*      g2b    = h2b + N * 64;                                 // N*64 bf16
    u16*      agg3b  = g2b + N * 64;                                 // N*64 bf16
    float*    sfc    = (float*)(agg3b + N * 64);                     // B*64

    size_t zero_bytes = (256 + (size_t)NB * 128 + NB) * 4;
    hipMemsetAsync(bktCnt, 0, zero_bytes, stream);

    k_matt<<<1, 128, 0, stream>>>(Wg, attS, attD, M);
    k_w2t<<<32, 256, 0, stream>>>(W2, w2t);
    k_att<<<(NND + 255) / 256, 256, 0, stream>>>(x, M, rec, a_d);
    k_bktcnt<<<(NED + 4095) / 4096, 1024, 0, stream>>>(ei, bktCnt);
    k_scanBkt<<<1, 256, 0, stream>>>(bktCnt, bktBase, bktCur, rowptr);
    k_bin<<<BIN_NBLK, 256, 0, stream>>>(ei, bktCur, staging);
    k_place<<<NBUCK, 512, 0, stream>>>(bktBase, bktCnt, staging, csr, rowptr, dinv);
    k_gat_g<<<(NND + 6) / 7, 256, 0, stream>>>(rowptr, csr, rec, a_d, z);
    k_fused_h2<<<(NND + 63) / 64, 256, 0, stream>>>(z, Wg, bg, w2t, dinv, h2b);
    k_gcn_g<1><<<NND / 4, 256, 0, stream>>>(rowptr, csr, dinv, h2b, b2, g2b);
    k_gcn_g<0><<<NND / 4, 256, 0, stream>>>(rowptr, csr, dinv, g2b, b2, agg3b);
    k_gcn2_pool<<<(NND + 63) / 64, 128, 0, stream>>>(agg3b, W3, b3, batch, pooled, cnt);
    k_seq<<<NB, 256, 0, stream>>>(seq, c1w, c1bb, c2w, c2bb, bn1g, bn1b, bn1m, bn1v,
                                  bn2g, bn2b, bn2m, bn2v, fcW, fcb, sfc);
    k_final<<<NB, 128, 0, stream>>>(pooled, cnt, sfc, fusW, fusb, cls1W, cls1b,
                                    cls3W, cls3b, (float*)d_out);
}

// Round 11
// 472.278 us; speedup vs baseline: 4.4476x; 1.0696x over previous
//
#include <hip/hip_runtime.h>

#define NND 100000
#define NED 1600000
#define NB  1024
#define FEAT 9
#define HC 128
#define NBUCK ((NND + 511) / 512)            // 196 buckets of 512 nodes
#define BCAP 12288u                          // fixed bucket capacity (mean 8192, +45 sigma)
#define BINCHUNK 4096
#define BIN_NBLK ((NED + BINCHUNK - 1) / BINCHUNK)  // 391

typedef unsigned short u16;

__device__ __forceinline__ void atomAdd(float* p, float v) {
    __hip_atomic_fetch_add(p, v, __ATOMIC_RELAXED, __HIP_MEMORY_SCOPE_AGENT);
}
__device__ __forceinline__ unsigned atomAddU(unsigned* p, unsigned v) {
    return __hip_atomic_fetch_add(p, v, __ATOMIC_RELAXED, __HIP_MEMORY_SCOPE_AGENT);
}
__device__ __forceinline__ float leaky(float v, float s) { return v >= 0.f ? v : s * v; }
__device__ __forceinline__ float bf2f(u16 u) {
    union { unsigned i; float f; } x; x.i = ((unsigned)u) << 16; return x.f;
}
__device__ __forceinline__ u16 f2bf(float f) {
    union { float f; unsigned i; } x; x.f = f;
    return (u16)((x.i + 0x7fffu + ((x.i >> 16) & 1u)) >> 16);
}
__device__ __forceinline__ float bflo(unsigned u) {
    union { unsigned i; float f; } x; x.i = u << 16; return x.f;
}
__device__ __forceinline__ float bfhi(unsigned u) {
    union { unsigned i; float f; } x; x.i = u & 0xffff0000u; return x.f;
}

// ---- K1: M_s[f,h] = sum_c Wg[f,h*32+c]*attS[h,c]; same for M_d (one block) ----
__global__ void k_matt(const float* __restrict__ Wg, const float* __restrict__ attS,
                       const float* __restrict__ attD, float* __restrict__ M) {
    int t = threadIdx.x;  // 128, use 72
    if (t >= 72) return;
    int d = t >= 36 ? 1 : 0;
    int q = t - 36 * d;
    int f = q >> 2, h = q & 3;
    const float* av = d ? attD : attS;
    float s = 0.f;
#pragma unroll
    for (int c = 0; c < 32; ++c) s += Wg[f * HC + h * 32 + c] * av[h * 32 + c];
    M[d * 36 + q] = s;
}

// ---- K1b: w2t[n][k] = bf16(W2[k][n]); also init bktCur[b] = b*BCAP ----
__global__ void k_w2t(const float* __restrict__ W2, u16* __restrict__ w2t,
                      unsigned* __restrict__ bktCur) {
    int i = blockIdx.x * 256 + threadIdx.x;  // 8192
    int n = i >> 7, k = i & 127;
    w2t[i] = f2bf(W2[k * 64 + n]);
    if (i < NBUCK) bktCur[i] = (unsigned)i * BCAP;
}

// ---- K2: per-node 32B bf16 record rec = {x[9], a_s[4], pad[3]} + a_d f32 ----
__global__ void k_att(const float* __restrict__ x, const float* __restrict__ M,
                      u16* __restrict__ rec, float* __restrict__ a_d) {
    __shared__ float Ms[36], Md[36];
    int t = threadIdx.x;  // 256
    if (t < 36) Ms[t] = M[t];
    else if (t < 72) Md[t - 36] = M[t];
    __syncthreads();
    int n = blockIdx.x * 256 + t;
    if (n >= NND) return;
    float xv[FEAT];
#pragma unroll
    for (int f = 0; f < FEAT; ++f) xv[f] = x[n * FEAT + f];
    float s0 = 0, s1 = 0, s2 = 0, s3 = 0, d0 = 0, d1 = 0, d2 = 0, d3 = 0;
#pragma unroll
    for (int f = 0; f < FEAT; ++f) {
        float xf = xv[f];
        s0 += xf * Ms[f * 4 + 0]; s1 += xf * Ms[f * 4 + 1];
        s2 += xf * Ms[f * 4 + 2]; s3 += xf * Ms[f * 4 + 3];
        d0 += xf * Md[f * 4 + 0]; d1 += xf * Md[f * 4 + 1];
        d2 += xf * Md[f * 4 + 2]; d3 += xf * Md[f * 4 + 3];
    }
    u16 v[16];
#pragma unroll
    for (int f = 0; f < FEAT; ++f) v[f] = f2bf(xv[f]);
    v[9] = f2bf(s0); v[10] = f2bf(s1); v[11] = f2bf(s2); v[12] = f2bf(s3);
    v[13] = 0; v[14] = 0; v[15] = 0;
    unsigned pk[8];
#pragma unroll
    for (int i = 0; i < 8; ++i) pk[i] = (unsigned)v[2 * i] | ((unsigned)v[2 * i + 1] << 16);
    uint4* rp = (uint4*)(rec + (size_t)n * 16);
    rp[0] = make_uint4(pk[0], pk[1], pk[2], pk[3]);
    rp[1] = make_uint4(pk[4], pk[5], pk[6], pk[7]);
    ((float4*)a_d)[n] = make_float4(d0, d1, d2, d3);
}

// ---- K5: bin edges into fixed-capacity bucket staging, packed (dstLocal<<17)|src ----
__global__ __launch_bounds__(256) void k_bin(const int* __restrict__ ei,
                                             unsigned* __restrict__ bktCursor,
                                             unsigned* __restrict__ staging) {
    __shared__ unsigned hist[NBUCK];
    __shared__ unsigned gbase[NBUCK];
    int t = threadIdx.x;
    if (t < NBUCK) hist[t] = 0;
    __syncthreads();
    int base = blockIdx.x * BINCHUNK;
    int lim = NED - base;
    int srcv[16], dstv[16];
#pragma unroll
    for (int k = 0; k < 16; ++k) {
        int i = t + k * 256;
        if (i < lim) {
            srcv[k] = ei[base + i];
            dstv[k] = ei[NED + base + i];
            atomicAdd(&hist[dstv[k] >> 9], 1u);
        } else dstv[k] = -1;
    }
    __syncthreads();
    if (t < NBUCK) {
        unsigned c = hist[t];
        gbase[t] = c ? atomAddU(&bktCursor[t], c) : 0u;
    }
    __syncthreads();
    if (t < NBUCK) hist[t] = 0;
    __syncthreads();
#pragma unroll
    for (int k = 0; k < 16; ++k) {
        if (dstv[k] >= 0) {
            int bk = dstv[k] >> 9;
            unsigned off = atomicAdd(&hist[bk], 1u);
            staging[gbase[bk] + off] = ((unsigned)(dstv[k] & 511) << 17) | (unsigned)srcv[k];
        }
    }
}

// ---- K6: per-bucket CSR build: LDS hist + scan -> rowptr/deg/dinv; cursor scatter ----
__global__ __launch_bounds__(512) void k_place(const unsigned* __restrict__ bktCur,
                                               const unsigned* __restrict__ staging,
                                               unsigned* __restrict__ csr,
                                               unsigned* __restrict__ rowptr,
                                               u16* __restrict__ degA,
                                               float* __restrict__ dinv) {
    __shared__ unsigned lh[512];
    __shared__ unsigned ls[512];
    int b = blockIdx.x, t = threadIdx.x;
    unsigned lo = (unsigned)b * BCAP;
    unsigned n = bktCur[b] - lo;
    lh[t] = 0;
    __syncthreads();
    for (unsigned i = t; i < n; i += 512) atomicAdd(&lh[staging[lo + i] >> 17], 1u);
    __syncthreads();
    unsigned v = lh[t];
    ls[t] = v;
    __syncthreads();
    for (int off = 1; off < 512; off <<= 1) {
        unsigned u = (t >= off) ? ls[t - off] : 0u;
        __syncthreads();
        ls[t] += u;
        __syncthreads();
    }
    unsigned excl = ls[t] - v;
    int node = b * 512 + t;
    if (node < NND) {
        rowptr[node] = lo + excl;
        degA[node] = (u16)v;
        dinv[node] = rsqrtf((float)v + 1.f);
    }
    __syncthreads();
    lh[t] = excl;  // reuse as local cursor
    __syncthreads();
    for (unsigned i = t; i < n; i += 512) {
        unsigned p = staging[lo + i];
        unsigned pos = atomicAdd(&lh[p >> 17], 1u);
        csr[lo + pos] = p & 0x1FFFFu;
    }
}

// ---- K7: GAT aggregation + fused denom; 7 groups of 36 lanes per 256-thr block ----
__global__ __launch_bounds__(256) void k_gat_g(const unsigned* __restrict__ rowptr,
                                               const u16* __restrict__ degA,
                                               const unsigned* __restrict__ csr,
                                               const u16* __restrict__ rec,
                                               const float* __restrict__ a_d,
                                               float* __restrict__ z) {
    int t = threadIdx.x;
    if (t >= 252) return;
    int g = t / 36, r = t - g * 36;
    int n = blockIdx.x * 7 + g;
    if (n >= NND) return;
    int h = r / 9, f = r - h * 9;
    unsigned e0 = rowptr[n], e1 = e0 + degA[n];
    float adh = a_d[n * 4 + h];
    size_t q = (size_t)n * 16;
    float ws = __expf(leaky(bf2f(rec[q + 9 + h]) + adh, 0.2f));
    float acc = ws * bf2f(rec[q + f]);
    float den = ws;
    unsigned e = e0;
    for (; e + 4 <= e1; e += 4) {
        size_t s0 = (size_t)csr[e] * 16, s1 = (size_t)csr[e + 1] * 16;
        size_t s2 = (size_t)csr[e + 2] * 16, s3 = (size_t)csr[e + 3] * 16;
        float a0 = bf2f(rec[s0 + 9 + h]), x0 = bf2f(rec[s0 + f]);
        float a1 = bf2f(rec[s1 + 9 + h]), x1 = bf2f(rec[s1 + f]);
        float a2 = bf2f(rec[s2 + 9 + h]), x2 = bf2f(rec[s2 + f]);
        float a3 = bf2f(rec[s3 + 9 + h]), x3 = bf2f(rec[s3 + f]);
        float w0 = __expf(leaky(a0 + adh, 0.2f));
        float w1 = __expf(leaky(a1 + adh, 0.2f));
        float w2 = __expf(leaky(a2 + adh, 0.2f));
        float w3 = __expf(leaky(a3 + adh, 0.2f));
        acc += w0 * x0 + w1 * x1 + w2 * x2 + w3 * x3;
        den += w0 + w1 + w2 + w3;
    }
    for (; e < e1; ++e) {
        size_t s = (size_t)csr[e] * 16;
        float w = __expf(leaky(bf2f(rec[s + 9 + h]) + adh, 0.2f));
        acc += w * bf2f(rec[s + f]);
        den += w;
    }
    z[n * 36 + r] = acc / (den + 1e-16f);
}

// ---- K9: fused g1 + MFMA GEMM: h2 = bf16(dinv*(leaky(z@Whead+bg) @ W2)) ----
typedef __attribute__((ext_vector_type(8))) short bfrag;
typedef __attribute__((ext_vector_type(4))) float ffrag;
__global__ __launch_bounds__(256) void k_fused_h2(const float* __restrict__ z,
                                                  const float* __restrict__ Wg,
                                                  const float* __restrict__ bg,
                                                  const u16* __restrict__ w2t,
                                                  const float* __restrict__ dinv,
                                                  u16* __restrict__ h2) {
    __shared__ float zL[64 * 36];
    __shared__ float Wf[FEAT * HC];
    __shared__ float bgs[HC];
    __shared__ u16 g1L[64 * 136];
    int t = threadIdx.x;
    int n0 = blockIdx.x * 64;
    for (int i = t; i < 64 * 36; i += 256) {
        int row = i / 36;
        zL[i] = (n0 + row < NND) ? z[(size_t)(n0 + row) * 36 + (i - row * 36)] : 0.f;
    }
    for (int i = t; i < FEAT * HC; i += 256) Wf[i] = Wg[i];
    if (t < HC) bgs[t] = bg[t];
    __syncthreads();
    for (int e = t; e < 64 * 128; e += 256) {
        int row = e >> 7, col = e & 127;
        int h = col >> 5;
        float acc = bgs[col];
        const float* zr = zL + row * 36 + h * 9;
#pragma unroll
        for (int f = 0; f < 9; ++f) acc += zr[f] * Wf[f * 128 + col];
        g1L[row * 136 + col] = f2bf(leaky(acc, 0.01f));
    }
    __syncthreads();
    int l = t & 63, wv = t >> 6;
    int mr = l & 15, quad = l >> 4;
    union U { uint4 u; bfrag v; };
    bfrag a[4];
#pragma unroll
    for (int ks = 0; ks < 4; ++ks) {
        U uu; uu.u = *(const uint4*)(g1L + (wv * 16 + mr) * 136 + ks * 32 + quad * 8);
        a[ks] = uu.v;
    }
    ffrag acc[4];
#pragma unroll
    for (int ct = 0; ct < 4; ++ct) acc[ct] = (ffrag){0.f, 0.f, 0.f, 0.f};
#pragma unroll
    for (int ct = 0; ct < 4; ++ct) {
#pragma unroll
        for (int ks = 0; ks < 4; ++ks) {
            U ub; ub.u = *(const uint4*)(w2t + (ct * 16 + mr) * 128 + ks * 32 + quad * 8);
            acc[ct] = __builtin_amdgcn_mfma_f32_16x16x32_bf16(a[ks], ub.v, acc[ct], 0, 0, 0);
        }
    }
    int rbase = n0 + wv * 16 + quad * 4;
    if (rbase < NND) {
        float4 d4 = *(const float4*)(dinv + rbase);
        const float dv[4] = {d4.x, d4.y, d4.z, d4.w};
#pragma unroll
        for (int ct = 0; ct < 4; ++ct)
#pragma unroll
            for (int r = 0; r < 4; ++r)
                h2[(size_t)(rbase + r) * 64 + ct * 16 + mr] = f2bf(dv[r] * acc[ct][r]);
    }
}

// ---- K10/K11: GCN aggregation, paired-edge 32-bit loads ----
// wave per node: lanes 0-31 even edges, lanes 32-63 odd edges; lane c = channels 2c,2c+1.
// OUTMODE 1: bf16(dinv*leaky(dn*acc+bias)); OUTMODE 0: bf16(dn*acc)
template <int OUTMODE>
__global__ void k_gcn_g(const unsigned* __restrict__ rowptr, const u16* __restrict__ degA,
                        const unsigned* __restrict__ csr,
                        const float* __restrict__ dinv, const u16* __restrict__ hin,
                        const float* __restrict__ bias, u16* __restrict__ hout) {
    int n = blockIdx.x * 4 + (threadIdx.x >> 6);  // grid 25000 x 256 exact
    int l = threadIdx.x & 63;
    int half = l >> 5;
    int c = l & 31;
    unsigned e0 = rowptr[n];
    unsigned e1 = e0 + degA[n];
    const unsigned* hinU = (const unsigned*)hin;
    float acc0 = 0.f, acc1 = 0.f;
    if (half == 0) {  // self term (pre-scaled at producer)
        unsigned u = hinU[(size_t)n * 32 + c];
        acc0 = bflo(u); acc1 = bfhi(u);
    }
    unsigned e = e0;
    for (; e + 8 <= e1; e += 8) {
        unsigned i0 = csr[e + half];
        unsigned i1 = csr[e + 2 + half];
        unsigned i2 = csr[e + 4 + half];
        unsigned i3 = csr[e + 6 + half];
        unsigned u0 = hinU[(size_t)i0 * 32 + c];
        unsigned u1 = hinU[(size_t)i1 * 32 + c];
        unsigned u2 = hinU[(size_t)i2 * 32 + c];
        unsigned u3 = hinU[(size_t)i3 * 32 + c];
        acc0 += bflo(u0) + bflo(u1) + bflo(u2) + bflo(u3);
        acc1 += bfhi(u0) + bfhi(u1) + bfhi(u2) + bfhi(u3);
    }
    for (; e + 2 <= e1; e += 2) {
        unsigned u = hinU[(size_t)csr[e + half] * 32 + c];
        acc0 += bflo(u); acc1 += bfhi(u);
    }
    if (e < e1 && half == 0) {
        unsigned u = hinU[(size_t)csr[e] * 32 + c];
        acc0 += bflo(u); acc1 += bfhi(u);
    }
    acc0 += __shfl_xor(acc0, 32, 64);
    acc1 += __shfl_xor(acc1, 32, 64);
    if (half == 0) {
        float dn = dinv[n];
        float o0 = dn * acc0, o1 = dn * acc1;
        if (OUTMODE == 1) {
            o0 = leaky(o0 + bias[2 * c], 0.01f) * dn;      // pre-scale for layer 2
            o1 = leaky(o1 + bias[2 * c + 1], 0.01f) * dn;
        }
        unsigned pk = (unsigned)f2bf(o0) | ((unsigned)f2bf(o1) << 16);
        ((unsigned*)hout)[(size_t)n * 32 + c] = pk;
    }
}

// ---- K12: fused GEMM + mean-pool: pooled[b] += leaky(agg3 @ W3 + b3) per node ----
__global__ __launch_bounds__(128) void k_gcn2_pool(const u16* __restrict__ agg3,
                                                   const float* __restrict__ W3,
                                                   const float* __restrict__ b3,
                                                   const int* __restrict__ batch,
                                                   float* __restrict__ pooled,
                                                   float* __restrict__ cnt) {
    __shared__ float rows[64][64];
    __shared__ int bts[64];
    int t = threadIdx.x;  // 128
    int n0 = blockIdx.x * 64;
    int nn = NND - n0; if (nn > 64) nn = 64;
    const unsigned* srcp = (const unsigned*)(agg3 + (size_t)n0 * 64);
    for (int i = t; i < nn * 32; i += 128) {
        unsigned u = srcp[i];
        ((float*)rows)[2 * i]     = bf2f((u16)(u & 0xffffu));
        ((float*)rows)[2 * i + 1] = bf2f((u16)(u >> 16));
    }
    if (t < nn) bts[t] = batch[n0 + t];
    float w[64];
#pragma unroll
    for (int k = 0; k < 64; ++k) w[k] = W3[k * 128 + t];
    float bc = b3[t];
    __syncthreads();
    float pacc = 0.f, pcnt = 0.f;
    int curb = -1;
    for (int j = 0; j < nn; ++j) {
        const float4* r4 = (const float4*)rows[j];
        float acc = bc;
#pragma unroll
        for (int kk = 0; kk < 16; ++kk) {
            float4 r = r4[kk];
            acc += r.x * w[4 * kk] + r.y * w[4 * kk + 1] + r.z * w[4 * kk + 2] + r.w * w[4 * kk + 3];
        }
        float g = leaky(acc, 0.01f);
        int b = bts[j];
        if (b != curb) {
            if (curb >= 0) {
                atomAdd(&pooled[curb * 128 + t], pacc);
                if (t == 0) atomAdd(&cnt[curb], pcnt);
            }
            curb = b; pacc = 0.f; pcnt = 0.f;
        }
        pacc += g; pcnt += 1.f;
    }
    if (curb >= 0) {
        atomAdd(&pooled[curb * 128 + t], pacc);
        if (t == 0) atomAdd(&cnt[curb], pcnt);
    }
}

// ---- K14: fused sequence branch -> sfc [B,64] ----
__global__ void k_seq(const float* __restrict__ seq, const float* __restrict__ w1, const float* __restrict__ c1b,
                      const float* __restrict__ w2, const float* __restrict__ c2b,
                      const float* __restrict__ g1n, const float* __restrict__ b1n,
                      const float* __restrict__ m1n, const float* __restrict__ v1n,
                      const float* __restrict__ g2n, const float* __restrict__ b2n,
                      const float* __restrict__ m2n, const float* __restrict__ v2n,
                      const float* __restrict__ fcW, const float* __restrict__ fcb,
                      float* __restrict__ sfc) {
    __shared__ float xs[30 * 20];
    __shared__ float y1[64 * 18];
    __shared__ float y2[64 * 16];
    __shared__ float red[4][64];
    int t = threadIdx.x;  // 256
    int b = blockIdx.x;
    for (int idx = t; idx < 600; idx += 256) xs[idx] = seq[b * 600 + idx];
    __syncthreads();
    for (int idx = t; idx < 64 * 18; idx += 256) {
        int o = idx / 18, l = idx - o * 18;
        float acc = c1b[o];
        for (int i = 0; i < 30; ++i)
#pragma unroll
            for (int k = 0; k < 3; ++k)
                acc += xs[i * 20 + l + k] * w1[o * 90 + i * 3 + k];
        float bn = (acc - m1n[o]) * rsqrtf(v1n[o] + 1e-5f) * g1n[o] + b1n[o];
        y1[idx] = leaky(bn, 0.01f);
    }
    __syncthreads();
    for (int idx = t; idx < 64 * 16; idx += 256) {
        int o = idx >> 4, l = idx & 15;
        float acc = c2b[o];
        for (int i = 0; i < 64; ++i)
#pragma unroll
            for (int k = 0; k < 3; ++k)
                acc += y1[i * 18 + l + k] * w2[o * 192 + i * 3 + k];
        float bn = (acc - m2n[o]) * rsqrtf(v2n[o] + 1e-5f) * g2n[o] + b2n[o];
        y2[idx] = leaky(bn, 0.01f);
    }
    __syncthreads();
    {
        int o = t & 63, part = t >> 6;
        float acc = 0.f;
        for (int j = part * 256; j < part * 256 + 256; ++j)
            acc += y2[j] * fcW[j * 64 + o];
        red[part][o] = acc;
    }
    __syncthreads();
    if (t < 64) sfc[b * 64 + t] = red[0][t] + red[1][t] + red[2][t] + red[3][t] + fcb[t];
}

// ---- K15: fusion + classifier -> out [B,1] f32 ----
__global__ void k_final(const float* __restrict__ pooled, const float* __restrict__ cnt,
                        const float* __restrict__ sfc,
                        const float* __restrict__ fusW, const float* __restrict__ fusb,
                        const float* __restrict__ c1W, const float* __restrict__ c1b,
                        const float* __restrict__ c3W, const float* __restrict__ c3b,
                        float* __restrict__ out) {
    __shared__ float comb[192];
    __shared__ float t1[128];
    int t = threadIdx.x;  // 128
    int b = blockIdx.x;
    float invc = 1.f / fmaxf(cnt[b], 1.f);
    comb[t] = pooled[b * 128 + t] * invc;
    if (t < 64) comb[128 + t] = sfc[b * 64 + t];
    __syncthreads();
    float acc = fusb[t];
    for (int k = 0; k < 192; ++k) acc += comb[k] * fusW[k * 128 + t];
    t1[t] = leaky(acc, 0.01f);
    __syncthreads();
    if (t < 64) {
        float a2 = c1b[t];
        for (int k = 0; k < 128; ++k) a2 += t1[k] * c1W[k * 64 + t];
        a2 = leaky(a2, 0.01f);
        float p = a2 * c3W[t];
#pragma unroll
        for (int off = 32; off; off >>= 1) p += __shfl_xor(p, off, 64);
        if (t == 0) out[b] = p + c3b[0];
    }
}

extern "C" void kernel_launch(void* const* d_in, const int* in_sizes, int n_in,
                              void* d_out, int out_size, void* d_ws, size_t ws_size,
                              hipStream_t stream) {
    const float* x     = (const float*)d_in[0];
    const int*   ei    = (const int*)d_in[1];
    const int*   batch = (const int*)d_in[2];
    const float* seq   = (const float*)d_in[3];
    const float* Wg    = (const float*)d_in[4];
    const float* attS  = (const float*)d_in[5];
    const float* attD  = (const float*)d_in[6];
    const float* bg    = (const float*)d_in[7];
    const float* W2    = (const float*)d_in[8];
    const float* b2    = (const float*)d_in[9];
    const float* W3    = (const float*)d_in[10];
    const float* b3    = (const float*)d_in[11];
    const float* c1w   = (const float*)d_in[12];
    const float* c1bb  = (const float*)d_in[13];
    const float* c2w   = (const float*)d_in[14];
    const float* c2bb  = (const float*)d_in[15];
    const float* bn1g  = (const float*)d_in[16];
    const float* bn1b  = (const float*)d_in[17];
    const float* bn1m  = (const float*)d_in[18];
    const float* bn1v  = (const float*)d_in[19];
    const float* bn2g  = (const float*)d_in[20];
    const float* bn2b  = (const float*)d_in[21];
    const float* bn2m  = (const float*)d_in[22];
    const float* bn2v  = (const float*)d_in[23];
    const float* fcW   = (const float*)d_in[24];
    const float* fcb   = (const float*)d_in[25];
    const float* fusW  = (const float*)d_in[26];
    const float* fusb  = (const float*)d_in[27];
    const float* cls1W = (const float*)d_in[28];
    const float* cls1b = (const float*)d_in[29];
    const float* cls3W = (const float*)d_in[30];
    const float* cls3b = (const float*)d_in[31];

    // ---- workspace arena ----
    char* wsb = (char*)d_ws;
    const size_t N = NND;
    float*    M      = (float*)wsb;                                  // 80
    float*    a_d    = M + 80;                                       // N*4 f32
    u16*      rec    = (u16*)(a_d + N * 4);                          // N*16 u16 (32B/node)
    float*    dinv   = (float*)(rec + N * 16);                       // N
    float*    pooled = dinv + N;                                     // B*128 } zero block
    float*    cnt    = pooled + (size_t)NB * 128;                    // B     }
    unsigned* bktCur = (unsigned*)(cnt + NB);                        // 256
    unsigned* rowptr = bktCur + 256;                                 // N
    u16*      degA   = (u16*)(rowptr + N);                           // N u16 (+pad)
    u16*      w2t    = degA + N + 8;                                 // 8192 u16
    unsigned* staging= (unsigned*)(w2t + 8192);                      // NBUCK*BCAP u32 (9.6MB)
    unsigned* csr    = staging + (size_t)NBUCK * BCAP;               // NBUCK*BCAP u32 (9.6MB)
    float*    z      = (float*)(csr + (size_t)NBUCK * BCAP);         // N*36 f32 (+64 pad)
    u16*      h2b    = (u16*)(z + N * 36 + 64);                      // N*64 bf16
    u16*      g2b    = h2b + N * 64;                                 // N*64 bf16
    u16*      agg3b  = g2b + N * 64;                                 // N*64 bf16
    float*    sfc    = (float*)(agg3b + N * 64);                     // B*64

    size_t zero_bytes = ((size_t)NB * 128 + NB) * 4;
    hipMemsetAsync(pooled, 0, zero_bytes, stream);

    k_matt<<<1, 128, 0, stream>>>(Wg, attS, attD, M);
    k_w2t<<<32, 256, 0, stream>>>(W2, w2t, bktCur);
    k_att<<<(NND + 255) / 256, 256, 0, stream>>>(x, M, rec, a_d);
    k_bin<<<BIN_NBLK, 256, 0, stream>>>(ei, bktCur, staging);
    k_place<<<NBUCK, 512, 0, stream>>>(bktCur, staging, csr, rowptr, degA, dinv);
    k_gat_g<<<(NND + 6) / 7, 256, 0, stream>>>(rowptr, degA, csr, rec, a_d, z);
    k_fused_h2<<<(NND + 63) / 64, 256, 0, stream>>>(z, Wg, bg, w2t, dinv, h2b);
    k_gcn_g<1><<<NND / 4, 256, 0, stream>>>(rowptr, degA, csr, dinv, h2b, b2, g2b);
    k_gcn_g<0><<<NND / 4, 256, 0, stream>>>(rowptr, degA, csr, dinv, g2b, b2, agg3b);
    k_gcn2_pool<<<(NND + 63) / 64, 128, 0, stream>>>(agg3b, W3, b3, batch, pooled, cnt);
    k_seq<<<NB, 256, 0, stream>>>(seq, c1w, c1bb, c2w, c2bb, bn1g, bn1b, bn1m, bn1v,
                                  bn2g, bn2b, bn2m, bn2v, fcW, fcb, sfc);
    k_final<<<NB, 128, 0, stream>>>(pooled, cnt, sfc, fusW, fusb, cls1W, cls1b,
                                    cls3W, cls3b, (float*)d_out);
}

// Round 12
// 455.520 us; speedup vs baseline: 4.6112x; 1.0368x over previous
//
#include <hip/hip_runtime.h>

#define NND 100000
#define NED 1600000
#define NB  1024
#define FEAT 9
#define HC 128
#define NBUCK ((NND + 511) / 512)            // 196 buckets of 512 nodes
#define BCAP 12288u                          // fixed bucket capacity (mean 8192, +45 sigma)
#define BINCHUNK 4096
#define BIN_NBLK ((NED + BINCHUNK - 1) / BINCHUNK)  // 391

typedef unsigned short u16;

__device__ __forceinline__ void atomAdd(float* p, float v) {
    __hip_atomic_fetch_add(p, v, __ATOMIC_RELAXED, __HIP_MEMORY_SCOPE_AGENT);
}
__device__ __forceinline__ unsigned atomAddU(unsigned* p, unsigned v) {
    return __hip_atomic_fetch_add(p, v, __ATOMIC_RELAXED, __HIP_MEMORY_SCOPE_AGENT);
}
__device__ __forceinline__ float leaky(float v, float s) { return v >= 0.f ? v : s * v; }
__device__ __forceinline__ float bf2f(u16 u) {
    union { unsigned i; float f; } x; x.i = ((unsigned)u) << 16; return x.f;
}
__device__ __forceinline__ u16 f2bf(float f) {
    union { float f; unsigned i; } x; x.f = f;
    return (u16)((x.i + 0x7fffu + ((x.i >> 16) & 1u)) >> 16);
}
__device__ __forceinline__ float bflo(unsigned u) {
    union { unsigned i; float f; } x; x.i = u << 16; return x.f;
}
__device__ __forceinline__ float bfhi(unsigned u) {
    union { unsigned i; float f; } x; x.i = u & 0xffff0000u; return x.f;
}

// ---- K1: M_s[f,h] = sum_c Wg[f,h*32+c]*attS[h,c]; same for M_d (one block) ----
__global__ void k_matt(const float* __restrict__ Wg, const float* __restrict__ attS,
                       const float* __restrict__ attD, float* __restrict__ M) {
    int t = threadIdx.x;  // 128, use 72
    if (t >= 72) return;
    int d = t >= 36 ? 1 : 0;
    int q = t - 36 * d;
    int f = q >> 2, h = q & 3;
    const float* av = d ? attD : attS;
    float s = 0.f;
#pragma unroll
    for (int c = 0; c < 32; ++c) s += Wg[f * HC + h * 32 + c] * av[h * 32 + c];
    M[d * 36 + q] = s;
}

// ---- K1b: w2t[n][k] = bf16(W2[k][n]); also init bktCur[b] = b*BCAP ----
__global__ void k_w2t(const float* __restrict__ W2, u16* __restrict__ w2t,
                      unsigned* __restrict__ bktCur) {
    int i = blockIdx.x * 256 + threadIdx.x;  // 8192
    int n = i >> 7, k = i & 127;
    w2t[i] = f2bf(W2[k * 64 + n]);
    if (i < NBUCK) bktCur[i] = (unsigned)i * BCAP;
}

// ---- K2: per-node 32B bf16 record rec = {x[9], pad[3], a_s[4]} + a_d f32 ----
__global__ void k_att(const float* __restrict__ x, const float* __restrict__ M,
                      u16* __restrict__ rec, float* __restrict__ a_d) {
    __shared__ float Ms[36], Md[36];
    int t = threadIdx.x;  // 256
    if (t < 36) Ms[t] = M[t];
    else if (t < 72) Md[t - 36] = M[t];
    __syncthreads();
    int n = blockIdx.x * 256 + t;
    if (n >= NND) return;
    float xv[FEAT];
#pragma unroll
    for (int f = 0; f < FEAT; ++f) xv[f] = x[n * FEAT + f];
    float s0 = 0, s1 = 0, s2 = 0, s3 = 0, d0 = 0, d1 = 0, d2 = 0, d3 = 0;
#pragma unroll
    for (int f = 0; f < FEAT; ++f) {
        float xf = xv[f];
        s0 += xf * Ms[f * 4 + 0]; s1 += xf * Ms[f * 4 + 1];
        s2 += xf * Ms[f * 4 + 2]; s3 += xf * Ms[f * 4 + 3];
        d0 += xf * Md[f * 4 + 0]; d1 += xf * Md[f * 4 + 1];
        d2 += xf * Md[f * 4 + 2]; d3 += xf * Md[f * 4 + 3];
    }
    u16 v[16];
#pragma unroll
    for (int f = 0; f < FEAT; ++f) v[f] = f2bf(xv[f]);
    v[9] = 0; v[10] = 0; v[11] = 0;
    v[12] = f2bf(s0); v[13] = f2bf(s1); v[14] = f2bf(s2); v[15] = f2bf(s3);
    unsigned pk[8];
#pragma unroll
    for (int i = 0; i < 8; ++i) pk[i] = (unsigned)v[2 * i] | ((unsigned)v[2 * i + 1] << 16);
    uint4* rp = (uint4*)(rec + (size_t)n * 16);
    rp[0] = make_uint4(pk[0], pk[1], pk[2], pk[3]);
    rp[1] = make_uint4(pk[4], pk[5], pk[6], pk[7]);
    ((float4*)a_d)[n] = make_float4(d0, d1, d2, d3);
}

// ---- K5: bin edges into fixed-capacity bucket staging, packed (dstLocal<<17)|src ----
__global__ __launch_bounds__(256) void k_bin(const int* __restrict__ ei,
                                             unsigned* __restrict__ bktCursor,
                                             unsigned* __restrict__ staging) {
    __shared__ unsigned hist[NBUCK];
    __shared__ unsigned gbase[NBUCK];
    int t = threadIdx.x;
    if (t < NBUCK) hist[t] = 0;
    __syncthreads();
    int base = blockIdx.x * BINCHUNK;
    int lim = NED - base;
    int srcv[16], dstv[16];
#pragma unroll
    for (int k = 0; k < 16; ++k) {
        int i = t + k * 256;
        if (i < lim) {
            srcv[k] = ei[base + i];
            dstv[k] = ei[NED + base + i];
            atomicAdd(&hist[dstv[k] >> 9], 1u);
        } else dstv[k] = -1;
    }
    __syncthreads();
    if (t < NBUCK) {
        unsigned c = hist[t];
        gbase[t] = c ? atomAddU(&bktCursor[t], c) : 0u;
    }
    __syncthreads();
    if (t < NBUCK) hist[t] = 0;
    __syncthreads();
#pragma unroll
    for (int k = 0; k < 16; ++k) {
        if (dstv[k] >= 0) {
            int bk = dstv[k] >> 9;
            unsigned off = atomicAdd(&hist[bk], 1u);
            staging[gbase[bk] + off] = ((unsigned)(dstv[k] & 511) << 17) | (unsigned)srcv[k];
        }
    }
}

// ---- K6: per-bucket CSR build: LDS hist + scan -> rowptr/deg/dinv; cursor scatter ----
__global__ __launch_bounds__(512) void k_place(const unsigned* __restrict__ bktCur,
                                               const unsigned* __restrict__ staging,
                                               unsigned* __restrict__ csr,
                                               unsigned* __restrict__ rowptr,
                                               u16* __restrict__ degA,
                                               float* __restrict__ dinv) {
    __shared__ unsigned lh[512];
    __shared__ unsigned ls[512];
    int b = blockIdx.x, t = threadIdx.x;
    unsigned lo = (unsigned)b * BCAP;
    unsigned n = bktCur[b] - lo;
    lh[t] = 0;
    __syncthreads();
    for (unsigned i = t; i < n; i += 512) atomicAdd(&lh[staging[lo + i] >> 17], 1u);
    __syncthreads();
    unsigned v = lh[t];
    ls[t] = v;
    __syncthreads();
    for (int off = 1; off < 512; off <<= 1) {
        unsigned u = (t >= off) ? ls[t - off] : 0u;
        __syncthreads();
        ls[t] += u;
        __syncthreads();
    }
    unsigned excl = ls[t] - v;
    int node = b * 512 + t;
    if (node < NND) {
        rowptr[node] = lo + excl;
        degA[node] = (u16)v;
        dinv[node] = rsqrtf((float)v + 1.f);
    }
    __syncthreads();
    lh[t] = excl;  // reuse as local cursor
    __syncthreads();
    for (unsigned i = t; i < n; i += 512) {
        unsigned p = staging[lo + i];
        unsigned pos = atomicAdd(&lh[p >> 17], 1u);
        csr[lo + pos] = p & 0x1FFFFu;
    }
}

// ---- K7: GAT aggregation, EDGE-PARALLEL: wave per node, lane = (edge 0..15, head 0..3) ----
// item 0 = self loop, items 1..d = csr edges. One exp per (edge,head); butterfly over e-lanes.
__global__ __launch_bounds__(256) void k_gat_g(const unsigned* __restrict__ rowptr,
                                               const u16* __restrict__ degA,
                                               const unsigned* __restrict__ csr,
                                               const u16* __restrict__ rec,
                                               const float* __restrict__ a_d,
                                               float* __restrict__ z) {
    int n = blockIdx.x * 4 + (threadIdx.x >> 6);  // grid NND/4 x 256 exact
    int l = threadIdx.x & 63;
    int e = l >> 2;   // 0..15 edge slot
    int h = l & 3;    // head
    unsigned e0 = rowptr[n];
    int m = (int)degA[n] + 1;  // items incl self
    float adh = a_d[n * 4 + h];
    float acc0 = 0, acc1 = 0, acc2 = 0, acc3 = 0, acc4 = 0, acc5 = 0, acc6 = 0, acc7 = 0, acc8 = 0;
    float den = 0.f;
    const uint4* recp = (const uint4*)rec;
    for (int c = 0; c < m; c += 16) {
        int idx = c + e;
        bool act = idx < m;
        int src = n;
        if (act && idx > 0) src = (int)csr[e0 + idx - 1];
        uint4 lo = recp[(size_t)src * 2];
        uint4 hi = recp[(size_t)src * 2 + 1];
        unsigned pair = (h & 2) ? hi.w : hi.z;
        float asf = (h & 1) ? bfhi(pair) : bflo(pair);
        float w = __expf(leaky(asf + adh, 0.2f));
        if (!act) w = 0.f;
        den += w;
        acc0 += w * bflo(lo.x); acc1 += w * bfhi(lo.x);
        acc2 += w * bflo(lo.y); acc3 += w * bfhi(lo.y);
        acc4 += w * bflo(lo.z); acc5 += w * bfhi(lo.z);
        acc6 += w * bflo(lo.w); acc7 += w * bfhi(lo.w);
        acc8 += w * bflo(hi.x);
    }
#pragma unroll
    for (int mask = 4; mask <= 32; mask <<= 1) {
        den  += __shfl_xor(den,  mask, 64);
        acc0 += __shfl_xor(acc0, mask, 64);
        acc1 += __shfl_xor(acc1, mask, 64);
        acc2 += __shfl_xor(acc2, mask, 64);
        acc3 += __shfl_xor(acc3, mask, 64);
        acc4 += __shfl_xor(acc4, mask, 64);
        acc5 += __shfl_xor(acc5, mask, 64);
        acc6 += __shfl_xor(acc6, mask, 64);
        acc7 += __shfl_xor(acc7, mask, 64);
        acc8 += __shfl_xor(acc8, mask, 64);
    }
    if (l < 4) {  // e==0, h=l
        float inv = 1.f / (den + 1e-16f);
        float* zp = z + (size_t)n * 36 + h * 9;
        zp[0] = acc0 * inv; zp[1] = acc1 * inv; zp[2] = acc2 * inv;
        zp[3] = acc3 * inv; zp[4] = acc4 * inv; zp[5] = acc5 * inv;
        zp[6] = acc6 * inv; zp[7] = acc7 * inv; zp[8] = acc8 * inv;
    }
}

// ---- K9: fused g1 + MFMA GEMM: h2 = bf16(dinv*(leaky(z@Whead+bg) @ W2)) ----
typedef __attribute__((ext_vector_type(8))) short bfrag;
typedef __attribute__((ext_vector_type(4))) float ffrag;
__global__ __launch_bounds__(256) void k_fused_h2(const float* __restrict__ z,
                                                  const float* __restrict__ Wg,
                                                  const float* __restrict__ bg,
                                                  const u16* __restrict__ w2t,
                                                  const float* __restrict__ dinv,
                                                  u16* __restrict__ h2) {
    __shared__ float zL[64 * 36];
    __shared__ float Wf[FEAT * HC];
    __shared__ float bgs[HC];
    __shared__ u16 g1L[64 * 136];
    int t = threadIdx.x;
    int n0 = blockIdx.x * 64;
    for (int i = t; i < 64 * 36; i += 256) {
        int row = i / 36;
        zL[i] = (n0 + row < NND) ? z[(size_t)(n0 + row) * 36 + (i - row * 36)] : 0.f;
    }
    for (int i = t; i < FEAT * HC; i += 256) Wf[i] = Wg[i];
    if (t < HC) bgs[t] = bg[t];
    __syncthreads();
    for (int e = t; e < 64 * 128; e += 256) {
        int row = e >> 7, col = e & 127;
        int h = col >> 5;
        float acc = bgs[col];
        const float* zr = zL + row * 36 + h * 9;
#pragma unroll
        for (int f = 0; f < 9; ++f) acc += zr[f] * Wf[f * 128 + col];
        g1L[row * 136 + col] = f2bf(leaky(acc, 0.01f));
    }
    __syncthreads();
    int l = t & 63, wv = t >> 6;
    int mr = l & 15, quad = l >> 4;
    union U { uint4 u; bfrag v; };
    bfrag a[4];
#pragma unroll
    for (int ks = 0; ks < 4; ++ks) {
        U uu; uu.u = *(const uint4*)(g1L + (wv * 16 + mr) * 136 + ks * 32 + quad * 8);
        a[ks] = uu.v;
    }
    ffrag acc[4];
#pragma unroll
    for (int ct = 0; ct < 4; ++ct) acc[ct] = (ffrag){0.f, 0.f, 0.f, 0.f};
#pragma unroll
    for (int ct = 0; ct < 4; ++ct) {
#pragma unroll
        for (int ks = 0; ks < 4; ++ks) {
            U ub; ub.u = *(const uint4*)(w2t + (ct * 16 + mr) * 128 + ks * 32 + quad * 8);
            acc[ct] = __builtin_amdgcn_mfma_f32_16x16x32_bf16(a[ks], ub.v, acc[ct], 0, 0, 0);
        }
    }
    int rbase = n0 + wv * 16 + quad * 4;
    if (rbase < NND) {
        float4 d4 = *(const float4*)(dinv + rbase);
        const float dv[4] = {d4.x, d4.y, d4.z, d4.w};
#pragma unroll
        for (int ct = 0; ct < 4; ++ct)
#pragma unroll
            for (int r = 0; r < 4; ++r)
                h2[(size_t)(rbase + r) * 64 + ct * 16 + mr] = f2bf(dv[r] * acc[ct][r]);
    }
}

// ---- K10/K11: GCN aggregation, QUAD-edge: lane = (edge-quad 0..3, channel-quad 0..15) ----
// Each lane loads uint2 (4 bf16 channels); one wave load covers 4 edge-rows.
// OUTMODE 1: bf16(dinv*leaky(dn*acc+bias)); OUTMODE 0: bf16(dn*acc)
template <int OUTMODE>
__global__ void k_gcn_g(const unsigned* __restrict__ rowptr, const u16* __restrict__ degA,
                        const unsigned* __restrict__ csr,
                        const float* __restrict__ dinv, const u16* __restrict__ hin,
                        const float* __restrict__ bias, u16* __restrict__ hout) {
    int n = blockIdx.x * 4 + (threadIdx.x >> 6);  // grid 25000 x 256 exact
    int l = threadIdx.x & 63;
    int grp = l >> 4;   // edge offset 0..3
    int c = l & 15;     // channel quad: channels 4c..4c+3
    unsigned e0 = rowptr[n];
    unsigned e1 = e0 + degA[n];
    const uint2* hinU = (const uint2*)hin;  // row = 16 uint2
    float a0 = 0, a1 = 0, a2 = 0, a3 = 0;
    if (grp == 0) {  // self term (pre-scaled at producer)
        uint2 u = hinU[(size_t)n * 16 + c];
        a0 = bflo(u.x); a1 = bfhi(u.x); a2 = bflo(u.y); a3 = bfhi(u.y);
    }
    unsigned e = e0;
    for (; e + 8 <= e1; e += 8) {
        unsigned s0 = csr[e + grp];
        unsigned s1 = csr[e + 4 + grp];
        uint2 u0 = hinU[(size_t)s0 * 16 + c];
        uint2 u1 = hinU[(size_t)s1 * 16 + c];
        a0 += bflo(u0.x) + bflo(u1.x); a1 += bfhi(u0.x) + bfhi(u1.x);
        a2 += bflo(u0.y) + bflo(u1.y); a3 += bfhi(u0.y) + bfhi(u1.y);
    }
    for (; e + 4 <= e1; e += 4) {
        unsigned s = csr[e + grp];
        uint2 u = hinU[(size_t)s * 16 + c];
        a0 += bflo(u.x); a1 += bfhi(u.x); a2 += bflo(u.y); a3 += bfhi(u.y);
    }
    if (grp < (int)(e1 - e)) {
        unsigned s = csr[e + grp];
        uint2 u = hinU[(size_t)s * 16 + c];
        a0 += bflo(u.x); a1 += bfhi(u.x); a2 += bflo(u.y); a3 += bfhi(u.y);
    }
#pragma unroll
    for (int mask = 16; mask <= 32; mask <<= 1) {
        a0 += __shfl_xor(a0, mask, 64);
        a1 += __shfl_xor(a1, mask, 64);
        a2 += __shfl_xor(a2, mask, 64);
        a3 += __shfl_xor(a3, mask, 64);
    }
    if (grp == 0) {
        float dn = dinv[n];
        float o0 = dn * a0, o1 = dn * a1, o2 = dn * a2, o3 = dn * a3;
        if (OUTMODE == 1) {
            o0 = leaky(o0 + bias[4 * c],     0.01f) * dn;
            o1 = leaky(o1 + bias[4 * c + 1], 0.01f) * dn;
            o2 = leaky(o2 + bias[4 * c + 2], 0.01f) * dn;
            o3 = leaky(o3 + bias[4 * c + 3], 0.01f) * dn;
        }
        uint2 pk;
        pk.x = (unsigned)f2bf(o0) | ((unsigned)f2bf(o1) << 16);
        pk.y = (unsigned)f2bf(o2) | ((unsigned)f2bf(o3) << 16);
        ((uint2*)hout)[(size_t)n * 16 + c] = pk;
    }
}

// ---- K12: fused GEMM + mean-pool: pooled[b] += leaky(agg3 @ W3 + b3) per node ----
__global__ __launch_bounds__(128) void k_gcn2_pool(const u16* __restrict__ agg3,
                                                   const float* __restrict__ W3,
                                                   const float* __restrict__ b3,
                                                   const int* __restrict__ batch,
                                                   float* __restrict__ pooled,
                                                   float* __restrict__ cnt) {
    __shared__ float rows[64][64];
    __shared__ int bts[64];
    int t = threadIdx.x;  // 128
    int n0 = blockIdx.x * 64;
    int nn = NND - n0; if (nn > 64) nn = 64;
    const unsigned* srcp = (const unsigned*)(agg3 + (size_t)n0 * 64);
    for (int i = t; i < nn * 32; i += 128) {
        unsigned u = srcp[i];
        ((float*)rows)[2 * i]     = bf2f((u16)(u & 0xffffu));
        ((float*)rows)[2 * i + 1] = bf2f((u16)(u >> 16));
    }
    if (t < nn) bts[t] = batch[n0 + t];
    float w[64];
#pragma unroll
    for (int k = 0; k < 64; ++k) w[k] = W3[k * 128 + t];
    float bc = b3[t];
    __syncthreads();
    float pacc = 0.f, pcnt = 0.f;
    int curb = -1;
    for (int j = 0; j < nn; ++j) {
        const float4* r4 = (const float4*)rows[j];
        float acc = bc;
#pragma unroll
        for (int kk = 0; kk < 16; ++kk) {
            float4 r = r4[kk];
            acc += r.x * w[4 * kk] + r.y * w[4 * kk + 1] + r.z * w[4 * kk + 2] + r.w * w[4 * kk + 3];
        }
        float g = leaky(acc, 0.01f);
        int b = bts[j];
        if (b != curb) {
            if (curb >= 0) {
                atomAdd(&pooled[curb * 128 + t], pacc);
                if (t == 0) atomAdd(&cnt[curb], pcnt);
            }
            curb = b; pacc = 0.f; pcnt = 0.f;
        }
        pacc += g; pcnt += 1.f;
    }
    if (curb >= 0) {
        atomAdd(&pooled[curb * 128 + t], pacc);
        if (t == 0) atomAdd(&cnt[curb], pcnt);
    }
}

// ---- K14: fused sequence branch -> sfc [B,64] ----
__global__ void k_seq(const float* __restrict__ seq, const float* __restrict__ w1, const float* __restrict__ c1b,
                      const float* __restrict__ w2, const float* __restrict__ c2b,
                      const float* __restrict__ g1n, const float* __restrict__ b1n,
                      const float* __restrict__ m1n, const float* __restrict__ v1n,
                      const float* __restrict__ g2n, const float* __restrict__ b2n,
                      const float* __restrict__ m2n, const float* __restrict__ v2n,
                      const float* __restrict__ fcW, const float* __restrict__ fcb,
                      float* __restrict__ sfc) {
    __shared__ float xs[30 * 20];
    __shared__ float y1[64 * 18];
    __shared__ float y2[64 * 16];
    __shared__ float red[4][64];
    int t = threadIdx.x;  // 256
    int b = blockIdx.x;
    for (int idx = t; idx < 600; idx += 256) xs[idx] = seq[b * 600 + idx];
    __syncthreads();
    for (int idx = t; idx < 64 * 18; idx += 256) {
        int o = idx / 18, l = idx - o * 18;
        float acc = c1b[o];
        for (int i = 0; i < 30; ++i)
#pragma unroll
            for (int k = 0; k < 3; ++k)
                acc += xs[i * 20 + l + k] * w1[o * 90 + i * 3 + k];
        float bn = (acc - m1n[o]) * rsqrtf(v1n[o] + 1e-5f) * g1n[o] + b1n[o];
        y1[idx] = leaky(bn, 0.01f);
    }
    __syncthreads();
    for (int idx = t; idx < 64 * 16; idx += 256) {
        int o = idx >> 4, l = idx & 15;
        float acc = c2b[o];
        for (int i = 0; i < 64; ++i)
#pragma unroll
            for (int k = 0; k < 3; ++k)
                acc += y1[i * 18 + l + k] * w2[o * 192 + i * 3 + k];
        float bn = (acc - m2n[o]) * rsqrtf(v2n[o] + 1e-5f) * g2n[o] + b2n[o];
        y2[idx] = leaky(bn, 0.01f);
    }
    __syncthreads();
    {
        int o = t & 63, part = t >> 6;
        float acc = 0.f;
        for (int j = part * 256; j < part * 256 + 256; ++j)
            acc += y2[j] * fcW[j * 64 + o];
        red[part][o] = acc;
    }
    __syncthreads();
    if (t < 64) sfc[b * 64 + t] = red[0][t] + red[1][t] + red[2][t] + red[3][t] + fcb[t];
}

// ---- K15: fusion + classifier -> out [B,1] f32 ----
__global__ void k_final(const float* __restrict__ pooled, const float* __restrict__ cnt,
                        const float* __restrict__ sfc,
                        const float* __restrict__ fusW, const float* __restrict__ fusb,
                        const float* __restrict__ c1W, const float* __restrict__ c1b,
                        const float* __restrict__ c3W, const float* __restrict__ c3b,
                        float* __restrict__ out) {
    __shared__ float comb[192];
    __shared__ float t1[128];
    int t = threadIdx.x;  // 128
    int b = blockIdx.x;
    float invc = 1.f / fmaxf(cnt[b], 1.f);
    comb[t] = pooled[b * 128 + t] * invc;
    if (t < 64) comb[128 + t] = sfc[b * 64 + t];
    __syncthreads();
    float acc = fusb[t];
    for (int k = 0; k < 192; ++k) acc += comb[k] * fusW[k * 128 + t];
    t1[t] = leaky(acc, 0.01f);
    __syncthreads();
    if (t < 64) {
        float a2 = c1b[t];
        for (int k = 0; k < 128; ++k) a2 += t1[k] * c1W[k * 64 + t];
        a2 = leaky(a2, 0.01f);
        float p = a2 * c3W[t];
#pragma unroll
        for (int off = 32; off; off >>= 1) p += __shfl_xor(p, off, 64);
        if (t == 0) out[b] = p + c3b[0];
    }
}

extern "C" void kernel_launch(void* const* d_in, const int* in_sizes, int n_in,
                              void* d_out, int out_size, void* d_ws, size_t ws_size,
                              hipStream_t stream) {
    const float* x     = (const float*)d_in[0];
    const int*   ei    = (const int*)d_in[1];
    const int*   batch = (const int*)d_in[2];
    const float* seq   = (const float*)d_in[3];
    const float* Wg    = (const float*)d_in[4];
    const float* attS  = (const float*)d_in[5];
    const float* attD  = (const float*)d_in[6];
    const float* bg    = (const float*)d_in[7];
    const float* W2    = (const float*)d_in[8];
    const float* b2    = (const float*)d_in[9];
    const float* W3    = (const float*)d_in[10];
    const float* b3    = (const float*)d_in[11];
    const float* c1w   = (const float*)d_in[12];
    const float* c1bb  = (const float*)d_in[13];
    const float* c2w   = (const float*)d_in[14];
    const float* c2bb  = (const float*)d_in[15];
    const float* bn1g  = (const float*)d_in[16];
    const float* bn1b  = (const float*)d_in[17];
    const float* bn1m  = (const float*)d_in[18];
    const float* bn1v  = (const float*)d_in[19];
    const float* bn2g  = (const float*)d_in[20];
    const float* bn2b  = (const float*)d_in[21];
    const float* bn2m  = (const float*)d_in[22];
    const float* bn2v  = (const float*)d_in[23];
    const float* fcW   = (const float*)d_in[24];
    const float* fcb   = (const float*)d_in[25];
    const float* fusW  = (const float*)d_in[26];
    const float* fusb  = (const float*)d_in[27];
    const float* cls1W = (const float*)d_in[28];
    const float* cls1b = (const float*)d_in[29];
    const float* cls3W = (const float*)d_in[30];
    const float* cls3b = (const float*)d_in[31];

    // ---- workspace arena ----
    char* wsb = (char*)d_ws;
    const size_t N = NND;
    float*    M      = (float*)wsb;                                  // 80
    float*    a_d    = M + 80;                                       // N*4 f32
    u16*      rec    = (u16*)(a_d + N * 4);                          // N*16 u16 (32B/node)
    float*    dinv   = (float*)(rec + N * 16);                       // N
    float*    pooled = dinv + N;                                     // B*128 } zero block
    float*    cnt    = pooled + (size_t)NB * 128;                    // B     }
    unsigned* bktCur = (unsigned*)(cnt + NB);                        // 256
    unsigned* rowptr = bktCur + 256;                                 // N
    u16*      degA   = (u16*)(rowptr + N);                           // N u16 (+pad)
    u16*      w2t    = degA + N + 8;                                 // 8192 u16
    unsigned* staging= (unsigned*)(w2t + 8192);                      // NBUCK*BCAP u32 (9.6MB)
    unsigned* csr    = staging + (size_t)NBUCK * BCAP;               // NBUCK*BCAP u32 (9.6MB)
    float*    z      = (float*)(csr + (size_t)NBUCK * BCAP);         // N*36 f32 (+64 pad)
    u16*      h2b    = (u16*)(z + N * 36 + 64);                      // N*64 bf16
    u16*      g2b    = h2b + N * 64;                                 // N*64 bf16
    u16*      agg3b  = g2b + N * 64;                                 // N*64 bf16
    float*    sfc    = (float*)(agg3b + N * 64);                     // B*64

    size_t zero_bytes = ((size_t)NB * 128 + NB) * 4;
    hipMemsetAsync(pooled, 0, zero_bytes, stream);

    k_matt<<<1, 128, 0, stream>>>(Wg, attS, attD, M);
    k_w2t<<<32, 256, 0, stream>>>(W2, w2t, bktCur);
    k_att<<<(NND + 255) / 256, 256, 0, stream>>>(x, M, rec, a_d);
    k_bin<<<BIN_NBLK, 256, 0, stream>>>(ei, bktCur, staging);
    k_place<<<NBUCK, 512, 0, stream>>>(bktCur, staging, csr, rowptr, degA, dinv);
    k_gat_g<<<NND / 4, 256, 0, stream>>>(rowptr, degA, csr, rec, a_d, z);
    k_fused_h2<<<(NND + 63) / 64, 256, 0, stream>>>(z, Wg, bg, w2t, dinv, h2b);
    k_gcn_g<1><<<NND / 4, 256, 0, stream>>>(rowptr, degA, csr, dinv, h2b, b2, g2b);
    k_gcn_g<0><<<NND / 4, 256, 0, stream>>>(rowptr, degA, csr, dinv, g2b, b2, agg3b);
    k_gcn2_pool<<<(NND + 63) / 64, 128, 0, stream>>>(agg3b, W3, b3, batch, pooled, cnt);
    k_seq<<<NB, 256, 0, stream>>>(seq, c1w, c1bb, c2w, c2bb, bn1g, bn1b, bn1m, bn1v,
                                  bn2g, bn2b, bn2m, bn2v, fcW, fcb, sfc);
    k_final<<<NB, 128, 0, stream>>>(pooled, cnt, sfc, fusW, fusb, cls1W, cls1b,
                                    cls3W, cls3b, (float*)d_out);
}

// Round 13
// 435.276 us; speedup vs baseline: 4.8257x; 1.0465x over previous
//
#include <hip/hip_runtime.h>

#define NND 100000
#define NED 1600000
#define NB  1024
#define FEAT 9
#define HC 128
#define NBUCK ((NND + 511) / 512)            // 196 buckets of 512 nodes
#define BCAP 12288u                          // fixed bucket capacity (mean 8192, +45 sigma)
#define BINCHUNK 4096
#define BIN_NBLK ((NED + BINCHUNK - 1) / BINCHUNK)  // 391

typedef unsigned short u16;

__device__ __forceinline__ void atomAdd(float* p, float v) {
    __hip_atomic_fetch_add(p, v, __ATOMIC_RELAXED, __HIP_MEMORY_SCOPE_AGENT);
}
__device__ __forceinline__ unsigned atomAddU(unsigned* p, unsigned v) {
    return __hip_atomic_fetch_add(p, v, __ATOMIC_RELAXED, __HIP_MEMORY_SCOPE_AGENT);
}
__device__ __forceinline__ float leaky(float v, float s) { return v >= 0.f ? v : s * v; }
__device__ __forceinline__ float bf2f(u16 u) {
    union { unsigned i; float f; } x; x.i = ((unsigned)u) << 16; return x.f;
}
__device__ __forceinline__ u16 f2bf(float f) {
    union { float f; unsigned i; } x; x.f = f;
    return (u16)((x.i + 0x7fffu + ((x.i >> 16) & 1u)) >> 16);
}
__device__ __forceinline__ float bflo(unsigned u) {
    union { unsigned i; float f; } x; x.i = u << 16; return x.f;
}
__device__ __forceinline__ float bfhi(unsigned u) {
    union { unsigned i; float f; } x; x.i = u & 0xffff0000u; return x.f;
}

// ---- K1: M_s[f,h] = sum_c Wg[f,h*32+c]*attS[h,c]; same for M_d (one block) ----
__global__ void k_matt(const float* __restrict__ Wg, const float* __restrict__ attS,
                       const float* __restrict__ attD, float* __restrict__ M) {
    int t = threadIdx.x;  // 128, use 72
    if (t >= 72) return;
    int d = t >= 36 ? 1 : 0;
    int q = t - 36 * d;
    int f = q >> 2, h = q & 3;
    const float* av = d ? attD : attS;
    float s = 0.f;
#pragma unroll
    for (int c = 0; c < 32; ++c) s += Wg[f * HC + h * 32 + c] * av[h * 32 + c];
    M[d * 36 + q] = s;
}

// ---- K1b: w2t[n][k]=bf16(W2[k][n]); w3t[n][k]=bf16(W3[k][n]); init bktCur ----
__global__ void k_w2t(const float* __restrict__ W2, const float* __restrict__ W3,
                      u16* __restrict__ w2t, u16* __restrict__ w3t,
                      unsigned* __restrict__ bktCur) {
    int i = blockIdx.x * 256 + threadIdx.x;  // 8192
    int n = i >> 7, k = i & 127;
    w2t[i] = f2bf(W2[k * 64 + n]);
    int n3 = i >> 6, k3 = i & 63;
    w3t[i] = f2bf(W3[k3 * 128 + n3]);
    if (i < NBUCK) bktCur[i] = (unsigned)i * BCAP;
}

// ---- K2: per-node 32B bf16 record rec = {x[9], pad[3], a_s[4]} + a_d f32 ----
__global__ void k_att(const float* __restrict__ x, const float* __restrict__ M,
                      u16* __restrict__ rec, float* __restrict__ a_d) {
    __shared__ float Ms[36], Md[36];
    int t = threadIdx.x;  // 256
    if (t < 36) Ms[t] = M[t];
    else if (t < 72) Md[t - 36] = M[t];
    __syncthreads();
    int n = blockIdx.x * 256 + t;
    if (n >= NND) return;
    float xv[FEAT];
#pragma unroll
    for (int f = 0; f < FEAT; ++f) xv[f] = x[n * FEAT + f];
    float s0 = 0, s1 = 0, s2 = 0, s3 = 0, d0 = 0, d1 = 0, d2 = 0, d3 = 0;
#pragma unroll
    for (int f = 0; f < FEAT; ++f) {
        float xf = xv[f];
        s0 += xf * Ms[f * 4 + 0]; s1 += xf * Ms[f * 4 + 1];
        s2 += xf * Ms[f * 4 + 2]; s3 += xf * Ms[f * 4 + 3];
        d0 += xf * Md[f * 4 + 0]; d1 += xf * Md[f * 4 + 1];
        d2 += xf * Md[f * 4 + 2]; d3 += xf * Md[f * 4 + 3];
    }
    u16 v[16];
#pragma unroll
    for (int f = 0; f < FEAT; ++f) v[f] = f2bf(xv[f]);
    v[9] = 0; v[10] = 0; v[11] = 0;
    v[12] = f2bf(s0); v[13] = f2bf(s1); v[14] = f2bf(s2); v[15] = f2bf(s3);
    unsigned pk[8];
#pragma unroll
    for (int i = 0; i < 8; ++i) pk[i] = (unsigned)v[2 * i] | ((unsigned)v[2 * i + 1] << 16);
    uint4* rp = (uint4*)(rec + (size_t)n * 16);
    rp[0] = make_uint4(pk[0], pk[1], pk[2], pk[3]);
    rp[1] = make_uint4(pk[4], pk[5], pk[6], pk[7]);
    ((float4*)a_d)[n] = make_float4(d0, d1, d2, d3);
}

// ---- K5: bin edges into fixed-capacity bucket staging, packed (dstLocal<<17)|src ----
__global__ __launch_bounds__(256) void k_bin(const int* __restrict__ ei,
                                             unsigned* __restrict__ bktCursor,
                                             unsigned* __restrict__ staging) {
    __shared__ unsigned hist[NBUCK];
    __shared__ unsigned gbase[NBUCK];
    int t = threadIdx.x;
    if (t < NBUCK) hist[t] = 0;
    __syncthreads();
    int base = blockIdx.x * BINCHUNK;
    int lim = NED - base;
    int srcv[16], dstv[16];
#pragma unroll
    for (int k = 0; k < 16; ++k) {
        int i = t + k * 256;
        if (i < lim) {
            srcv[k] = ei[base + i];
            dstv[k] = ei[NED + base + i];
            atomicAdd(&hist[dstv[k] >> 9], 1u);
        } else dstv[k] = -1;
    }
    __syncthreads();
    if (t < NBUCK) {
        unsigned c = hist[t];
        gbase[t] = c ? atomAddU(&bktCursor[t], c) : 0u;
    }
    __syncthreads();
    if (t < NBUCK) hist[t] = 0;
    __syncthreads();
#pragma unroll
    for (int k = 0; k < 16; ++k) {
        if (dstv[k] >= 0) {
            int bk = dstv[k] >> 9;
            unsigned off = atomicAdd(&hist[bk], 1u);
            staging[gbase[bk] + off] = ((unsigned)(dstv[k] & 511) << 17) | (unsigned)srcv[k];
        }
    }
}

// ---- K6: per-bucket CSR build: LDS hist + scan -> rowptr/deg/dinv; cursor scatter ----
__global__ __launch_bounds__(512) void k_place(const unsigned* __restrict__ bktCur,
                                               const unsigned* __restrict__ staging,
                                               unsigned* __restrict__ csr,
                                               unsigned* __restrict__ rowptr,
                                               u16* __restrict__ degA,
                                               float* __restrict__ dinv) {
    __shared__ unsigned lh[512];
    __shared__ unsigned ls[512];
    int b = blockIdx.x, t = threadIdx.x;
    unsigned lo = (unsigned)b * BCAP;
    unsigned n = bktCur[b] - lo;
    lh[t] = 0;
    __syncthreads();
    for (unsigned i = t; i < n; i += 512) atomicAdd(&lh[staging[lo + i] >> 17], 1u);
    __syncthreads();
    unsigned v = lh[t];
    ls[t] = v;
    __syncthreads();
    for (int off = 1; off < 512; off <<= 1) {
        unsigned u = (t >= off) ? ls[t - off] : 0u;
        __syncthreads();
        ls[t] += u;
        __syncthreads();
    }
    unsigned excl = ls[t] - v;
    int node = b * 512 + t;
    if (node < NND) {
        rowptr[node] = lo + excl;
        degA[node] = (u16)v;
        dinv[node] = rsqrtf((float)v + 1.f);
    }
    __syncthreads();
    lh[t] = excl;  // reuse as local cursor
    __syncthreads();
    for (unsigned i = t; i < n; i += 512) {
        unsigned p = staging[lo + i];
        unsigned pos = atomicAdd(&lh[p >> 17], 1u);
        csr[lo + pos] = p & 0x1FFFFu;
    }
}

// ---- K7: GAT aggregation, EDGE-PARALLEL: wave per node, lane = (edge 0..15, head 0..3) ----
__global__ __launch_bounds__(256) void k_gat_g(const unsigned* __restrict__ rowptr,
                                               const u16* __restrict__ degA,
                                               const unsigned* __restrict__ csr,
                                               const u16* __restrict__ rec,
                                               const float* __restrict__ a_d,
                                               float* __restrict__ z) {
    int n = blockIdx.x * 4 + (threadIdx.x >> 6);  // grid NND/4 x 256 exact
    int l = threadIdx.x & 63;
    int e = l >> 2;   // 0..15 edge slot
    int h = l & 3;    // head
    unsigned e0 = rowptr[n];
    int m = (int)degA[n] + 1;  // items incl self
    float adh = a_d[n * 4 + h];
    float acc0 = 0, acc1 = 0, acc2 = 0, acc3 = 0, acc4 = 0, acc5 = 0, acc6 = 0, acc7 = 0, acc8 = 0;
    float den = 0.f;
    const uint4* recp = (const uint4*)rec;
    for (int c = 0; c < m; c += 16) {
        int idx = c + e;
        bool act = idx < m;
        int src = n;
        if (act && idx > 0) src = (int)csr[e0 + idx - 1];
        uint4 lo = recp[(size_t)src * 2];
        uint4 hi = recp[(size_t)src * 2 + 1];
        unsigned pair = (h & 2) ? hi.w : hi.z;
        float asf = (h & 1) ? bfhi(pair) : bflo(pair);
        float w = __expf(leaky(asf + adh, 0.2f));
        if (!act) w = 0.f;
        den += w;
        acc0 += w * bflo(lo.x); acc1 += w * bfhi(lo.x);
        acc2 += w * bflo(lo.y); acc3 += w * bfhi(lo.y);
        acc4 += w * bflo(lo.z); acc5 += w * bfhi(lo.z);
        acc6 += w * bflo(lo.w); acc7 += w * bfhi(lo.w);
        acc8 += w * bflo(hi.x);
    }
#pragma unroll
    for (int mask = 4; mask <= 32; mask <<= 1) {
        den  += __shfl_xor(den,  mask, 64);
        acc0 += __shfl_xor(acc0, mask, 64);
        acc1 += __shfl_xor(acc1, mask, 64);
        acc2 += __shfl_xor(acc2, mask, 64);
        acc3 += __shfl_xor(acc3, mask, 64);
        acc4 += __shfl_xor(acc4, mask, 64);
        acc5 += __shfl_xor(acc5, mask, 64);
        acc6 += __shfl_xor(acc6, mask, 64);
        acc7 += __shfl_xor(acc7, mask, 64);
        acc8 += __shfl_xor(acc8, mask, 64);
    }
    if (l < 4) {  // e==0, h=l
        float inv = 1.f / (den + 1e-16f);
        float* zp = z + (size_t)n * 36 + h * 9;
        zp[0] = acc0 * inv; zp[1] = acc1 * inv; zp[2] = acc2 * inv;
        zp[3] = acc3 * inv; zp[4] = acc4 * inv; zp[5] = acc5 * inv;
        zp[6] = acc6 * inv; zp[7] = acc7 * inv; zp[8] = acc8 * inv;
    }
}

// ---- K9: fused g1 + MFMA GEMM: h2 = bf16(dinv*(leaky(z@Whead+bg) @ W2)) ----
typedef __attribute__((ext_vector_type(8))) short bfrag;
typedef __attribute__((ext_vector_type(4))) float ffrag;
__global__ __launch_bounds__(256) void k_fused_h2(const float* __restrict__ z,
                                                  const float* __restrict__ Wg,
                                                  const float* __restrict__ bg,
                                                  const u16* __restrict__ w2t,
                                                  const float* __restrict__ dinv,
                                                  u16* __restrict__ h2) {
    __shared__ float zL[64 * 36];
    __shared__ float Wf[FEAT * HC];
    __shared__ float bgs[HC];
    __shared__ u16 g1L[64 * 136];
    int t = threadIdx.x;
    int n0 = blockIdx.x * 64;
    for (int i = t; i < 64 * 36; i += 256) {
        int row = i / 36;
        zL[i] = (n0 + row < NND) ? z[(size_t)(n0 + row) * 36 + (i - row * 36)] : 0.f;
    }
    for (int i = t; i < FEAT * HC; i += 256) Wf[i] = Wg[i];
    if (t < HC) bgs[t] = bg[t];
    __syncthreads();
    for (int e = t; e < 64 * 128; e += 256) {
        int row = e >> 7, col = e & 127;
        int h = col >> 5;
        float acc = bgs[col];
        const float* zr = zL + row * 36 + h * 9;
#pragma unroll
        for (int f = 0; f < 9; ++f) acc += zr[f] * Wf[f * 128 + col];
        g1L[row * 136 + col] = f2bf(leaky(acc, 0.01f));
    }
    __syncthreads();
    int l = t & 63, wv = t >> 6;
    int mr = l & 15, quad = l >> 4;
    union U { uint4 u; bfrag v; };
    bfrag a[4];
#pragma unroll
    for (int ks = 0; ks < 4; ++ks) {
        U uu; uu.u = *(const uint4*)(g1L + (wv * 16 + mr) * 136 + ks * 32 + quad * 8);
        a[ks] = uu.v;
    }
    ffrag acc[4];
#pragma unroll
    for (int ct = 0; ct < 4; ++ct) acc[ct] = (ffrag){0.f, 0.f, 0.f, 0.f};
#pragma unroll
    for (int ct = 0; ct < 4; ++ct) {
#pragma unroll
        for (int ks = 0; ks < 4; ++ks) {
            U ub; ub.u = *(const uint4*)(w2t + (ct * 16 + mr) * 128 + ks * 32 + quad * 8);
            acc[ct] = __builtin_amdgcn_mfma_f32_16x16x32_bf16(a[ks], ub.v, acc[ct], 0, 0, 0);
        }
    }
    int rbase = n0 + wv * 16 + quad * 4;
    if (rbase < NND) {
        float4 d4 = *(const float4*)(dinv + rbase);
        const float dv[4] = {d4.x, d4.y, d4.z, d4.w};
#pragma unroll
        for (int ct = 0; ct < 4; ++ct)
#pragma unroll
            for (int r = 0; r < 4; ++r)
                h2[(size_t)(rbase + r) * 64 + ct * 16 + mr] = f2bf(dv[r] * acc[ct][r]);
    }
}

// ---- K10/K11: GCN aggregation, QUAD-edge: lane = (edge-quad 0..3, channel-quad 0..15) ----
template <int OUTMODE>
__global__ void k_gcn_g(const unsigned* __restrict__ rowptr, const u16* __restrict__ degA,
                        const unsigned* __restrict__ csr,
                        const float* __restrict__ dinv, const u16* __restrict__ hin,
                        const float* __restrict__ bias, u16* __restrict__ hout) {
    int n = blockIdx.x * 4 + (threadIdx.x >> 6);  // grid 25000 x 256 exact
    int l = threadIdx.x & 63;
    int grp = l >> 4;   // edge offset 0..3
    int c = l & 15;     // channel quad: channels 4c..4c+3
    unsigned e0 = rowptr[n];
    unsigned e1 = e0 + degA[n];
    const uint2* hinU = (const uint2*)hin;  // row = 16 uint2
    float a0 = 0, a1 = 0, a2 = 0, a3 = 0;
    if (grp == 0) {  // self term (pre-scaled at producer)
        uint2 u = hinU[(size_t)n * 16 + c];
        a0 = bflo(u.x); a1 = bfhi(u.x); a2 = bflo(u.y); a3 = bfhi(u.y);
    }
    unsigned e = e0;
    for (; e + 8 <= e1; e += 8) {
        unsigned s0 = csr[e + grp];
        unsigned s1 = csr[e + 4 + grp];
        uint2 u0 = hinU[(size_t)s0 * 16 + c];
        uint2 u1 = hinU[(size_t)s1 * 16 + c];
        a0 += bflo(u0.x) + bflo(u1.x); a1 += bfhi(u0.x) + bfhi(u1.x);
        a2 += bflo(u0.y) + bflo(u1.y); a3 += bfhi(u0.y) + bfhi(u1.y);
    }
    for (; e + 4 <= e1; e += 4) {
        unsigned s = csr[e + grp];
        uint2 u = hinU[(size_t)s * 16 + c];
        a0 += bflo(u.x); a1 += bfhi(u.x); a2 += bflo(u.y); a3 += bfhi(u.y);
    }
    if (grp < (int)(e1 - e)) {
        unsigned s = csr[e + grp];
        uint2 u = hinU[(size_t)s * 16 + c];
        a0 += bflo(u.x); a1 += bfhi(u.x); a2 += bflo(u.y); a3 += bfhi(u.y);
    }
#pragma unroll
    for (int mask = 16; mask <= 32; mask <<= 1) {
        a0 += __shfl_xor(a0, mask, 64);
        a1 += __shfl_xor(a1, mask, 64);
        a2 += __shfl_xor(a2, mask, 64);
        a3 += __shfl_xor(a3, mask, 64);
    }
    if (grp == 0) {
        float dn = dinv[n];
        float o0 = dn * a0, o1 = dn * a1, o2 = dn * a2, o3 = dn * a3;
        if (OUTMODE == 1) {
            o0 = leaky(o0 + bias[4 * c],     0.01f) * dn;
            o1 = leaky(o1 + bias[4 * c + 1], 0.01f) * dn;
            o2 = leaky(o2 + bias[4 * c + 2], 0.01f) * dn;
            o3 = leaky(o3 + bias[4 * c + 3], 0.01f) * dn;
        }
        uint2 pk;
        pk.x = (unsigned)f2bf(o0) | ((unsigned)f2bf(o1) << 16);
        pk.y = (unsigned)f2bf(o2) | ((unsigned)f2bf(o3) << 16);
        ((uint2*)hout)[(size_t)n * 16 + c] = pk;
    }
}

// ---- K12: MFMA GEMM + fused mean-pool: pooled[b] += leaky(agg3 @ W3 + b3) ----
// 64 nodes/block, 4 waves x 16 rows; agg3 tile bf16 in LDS [64][72]; w3t B-frags.
__global__ __launch_bounds__(256) void k_gcn2_pool(const u16* __restrict__ agg3,
                                                   const u16* __restrict__ w3t,
                                                   const float* __restrict__ b3,
                                                   const int* __restrict__ batch,
                                                   float* __restrict__ pooled,
                                                   float* __restrict__ cnt) {
    __shared__ u16 rows[64 * 72];
    __shared__ int bts[64];
    __shared__ float b3s[128];
    int t = threadIdx.x;
    int n0 = blockIdx.x * 64;
    int nn = NND - n0; if (nn > 64) nn = 64;
    const uint4* src = (const uint4*)(agg3 + (size_t)n0 * 64);  // 8 uint4 per row
    for (int i = t; i < 512; i += 256) {
        int r = i >> 3, c8 = i & 7;
        uint4 v = (r < nn) ? src[i] : make_uint4(0u, 0u, 0u, 0u);
        *(uint4*)(rows + r * 72 + c8 * 8) = v;
    }
    if (t < 64) bts[t] = (t < nn) ? batch[n0 + t] : -1;
    if (t < 128) b3s[t] = b3[t];
    __syncthreads();
    int l = t & 63, wv = t >> 6;
    int mr = l & 15, quad = l >> 4;
    union U { uint4 u; bfrag v; };
    bfrag a[2];
#pragma unroll
    for (int ks = 0; ks < 2; ++ks) {
        U uu; uu.u = *(const uint4*)(rows + (wv * 16 + mr) * 72 + ks * 32 + quad * 8);
        a[ks] = uu.v;
    }
    ffrag acc[8];
#pragma unroll
    for (int ct = 0; ct < 8; ++ct) acc[ct] = (ffrag){0.f, 0.f, 0.f, 0.f};
#pragma unroll
    for (int ct = 0; ct < 8; ++ct) {
#pragma unroll
        for (int ks = 0; ks < 2; ++ks) {
            U ub; ub.u = *(const uint4*)(w3t + (ct * 16 + mr) * 64 + ks * 32 + quad * 8);
            acc[ct] = __builtin_amdgcn_mfma_f32_16x16x32_bf16(a[ks], ub.v, acc[ct], 0, 0, 0);
        }
    }
    int rl = wv * 16 + quad * 4;
    int ub = bts[wv * 16];
    bool uni = (ub == bts[wv * 16 + 15]);
#pragma unroll
    for (int ct = 0; ct < 8; ++ct) {
        int col = ct * 16 + mr;
        float bc = b3s[col];
        float g0 = leaky(acc[ct][0] + bc, 0.01f);
        float g1 = leaky(acc[ct][1] + bc, 0.01f);
        float g2 = leaky(acc[ct][2] + bc, 0.01f);
        float g3 = leaky(acc[ct][3] + bc, 0.01f);
        if (uni) {
            float s = g0 + g1 + g2 + g3;
            s += __shfl_xor(s, 16, 64);
            s += __shfl_xor(s, 32, 64);
            if (quad == 0 && ub >= 0) atomAdd(&pooled[ub * 128 + col], s);
        } else {
            float gr[4] = {g0, g1, g2, g3};
            int curb = bts[rl];
            float s = 0.f;
#pragma unroll
            for (int r = 0; r < 4; ++r) {
                int b = bts[rl + r];
                if (b != curb) {
                    if (curb >= 0) atomAdd(&pooled[curb * 128 + col], s);
                    s = 0.f; curb = b;
                }
                s += gr[r];
            }
            if (curb >= 0) atomAdd(&pooled[curb * 128 + col], s);
        }
    }
    if (t < nn) {
        int b = bts[t];
        if (t == 0 || bts[t - 1] != b) {
            int len = 1;
            for (int j = t + 1; j < nn && bts[j] == b; ++j) ++len;
            atomAdd(&cnt[b], (float)len);
        }
    }
}

// ---- K14: fused sequence branch -> sfc [B,64] ----
__global__ void k_seq(const float* __restrict__ seq, const float* __restrict__ w1, const float* __restrict__ c1b,
                      const float* __restrict__ w2, const float* __restrict__ c2b,
                      const float* __restrict__ g1n, const float* __restrict__ b1n,
                      const float* __restrict__ m1n, const float* __restrict__ v1n,
                      const float* __restrict__ g2n, const float* __restrict__ b2n,
                      const float* __restrict__ m2n, const float* __restrict__ v2n,
                      const float* __restrict__ fcW, const float* __restrict__ fcb,
                      float* __restrict__ sfc) {
    __shared__ float xs[30 * 20];
    __shared__ float y1[64 * 18];
    __shared__ float y2[64 * 16];
    __shared__ float red[4][64];
    int t = threadIdx.x;  // 256
    int b = blockIdx.x;
    for (int idx = t; idx < 600; idx += 256) xs[idx] = seq[b * 600 + idx];
    __syncthreads();
    for (int idx = t; idx < 64 * 18; idx += 256) {
        int o = idx / 18, l = idx - o * 18;
        float acc = c1b[o];
        for (int i = 0; i < 30; ++i)
#pragma unroll
            for (int k = 0; k < 3; ++k)
                acc += xs[i * 20 + l + k] * w1[o * 90 + i * 3 + k];
        float bn = (acc - m1n[o]) * rsqrtf(v1n[o] + 1e-5f) * g1n[o] + b1n[o];
        y1[idx] = leaky(bn, 0.01f);
    }
    __syncthreads();
    for (int idx = t; idx < 64 * 16; idx += 256) {
        int o = idx >> 4, l = idx & 15;
        float acc = c2b[o];
        for (int i = 0; i < 64; ++i)
#pragma unroll
            for (int k = 0; k < 3; ++k)
                acc += y1[i * 18 + l + k] * w2[o * 192 + i * 3 + k];
        float bn = (acc - m2n[o]) * rsqrtf(v2n[o] + 1e-5f) * g2n[o] + b2n[o];
        y2[idx] = leaky(bn, 0.01f);
    }
    __syncthreads();
    {
        int o = t & 63, part = t >> 6;
        float acc = 0.f;
        for (int j = part * 256; j < part * 256 + 256; ++j)
            acc += y2[j] * fcW[j * 64 + o];
        red[part][o] = acc;
    }
    __syncthreads();
    if (t < 64) sfc[b * 64 + t] = red[0][t] + red[1][t] + red[2][t] + red[3][t] + fcb[t];
}

// ---- K15: fusion + classifier -> out [B,1] f32 ----
__global__ void k_final(const float* __restrict__ pooled, const float* __restrict__ cnt,
                        const float* __restrict__ sfc,
                        const float* __restrict__ fusW, const float* __restrict__ fusb,
                        const float* __restrict__ c1W, const float* __restrict__ c1b,
                        const float* __restrict__ c3W, const float* __restrict__ c3b,
                        float* __restrict__ out) {
    __shared__ float comb[192];
    __shared__ float t1[128];
    int t = threadIdx.x;  // 128
    int b = blockIdx.x;
    float invc = 1.f / fmaxf(cnt[b], 1.f);
    comb[t] = pooled[b * 128 + t] * invc;
    if (t < 64) comb[128 + t] = sfc[b * 64 + t];
    __syncthreads();
    float acc = fusb[t];
    for (int k = 0; k < 192; ++k) acc += comb[k] * fusW[k * 128 + t];
    t1[t] = leaky(acc, 0.01f);
    __syncthreads();
    if (t < 64) {
        float a2 = c1b[t];
        for (int k = 0; k < 128; ++k) a2 += t1[k] * c1W[k * 64 + t];
        a2 = leaky(a2, 0.01f);
        float p = a2 * c3W[t];
#pragma unroll
        for (int off = 32; off; off >>= 1) p += __shfl_xor(p, off, 64);
        if (t == 0) out[b] = p + c3b[0];
    }
}

extern "C" void kernel_launch(void* const* d_in, const int* in_sizes, int n_in,
                              void* d_out, int out_size, void* d_ws, size_t ws_size,
                              hipStream_t stream) {
    const float* x     = (const float*)d_in[0];
    const int*   ei    = (const int*)d_in[1];
    const int*   batch = (const int*)d_in[2];
    const float* seq   = (const float*)d_in[3];
    const float* Wg    = (const float*)d_in[4];
    const float* attS  = (const float*)d_in[5];
    const float* attD  = (const float*)d_in[6];
    const float* bg    = (const float*)d_in[7];
    const float* W2    = (const float*)d_in[8];
    const float* b2    = (const float*)d_in[9];
    const float* W3    = (const float*)d_in[10];
    const float* b3    = (const float*)d_in[11];
    const float* c1w   = (const float*)d_in[12];
    const float* c1bb  = (const float*)d_in[13];
    const float* c2w   = (const float*)d_in[14];
    const float* c2bb  = (const float*)d_in[15];
    const float* bn1g  = (const float*)d_in[16];
    const float* bn1b  = (const float*)d_in[17];
    const float* bn1m  = (const float*)d_in[18];
    const float* bn1v  = (const float*)d_in[19];
    const float* bn2g  = (const float*)d_in[20];
    const float* bn2b  = (const float*)d_in[21];
    const float* bn2m  = (const float*)d_in[22];
    const float* bn2v  = (const float*)d_in[23];
    const float* fcW   = (const float*)d_in[24];
    const float* fcb   = (const float*)d_in[25];
    const float* fusW  = (const float*)d_in[26];
    const float* fusb  = (const float*)d_in[27];
    const float* cls1W = (const float*)d_in[28];
    const float* cls1b = (const float*)d_in[29];
    const float* cls3W = (const float*)d_in[30];
    const float* cls3b = (const float*)d_in[31];

    // ---- workspace arena ----
    char* wsb = (char*)d_ws;
    const size_t N = NND;
    float*    M      = (float*)wsb;                                  // 80
    float*    a_d    = M + 80;                                       // N*4 f32
    u16*      rec    = (u16*)(a_d + N * 4);                          // N*16 u16 (32B/node)
    float*    dinv   = (float*)(rec + N * 16);                       // N
    float*    pooled = dinv + N;                                     // B*128 } zero block
    float*    cnt    = pooled + (size_t)NB * 128;                    // B     }
    unsigned* bktCur = (unsigned*)(cnt + NB);                        // 256
    unsigned* rowptr = bktCur + 256;                                 // N
    u16*      degA   = (u16*)(rowptr + N);                           // N u16 (+pad)
    u16*      w2t    = degA + N + 8;                                 // 8192 u16
    u16*      w3t    = w2t + 8192;                                   // 8192 u16
    unsigned* staging= (unsigned*)(w3t + 8192);                      // NBUCK*BCAP u32 (9.6MB)
    unsigned* csr    = staging + (size_t)NBUCK * BCAP;               // NBUCK*BCAP u32 (9.6MB)
    float*    z      = (float*)(csr + (size_t)NBUCK * BCAP);         // N*36 f32 (+64 pad)
    u16*      h2b    = (u16*)(z + N * 36 + 64);                      // N*64 bf16
    u16*      g2b    = h2b + N * 64;                                 // N*64 bf16
    u16*      agg3b  = g2b + N * 64;                                 // N*64 bf16
    float*    sfc    = (float*)(agg3b + N * 64);                     // B*64

    size_t zero_bytes = ((size_t)NB * 128 + NB) * 4;
    hipMemsetAsync(pooled, 0, zero_bytes, stream);

    k_matt<<<1, 128, 0, stream>>>(Wg, attS, attD, M);
    k_w2t<<<32, 256, 0, stream>>>(W2, W3, w2t, w3t, bktCur);
    k_att<<<(NND + 255) / 256, 256, 0, stream>>>(x, M, rec, a_d);
    k_bin<<<BIN_NBLK, 256, 0, stream>>>(ei, bktCur, staging);
    k_place<<<NBUCK, 512, 0, stream>>>(bktCur, staging, csr, rowptr, degA, dinv);
    k_gat_g<<<NND / 4, 256, 0, stream>>>(rowptr, degA, csr, rec, a_d, z);
    k_fused_h2<<<(NND + 63) / 64, 256, 0, stream>>>(z, Wg, bg, w2t, dinv, h2b);
    k_gcn_g<1><<<NND / 4, 256, 0, stream>>>(rowptr, degA, csr, dinv, h2b, b2, g2b);
    k_gcn_g<0><<<NND / 4, 256, 0, stream>>>(rowptr, degA, csr, dinv, g2b, b2, agg3b);
    k_gcn2_pool<<<(NND + 63) / 64, 256, 0, stream>>>(agg3b, w3t, b3, batch, pooled, cnt);
    k_seq<<<NB, 256, 0, stream>>>(seq, c1w, c1bb, c2w, c2bb, bn1g, bn1b, bn1m, bn1v,
                                  bn2g, bn2b, bn2m, bn2v, fcW, fcb, sfc);
    k_final<<<NB, 128, 0, stream>>>(pooled, cnt, sfc, fusW, fusb, cls1W, cls1b,
                                    cls3W, cls3b, (float*)d_out);
}